// Round 1
// 1184.620 us; speedup vs baseline: 1.0870x; 1.0870x over previous
//
#include <hip/hip_runtime.h>
#include <hip/hip_bf16.h>
#include <math.h>

typedef __bf16 bf16x8_t __attribute__((ext_vector_type(8)));
typedef float f32x4_t __attribute__((ext_vector_type(4)));
typedef unsigned short u16x8_t __attribute__((ext_vector_type(8)));
typedef unsigned short u16x4_t __attribute__((ext_vector_type(4)));

#define DEV __device__ __forceinline__

DEV float bf2f(unsigned short u) {
    unsigned int v = ((unsigned int)u) << 16;
    return __builtin_bit_cast(float, v);
}
DEV unsigned short f2bf(float f) {
    unsigned int u = __builtin_bit_cast(unsigned int, f);
    u += 0x7fffu + ((u >> 16) & 1u);   // RNE
    return (unsigned short)(u >> 16);
}

// ---------------------------------------------------------------------------
// fp32 -> bf16 conversion (8 elems/thread)
// ---------------------------------------------------------------------------
__global__ __launch_bounds__(256) void cvt_k(
    const float* __restrict__ in, unsigned short* __restrict__ out, int n8)
{
    int t = blockIdx.x * 256 + threadIdx.x;
    if (t >= n8) return;
    f32x4_t a = ((const f32x4_t*)in)[t * 2];
    f32x4_t b = ((const f32x4_t*)in)[t * 2 + 1];
    u16x8_t o;
#pragma unroll
    for (int j = 0; j < 4; j++) { o[j] = f2bf(a[j]); o[4 + j] = f2bf(b[j]); }
    ((u16x8_t*)out)[t] = o;
}

// ---------------------------------------------------------------------------
// MFMA GEMM:  C[M x N] = A'[M x K] @ W[N x K]^T   (bf16 in, fp32 accum)
// 128x128 tile, BK=32, global_load_lds width-16 staging, XOR-swizzled chunks.
// staging: chunk c (0..511) -> row=c>>2, pos=c&3; holds kgroup g = pos ^ ((row>>1)&3)
// ---------------------------------------------------------------------------
template <bool FLIP_A, bool FLIP_C, bool OUT_F32, bool ADD_BIAS, bool ACCUM>
__global__ __launch_bounds__(256, 2) void gemm_bt(
    const unsigned short* __restrict__ A,
    const unsigned short* __restrict__ W,
    void* __restrict__ Cout,
    const float* __restrict__ bias,
    int N, int K, int ldc, int col_ofs)
{
    __shared__ __attribute__((aligned(16))) unsigned char smem[16384]; // A: 8KB, W: 8KB
    const int tid  = threadIdx.x;
    const int wave = tid >> 6;
    const int lane = tid & 63;
    const int mtile = blockIdx.y << 7;
    const int ntile = blockIdx.x << 7;

    const int c0 = tid, c1 = 256 + tid;
    const int r0 = c0 >> 2, p0 = c0 & 3, g0 = p0 ^ ((r0 >> 1) & 3);
    const int r1 = c1 >> 2, p1 = c1 & 3, g1 = p1 ^ ((r1 >> 1) & 3);

    int am0 = mtile + r0; if (FLIP_A) am0 ^= 4095;
    int am1 = mtile + r1; if (FLIP_A) am1 ^= 4095;
    const unsigned short* aP0 = A + (size_t)am0 * K + g0 * 8;
    const unsigned short* aP1 = A + (size_t)am1 * K + g1 * 8;

    int wr0 = ntile + r0; if (wr0 > N - 1) wr0 = N - 1;
    int wr1 = ntile + r1; if (wr1 > N - 1) wr1 = N - 1;
    const unsigned short* wP0 = W + (size_t)wr0 * K + g0 * 8;
    const unsigned short* wP1 = W + (size_t)wr1 * K + g1 * 8;

    unsigned char* ldsA = smem;
    unsigned char* ldsW = smem + 8192;
    unsigned char* ldsA0 = ldsA + wave * 1024;          // wave-uniform bases
    unsigned char* ldsA1 = ldsA + 4096 + wave * 1024;
    unsigned char* ldsW0 = ldsW + wave * 1024;
    unsigned char* ldsW1 = ldsW + 4096 + wave * 1024;

    f32x4_t acc[4][4] = {};

    const int wm = (wave & 1) << 6;
    const int wn = (wave >> 1) << 6;
    const int r    = lane & 15;
    const int quad = lane >> 4;
    const int sw   = (r >> 1) & 3;

    int aoff[4], woff[4];
#pragma unroll
    for (int i = 0; i < 4; i++) {
        int m = wm + i * 16 + r;
        aoff[i] = (m * 4 + (quad ^ sw)) * 16;
        int n = wn + i * 16 + r;
        woff[i] = (n * 4 + (quad ^ sw)) * 16;
    }

    for (int k0 = 0; k0 < K; k0 += 32) {
        __builtin_amdgcn_global_load_lds(
            (const __attribute__((address_space(1))) void*)(aP0 + k0),
            (__attribute__((address_space(3))) void*)ldsA0, 16, 0, 0);
        __builtin_amdgcn_global_load_lds(
            (const __attribute__((address_space(1))) void*)(aP1 + k0),
            (__attribute__((address_space(3))) void*)ldsA1, 16, 0, 0);
        __builtin_amdgcn_global_load_lds(
            (const __attribute__((address_space(1))) void*)(wP0 + k0),
            (__attribute__((address_space(3))) void*)ldsW0, 16, 0, 0);
        __builtin_amdgcn_global_load_lds(
            (const __attribute__((address_space(1))) void*)(wP1 + k0),
            (__attribute__((address_space(3))) void*)ldsW1, 16, 0, 0);
        __syncthreads();

        bf16x8_t af[4], wf[4];
#pragma unroll
        for (int i = 0; i < 4; i++)
            af[i] = __builtin_bit_cast(bf16x8_t, *(const u16x8_t*)(ldsA + aoff[i]));
#pragma unroll
        for (int j = 0; j < 4; j++)
            wf[j] = __builtin_bit_cast(bf16x8_t, *(const u16x8_t*)(ldsW + woff[j]));
#pragma unroll
        for (int i = 0; i < 4; i++)
#pragma unroll
            for (int j = 0; j < 4; j++)
                acc[i][j] = __builtin_amdgcn_mfma_f32_16x16x32_bf16(af[i], wf[j], acc[i][j], 0, 0, 0);
        __syncthreads();
    }

    // epilogue: C/D layout col=lane&15, row=quad*4+reg
#pragma unroll
    for (int i = 0; i < 4; i++) {
#pragma unroll
        for (int j = 0; j < 4; j++) {
            int cc = ntile + wn + j * 16 + r;
            if (cc >= N) continue;
#pragma unroll
            for (int reg = 0; reg < 4; reg++) {
                int rr = mtile + wm + i * 16 + quad * 4 + reg;
                int orow = FLIP_C ? (rr ^ 4095) : rr;
                float v = acc[i][j][reg];
                if (ADD_BIAS) v += bias[cc];
                if (OUT_F32) {
                    float* p = (float*)Cout + (size_t)orow * ldc + col_ofs + cc;
                    if (ACCUM) v += *p;
                    *p = v;
                } else {
                    ((unsigned short*)Cout)[(size_t)orow * ldc + col_ofs + cc] = f2bf(v);
                }
            }
        }
    }
}

// ---------------------------------------------------------------------------
// E[dir][n][k] = sum_j proj_w[n][dir*512+j] * out_proj_dir[j][k]
// Register-tiled: each block computes 4 n-rows x 1024 k (fp32 accum, bf16 out).
// n0 is blockIdx-only (wave-uniform) -> proj_w row reads become s_loads.
// Each out_proj float4 load feeds 16 FMAs (4 rows x 4 lanes-of-quad).
// grid: (128, 2)  -> 256 blocks = 1/CU.
// ---------------------------------------------------------------------------
__global__ __launch_bounds__(256) void eprep2_k(
    const float* __restrict__ pw,    // 512 x 1024 fp32
    const float* __restrict__ op0,   // 512 x 1024 fp32
    const float* __restrict__ op1,   // 512 x 1024 fp32
    unsigned short* __restrict__ E)  // [2][512][1024] bf16 (Ef then Eb)
{
    const int dir = blockIdx.y;
    const int n0  = blockIdx.x << 2;         // 4 rows per block, uniform
    const int k4  = threadIdx.x;             // float4 column group
    const float* op  = dir ? op1 : op0;
    const float* pwr = pw + (size_t)n0 * 1024 + (dir ? 512 : 0);
    const float* opc = op + (k4 << 2);

    float acc[4][4] = {};
#pragma unroll 8
    for (int j = 0; j < 512; j++) {
        f32x4_t o = *(const f32x4_t*)(opc + ((size_t)j << 10));
        float w0 = pwr[j];
        float w1 = pwr[1024 + j];
        float w2 = pwr[2048 + j];
        float w3 = pwr[3072 + j];
#pragma unroll
        for (int q = 0; q < 4; q++) {
            acc[0][q] = fmaf(w0, o[q], acc[0][q]);
            acc[1][q] = fmaf(w1, o[q], acc[1][q]);
            acc[2][q] = fmaf(w2, o[q], acc[2][q]);
            acc[3][q] = fmaf(w3, o[q], acc[3][q]);
        }
    }

    unsigned short* Ed = E + (size_t)dir * 512 * 1024;
#pragma unroll
    for (int i = 0; i < 4; i++) {
        u16x4_t e;
#pragma unroll
        for (int q = 0; q < 4; q++) e[q] = f2bf(acc[i][q]);
        *(u16x4_t*)(Ed + (size_t)(n0 + i) * 1024 + (k4 << 2)) = e;
    }
}

// ---------------------------------------------------------------------------
// Depthwise causal conv (width 4) + SiLU, 8 rows/thread sliding window.
// thread: c8 = t%132 (8 channels), rb = t/132 (8 rows rb*8..rb*8+7)
// ---------------------------------------------------------------------------
__global__ __launch_bounds__(256) void conv_silu_k(
    const unsigned short* __restrict__ xin,  // R x 1072 bf16
    const float* __restrict__ cw,            // 1056 x 4 fp32
    const float* __restrict__ cb,            // 1056 fp32
    unsigned short* __restrict__ outp)       // R x 1056 bf16
{
    int t = blockIdx.x * 256 + threadIdx.x;
    int c8 = t % 132;
    int rb = t / 132;
    int c = c8 * 8;
    int row0 = rb * 8;
    int l0 = row0 & 4095;

    float w[8][4];
#pragma unroll
    for (int j = 0; j < 8; j++) {
        f32x4_t wv = *(const f32x4_t*)(cw + (c + j) * 4);
        w[j][0] = wv[0]; w[j][1] = wv[1]; w[j][2] = wv[2]; w[j][3] = wv[3];
    }
    float bia[8];
    {
        f32x4_t b0 = *(const f32x4_t*)(cb + c);
        f32x4_t b1 = *(const f32x4_t*)(cb + c + 4);
#pragma unroll
        for (int j = 0; j < 4; j++) { bia[j] = b0[j]; bia[4 + j] = b1[j]; }
    }

    u16x8_t zero;
#pragma unroll
    for (int j = 0; j < 8; j++) zero[j] = 0;

    // window rows row0-3 .. row0+7 (11 rows); pre-batch rows are zero
    u16x8_t win[11];
#pragma unroll
    for (int u = 0; u < 11; u++) {
        int lu = l0 - 3 + u;
        win[u] = (lu >= 0)
            ? *(const u16x8_t*)(xin + (size_t)(row0 - 3 + u) * 1072 + c)
            : zero;
    }

#pragma unroll
    for (int s = 0; s < 8; s++) {
        float acc[8];
#pragma unroll
        for (int j = 0; j < 8; j++) acc[j] = bia[j];
#pragma unroll
        for (int k = 0; k < 4; k++) {
            u16x8_t xv = win[s + k];
#pragma unroll
            for (int j = 0; j < 8; j++)
                acc[j] = fmaf(bf2f(xv[j]), w[j][k], acc[j]);
        }
        u16x8_t o;
#pragma unroll
        for (int j = 0; j < 8; j++) {
            float xx = acc[j];
            o[j] = f2bf(xx * __builtin_amdgcn_rcpf(1.f + __expf(-xx)));
        }
        *(u16x8_t*)(outp + (size_t)(row0 + s) * 1056 + c) = o;
    }
}

// ---------------------------------------------------------------------------
// dt = softplus(dt_raw + dt_bias), dA = exp(dt * -exp(A_log))  (fp32 params)
// ---------------------------------------------------------------------------
__global__ __launch_bounds__(256) void dt_pre_k(
    const unsigned short* __restrict__ xin,  // R x 1072 bf16 (dt raw at 1056..1071)
    const float* __restrict__ dt_bias,
    const float* __restrict__ A_log,
    float* __restrict__ dtb, float* __restrict__ dab)
{
    int t = blockIdx.x * 256 + threadIdx.x;  // R*16
    int h = t & 15;
    int row = t >> 4;
    float x = bf2f(xin[(size_t)row * 1072 + 1056 + h]) + dt_bias[h];
    float dt = (x > 20.f) ? x : log1pf(__expf(x));
    float A = -__expf(A_log[h]);
    dtb[t] = dt;
    dab[t] = __expf(dt * A);
}

// ---------------------------------------------------------------------------
// Chunked scan, chunk=64. xconv row: [0,1024)=x heads, [1024,1040)=B, [1040,1056)=C
// ---------------------------------------------------------------------------
__global__ __launch_bounds__(64) void scan_state_k(
    const unsigned short* __restrict__ xc,
    const float* __restrict__ dtb, const float* __restrict__ dab,
    float* __restrict__ Hend, float* __restrict__ dec)
{
    int blk = blockIdx.x;
    int chunk = blk & 63;
    int bh = blk >> 6;
    int h = bh & 15, b = bh >> 4;
    int p = threadIdx.x;
    float hs[16];
#pragma unroll
    for (int n = 0; n < 16; n++) hs[n] = 0.f;
    float decay = 1.f;
    int row0 = b * 4096 + chunk * 64;
#pragma unroll 2
    for (int t = 0; t < 64; t++) {
        int row = row0 + t;
        const unsigned short* xr = xc + (size_t)row * 1056;
        float xp = bf2f(xr[h * 64 + p]);
        u16x8_t b0 = *(const u16x8_t*)(xr + 1024);
        u16x8_t b1 = *(const u16x8_t*)(xr + 1032);
        float dt = dtb[row * 16 + h];
        float dA = dab[row * 16 + h];
        float coef = dt * xp;
#pragma unroll
        for (int n = 0; n < 8; n++) hs[n] = fmaf(hs[n], dA, coef * bf2f(b0[n]));
#pragma unroll
        for (int n = 0; n < 8; n++) hs[8 + n] = fmaf(hs[8 + n], dA, coef * bf2f(b1[n]));
        decay *= dA;
    }
    float* o = Hend + (size_t)blk * 1024 + p * 16;
#pragma unroll
    for (int n = 0; n < 16; n++) o[n] = hs[n];
    if (p == 0) dec[blk] = decay;
}

__global__ __launch_bounds__(64) void scan_comb_k(float* __restrict__ H, const float* __restrict__ dec)
{
    int bh = blockIdx.x;
    int p = threadIdx.x;
    float hs[16];
#pragma unroll
    for (int n = 0; n < 16; n++) hs[n] = 0.f;
    for (int c = 0; c < 64; c++) {
        float* ptr = H + (size_t)(bh * 64 + c) * 1024 + p * 16;
        float tmp[16];
#pragma unroll
        for (int n = 0; n < 16; n++) tmp[n] = ptr[n];
        float d = dec[bh * 64 + c];
#pragma unroll
        for (int n = 0; n < 16; n++) { ptr[n] = hs[n]; hs[n] = fmaf(hs[n], d, tmp[n]); }
    }
}

__global__ __launch_bounds__(64) void scan_out_k(
    const unsigned short* __restrict__ xc,
    const float* __restrict__ dtb, const float* __restrict__ dab,
    const float* __restrict__ Hst,
    const float* __restrict__ Dp,
    unsigned short* __restrict__ ybuf)  // R x 1024 bf16
{
    int blk = blockIdx.x;
    int chunk = blk & 63;
    int bh = blk >> 6;
    int h = bh & 15, b = bh >> 4;
    int p = threadIdx.x;
    float hs[16];
    const float* hi = Hst + (size_t)blk * 1024 + p * 16;
#pragma unroll
    for (int n = 0; n < 16; n++) hs[n] = hi[n];
    float Dh = Dp[h];
    int row0 = b * 4096 + chunk * 64;
#pragma unroll 2
    for (int t = 0; t < 64; t++) {
        int row = row0 + t;
        const unsigned short* xr = xc + (size_t)row * 1056;
        float xp = bf2f(xr[h * 64 + p]);
        u16x8_t b0 = *(const u16x8_t*)(xr + 1024);
        u16x8_t b1 = *(const u16x8_t*)(xr + 1032);
        u16x8_t c0 = *(const u16x8_t*)(xr + 1040);
        u16x8_t c1 = *(const u16x8_t*)(xr + 1048);
        float dt = dtb[row * 16 + h];
        float dA = dab[row * 16 + h];
        float coef = dt * xp;
        float yp = 0.f;
#pragma unroll
        for (int n = 0; n < 8; n++) {
            hs[n] = fmaf(hs[n], dA, coef * bf2f(b0[n]));
            yp = fmaf(hs[n], bf2f(c0[n]), yp);
        }
#pragma unroll
        for (int n = 0; n < 8; n++) {
            hs[8 + n] = fmaf(hs[8 + n], dA, coef * bf2f(b1[n]));
            yp = fmaf(hs[8 + n], bf2f(c1[n]), yp);
        }
        yp = fmaf(Dh, xp, yp);
        ybuf[(size_t)row * 1024 + h * 64 + p] = f2bf(yp);
    }
}

// ---------------------------------------------------------------------------
// Gated RMSNorm (in-place on y, bf16): norm_w fp32
// ---------------------------------------------------------------------------
__global__ __launch_bounds__(256) void rmsgate_k(
    unsigned short* __restrict__ y,
    const unsigned short* __restrict__ z,
    const float* __restrict__ nw)
{
    __shared__ float sred[256];
    int row = blockIdx.x;
    int t = threadIdx.x;
    int c = t * 4;
    u16x4_t yv = *(const u16x4_t*)(y + (size_t)row * 1024 + c);
    u16x4_t zv = *(const u16x4_t*)(z + (size_t)row * 1024 + c);
    float g[4];
    float ss = 0.f;
#pragma unroll
    for (int j = 0; j < 4; j++) {
        float zf = bf2f(zv[j]);
        float sil = zf * __builtin_amdgcn_rcpf(1.f + __expf(-zf));
        g[j] = bf2f(yv[j]) * sil;
        ss += g[j] * g[j];
    }
    sred[t] = ss;
    __syncthreads();
#pragma unroll
    for (int s = 128; s > 0; s >>= 1) {
        if (t < s) sred[t] += sred[t + s];
        __syncthreads();
    }
    float scale = rsqrtf(sred[0] * (1.f / 1024.f) + 1e-5f);
    u16x4_t o4;
#pragma unroll
    for (int j = 0; j < 4; j++) o4[j] = f2bf(g[j] * scale * nw[c + j]);
    *(u16x4_t*)(y + (size_t)row * 1024 + c) = o4;
}

// ---------------------------------------------------------------------------
// Final: out = LayerNorm(x + f)  — all fp32 I/O
// ---------------------------------------------------------------------------
__global__ __launch_bounds__(128) void ln_k(
    const float* __restrict__ x,   // R x 512 fp32
    const float* __restrict__ f,   // R x 512 fp32
    const float* __restrict__ lw,
    const float* __restrict__ lb,
    float* __restrict__ outp)      // R x 512 fp32
{
    __shared__ float sA[128], sB[128];
    int row = blockIdx.x;
    int t = threadIdx.x;
    int c = t * 4;
    float s[4];
    float sum = 0.f, sq = 0.f;
    f32x4_t xv = *(const f32x4_t*)(x + (size_t)row * 512 + c);
    f32x4_t fv = *(const f32x4_t*)(f + (size_t)row * 512 + c);
#pragma unroll
    for (int j = 0; j < 4; j++) {
        s[j] = xv[j] + fv[j];
        sum += s[j];
        sq += s[j] * s[j];
    }
    sA[t] = sum; sB[t] = sq;
    __syncthreads();
#pragma unroll
    for (int st = 64; st > 0; st >>= 1) {
        if (t < st) { sA[t] += sA[t + st]; sB[t] += sB[t + st]; }
        __syncthreads();
    }
    float mu = sA[0] * (1.f / 512.f);
    float var = sB[0] * (1.f / 512.f) - mu * mu;
    if (var < 0.f) var = 0.f;
    float inv = rsqrtf(var + 1e-5f);
    f32x4_t o4;
#pragma unroll
    for (int j = 0; j < 4; j++)
        o4[j] = (s[j] - mu) * inv * lw[c + j] + lb[c + j];
    *(f32x4_t*)(outp + (size_t)row * 512 + c) = o4;
}

// ---------------------------------------------------------------------------
extern "C" void kernel_launch(void* const* d_in, const int* in_sizes, int n_in,
                              void* d_out, int out_size, void* d_ws, size_t ws_size,
                              hipStream_t stream)
{
    (void)in_sizes; (void)n_in; (void)out_size;

    const float* x           = (const float*)d_in[0];
    const float* in_proj[2]  = {(const float*)d_in[1],  (const float*)d_in[9]};
    const float* conv_w[2]   = {(const float*)d_in[2],  (const float*)d_in[10]};
    const float* conv_b[2]   = {(const float*)d_in[3],  (const float*)d_in[11]};
    const float* dt_bias[2]  = {(const float*)d_in[4],  (const float*)d_in[12]};
    const float* A_log[2]    = {(const float*)d_in[5],  (const float*)d_in[13]};
    const float* Dp[2]       = {(const float*)d_in[6],  (const float*)d_in[14]};
    const float* norm_w[2]   = {(const float*)d_in[7],  (const float*)d_in[15]};
    const float* out_proj[2] = {(const float*)d_in[8],  (const float*)d_in[16]};
    const float* proj_w      = (const float*)d_in[17];
    const float* proj_b      = (const float*)d_in[18];
    const float* ln_w        = (const float*)d_in[19];
    const float* ln_b        = (const float*)d_in[20];
    float* outp = (float*)d_out;

    const size_t IP_ELEMS = (size_t)2096 * 512;
    const size_t X_ELEMS  = (size_t)32768 * 512;

    const size_t constBytes = X_ELEMS * 2 + 2 * IP_ELEMS * 2 + 2 * 512 * 1024 * 2 + 4096;
    int g = 1;
    {
        const int cands[3] = {8, 4, 2};
        for (int ci = 0; ci < 3; ci++) {
            size_t R = (size_t)cands[ci] * 4096;
            size_t need = constBytes + R * (2144 + 2112 + 2048 + 64 + 64 + 1024)
                        + (size_t)cands[ci] * 1024 * 4 + 16 * 256;
            if (need <= ws_size) { g = cands[ci]; break; }
        }
    }
    const size_t R = (size_t)g * 4096;
    const int nGroups = 8 / g;
    const int MT = (int)(R >> 7);

    char* ws = (char*)d_ws;
    size_t off = 0;
    auto alloc = [&](size_t bytes) -> char* {
        char* p = ws + off;
        off += (bytes + 255) & ~(size_t)255;
        return p;
    };
    unsigned short* xb16  = (unsigned short*)alloc(X_ELEMS * 2);
    unsigned short* ipb16[2];
    ipb16[0] = (unsigned short*)alloc(IP_ELEMS * 2);
    ipb16[1] = (unsigned short*)alloc(IP_ELEMS * 2);
    unsigned short* Ebuf  = (unsigned short*)alloc(2 * 512 * 1024 * 2);
    unsigned short* Ef    = Ebuf;
    unsigned short* Eb    = Ebuf + 512 * 1024;
    unsigned short* xbcdt = (unsigned short*)alloc(R * 1072 * 2);
    unsigned short* ybuf  = xbcdt;                       // alias (xbcdt dead by scan_out)
    unsigned short* xconv = (unsigned short*)alloc(R * 1056 * 2);
    unsigned short* zbuf  = xconv;                       // alias (xconv dead after scans)
    float* fbuf = (float*)alloc(R * 512 * 4);
    float* dtb  = (float*)alloc(R * 16 * 4);
    float* dab  = (float*)alloc(R * 16 * 4);
    float* Hbuf = (float*)alloc(R * 1024);
    float* dec  = (float*)alloc((size_t)g * 1024 * 4);

    dim3 blk(256);

    cvt_k<<<(unsigned)((X_ELEMS / 8 + 255) / 256), blk, 0, stream>>>(x, xb16, (int)(X_ELEMS / 8));
    cvt_k<<<(unsigned)((IP_ELEMS / 8 + 255) / 256), blk, 0, stream>>>(in_proj[0], ipb16[0], (int)(IP_ELEMS / 8));
    cvt_k<<<(unsigned)((IP_ELEMS / 8 + 255) / 256), blk, 0, stream>>>(in_proj[1], ipb16[1], (int)(IP_ELEMS / 8));
    eprep2_k<<<dim3(128, 2), blk, 0, stream>>>(proj_w, out_proj[0], out_proj[1], Ebuf);

    for (int grp = 0; grp < nGroups; grp++) {
        const unsigned short* xg = xb16 + (size_t)grp * R * 512;
        const float* xgf = x + (size_t)grp * R * 512;
        float* og = outp + (size_t)grp * R * 512;

        for (int dir = 0; dir < 2; dir++) {
            if (dir == 0)
                gemm_bt<false, false, false, false, false><<<dim3(9, MT), blk, 0, stream>>>(
                    xg, ipb16[0] + (size_t)1024 * 512, xbcdt, nullptr, 1072, 512, 1072, 0);
            else
                gemm_bt<true, false, false, false, false><<<dim3(9, MT), blk, 0, stream>>>(
                    xg, ipb16[1] + (size_t)1024 * 512, xbcdt, nullptr, 1072, 512, 1072, 0);

            conv_silu_k<<<(unsigned)(R * 132 / 2048), blk, 0, stream>>>(xbcdt, conv_w[dir], conv_b[dir], xconv);
            dt_pre_k<<<(unsigned)(R * 16 / 256), blk, 0, stream>>>(xbcdt, dt_bias[dir], A_log[dir], dtb, dab);

            scan_state_k<<<(unsigned)(R / 4), dim3(64), 0, stream>>>(xconv, dtb, dab, Hbuf, dec);
            scan_comb_k<<<(unsigned)(g * 16), dim3(64), 0, stream>>>(Hbuf, dec);
            scan_out_k<<<(unsigned)(R / 4), dim3(64), 0, stream>>>(xconv, dtb, dab, Hbuf, Dp[dir], ybuf);

            if (dir == 0)
                gemm_bt<false, false, false, false, false><<<dim3(8, MT), blk, 0, stream>>>(
                    xg, ipb16[0], zbuf, nullptr, 1024, 512, 1024, 0);
            else
                gemm_bt<true, false, false, false, false><<<dim3(8, MT), blk, 0, stream>>>(
                    xg, ipb16[1], zbuf, nullptr, 1024, 512, 1024, 0);

            rmsgate_k<<<(unsigned)R, blk, 0, stream>>>(ybuf, zbuf, norm_w[dir]);

            if (dir == 0)
                gemm_bt<false, false, true, true, false><<<dim3(4, MT), blk, 0, stream>>>(
                    ybuf, Ef, fbuf, proj_b, 512, 1024, 512, 0);
            else
                gemm_bt<false, true, true, false, true><<<dim3(4, MT), blk, 0, stream>>>(
                    ybuf, Eb, fbuf, nullptr, 512, 1024, 512, 0);
        }
        ln_k<<<(unsigned)R, dim3(128), 0, stream>>>(xgf, fbuf, ln_w, ln_b, og);
    }
}

// Round 2
// 1131.543 us; speedup vs baseline: 1.1379x; 1.0469x over previous
//
#include <hip/hip_runtime.h>
#include <hip/hip_bf16.h>
#include <math.h>

typedef __bf16 bf16x8_t __attribute__((ext_vector_type(8)));
typedef float f32x4_t __attribute__((ext_vector_type(4)));
typedef unsigned short u16x8_t __attribute__((ext_vector_type(8)));
typedef unsigned short u16x4_t __attribute__((ext_vector_type(4)));

#define DEV __device__ __forceinline__

DEV float bf2f(unsigned short u) {
    unsigned int v = ((unsigned int)u) << 16;
    return __builtin_bit_cast(float, v);
}
DEV unsigned short f2bf(float f) {
    unsigned int u = __builtin_bit_cast(unsigned int, f);
    u += 0x7fffu + ((u >> 16) & 1u);   // RNE
    return (unsigned short)(u >> 16);
}

// ---------------------------------------------------------------------------
// fp32 -> bf16 conversion (8 elems/thread)
// ---------------------------------------------------------------------------
__global__ __launch_bounds__(256) void cvt_k(
    const float* __restrict__ in, unsigned short* __restrict__ out, int n8)
{
    int t = blockIdx.x * 256 + threadIdx.x;
    if (t >= n8) return;
    f32x4_t a = ((const f32x4_t*)in)[t * 2];
    f32x4_t b = ((const f32x4_t*)in)[t * 2 + 1];
    u16x8_t o;
#pragma unroll
    for (int j = 0; j < 4; j++) { o[j] = f2bf(a[j]); o[4 + j] = f2bf(b[j]); }
    ((u16x8_t*)out)[t] = o;
}

// ---------------------------------------------------------------------------
// MFMA GEMM:  C[M x N] = A'[M x K] @ W[N x K]^T   (bf16 in, fp32 accum)
// 128x128 tile, BK=32, global_load_lds width-16 staging, XOR-swizzled chunks.
// ---------------------------------------------------------------------------
template <bool FLIP_A, bool FLIP_C, bool OUT_F32, bool ADD_BIAS, bool ACCUM>
__global__ __launch_bounds__(256, 2) void gemm_bt(
    const unsigned short* __restrict__ A,
    const unsigned short* __restrict__ W,
    void* __restrict__ Cout,
    const float* __restrict__ bias,
    int N, int K, int ldc, int col_ofs)
{
    __shared__ __attribute__((aligned(16))) unsigned char smem[16384]; // A: 8KB, W: 8KB
    const int tid  = threadIdx.x;
    const int wave = tid >> 6;
    const int lane = tid & 63;
    const int mtile = blockIdx.y << 7;
    const int ntile = blockIdx.x << 7;

    const int c0 = tid, c1 = 256 + tid;
    const int r0 = c0 >> 2, p0 = c0 & 3, g0 = p0 ^ ((r0 >> 1) & 3);
    const int r1 = c1 >> 2, p1 = c1 & 3, g1 = p1 ^ ((r1 >> 1) & 3);

    int am0 = mtile + r0; if (FLIP_A) am0 ^= 4095;
    int am1 = mtile + r1; if (FLIP_A) am1 ^= 4095;
    const unsigned short* aP0 = A + (size_t)am0 * K + g0 * 8;
    const unsigned short* aP1 = A + (size_t)am1 * K + g1 * 8;

    int wr0 = ntile + r0; if (wr0 > N - 1) wr0 = N - 1;
    int wr1 = ntile + r1; if (wr1 > N - 1) wr1 = N - 1;
    const unsigned short* wP0 = W + (size_t)wr0 * K + g0 * 8;
    const unsigned short* wP1 = W + (size_t)wr1 * K + g1 * 8;

    unsigned char* ldsA = smem;
    unsigned char* ldsW = smem + 8192;
    unsigned char* ldsA0 = ldsA + wave * 1024;          // wave-uniform bases
    unsigned char* ldsA1 = ldsA + 4096 + wave * 1024;
    unsigned char* ldsW0 = ldsW + wave * 1024;
    unsigned char* ldsW1 = ldsW + 4096 + wave * 1024;

    f32x4_t acc[4][4] = {};

    const int wm = (wave & 1) << 6;
    const int wn = (wave >> 1) << 6;
    const int r    = lane & 15;
    const int quad = lane >> 4;
    const int sw   = (r >> 1) & 3;

    int aoff[4], woff[4];
#pragma unroll
    for (int i = 0; i < 4; i++) {
        int m = wm + i * 16 + r;
        aoff[i] = (m * 4 + (quad ^ sw)) * 16;
        int n = wn + i * 16 + r;
        woff[i] = (n * 4 + (quad ^ sw)) * 16;
    }

    for (int k0 = 0; k0 < K; k0 += 32) {
        __builtin_amdgcn_global_load_lds(
            (const __attribute__((address_space(1))) void*)(aP0 + k0),
            (__attribute__((address_space(3))) void*)ldsA0, 16, 0, 0);
        __builtin_amdgcn_global_load_lds(
            (const __attribute__((address_space(1))) void*)(aP1 + k0),
            (__attribute__((address_space(3))) void*)ldsA1, 16, 0, 0);
        __builtin_amdgcn_global_load_lds(
            (const __attribute__((address_space(1))) void*)(wP0 + k0),
            (__attribute__((address_space(3))) void*)ldsW0, 16, 0, 0);
        __builtin_amdgcn_global_load_lds(
            (const __attribute__((address_space(1))) void*)(wP1 + k0),
            (__attribute__((address_space(3))) void*)ldsW1, 16, 0, 0);
        __syncthreads();

        bf16x8_t af[4], wf[4];
#pragma unroll
        for (int i = 0; i < 4; i++)
            af[i] = __builtin_bit_cast(bf16x8_t, *(const u16x8_t*)(ldsA + aoff[i]));
#pragma unroll
        for (int j = 0; j < 4; j++)
            wf[j] = __builtin_bit_cast(bf16x8_t, *(const u16x8_t*)(ldsW + woff[j]));
#pragma unroll
        for (int i = 0; i < 4; i++)
#pragma unroll
            for (int j = 0; j < 4; j++)
                acc[i][j] = __builtin_amdgcn_mfma_f32_16x16x32_bf16(af[i], wf[j], acc[i][j], 0, 0, 0);
        __syncthreads();
    }

    // epilogue: C/D layout col=lane&15, row=quad*4+reg
#pragma unroll
    for (int i = 0; i < 4; i++) {
#pragma unroll
        for (int j = 0; j < 4; j++) {
            int cc = ntile + wn + j * 16 + r;
            if (cc >= N) continue;
#pragma unroll
            for (int reg = 0; reg < 4; reg++) {
                int rr = mtile + wm + i * 16 + quad * 4 + reg;
                int orow = FLIP_C ? (rr ^ 4095) : rr;
                float v = acc[i][j][reg];
                if (ADD_BIAS) v += bias[cc];
                if (OUT_F32) {
                    float* p = (float*)Cout + (size_t)orow * ldc + col_ofs + cc;
                    if (ACCUM) v += *p;
                    *p = v;
                } else {
                    ((unsigned short*)Cout)[(size_t)orow * ldc + col_ofs + cc] = f2bf(v);
                }
            }
        }
    }
}

// ---------------------------------------------------------------------------
// E[dir][n][k] = sum_j proj_w[n][dir*512+j] * out_proj_dir[j][k]
// Register-tiled: 4 n-rows x 1024 k per block.
// ---------------------------------------------------------------------------
__global__ __launch_bounds__(256) void eprep2_k(
    const float* __restrict__ pw,    // 512 x 1024 fp32
    const float* __restrict__ op0,   // 512 x 1024 fp32
    const float* __restrict__ op1,   // 512 x 1024 fp32
    unsigned short* __restrict__ E)  // [2][512][1024] bf16 (Ef then Eb)
{
    const int dir = blockIdx.y;
    const int n0  = blockIdx.x << 2;         // 4 rows per block, uniform
    const int k4  = threadIdx.x;             // float4 column group
    const float* op  = dir ? op1 : op0;
    const float* pwr = pw + (size_t)n0 * 1024 + (dir ? 512 : 0);
    const float* opc = op + (k4 << 2);

    float acc[4][4] = {};
#pragma unroll 8
    for (int j = 0; j < 512; j++) {
        f32x4_t o = *(const f32x4_t*)(opc + ((size_t)j << 10));
        float w0 = pwr[j];
        float w1 = pwr[1024 + j];
        float w2 = pwr[2048 + j];
        float w3 = pwr[3072 + j];
#pragma unroll
        for (int q = 0; q < 4; q++) {
            acc[0][q] = fmaf(w0, o[q], acc[0][q]);
            acc[1][q] = fmaf(w1, o[q], acc[1][q]);
            acc[2][q] = fmaf(w2, o[q], acc[2][q]);
            acc[3][q] = fmaf(w3, o[q], acc[3][q]);
        }
    }

    unsigned short* Ed = E + (size_t)dir * 512 * 1024;
#pragma unroll
    for (int i = 0; i < 4; i++) {
        u16x4_t e;
#pragma unroll
        for (int q = 0; q < 4; q++) e[q] = f2bf(acc[i][q]);
        *(u16x4_t*)(Ed + (size_t)(n0 + i) * 1024 + (k4 << 2)) = e;
    }
}

// ---------------------------------------------------------------------------
// Depthwise causal conv (width 4) + SiLU, 8 rows/thread sliding window.
// ---------------------------------------------------------------------------
__global__ __launch_bounds__(256) void conv_silu_k(
    const unsigned short* __restrict__ xin,  // R x 1072 bf16
    const float* __restrict__ cw,            // 1056 x 4 fp32
    const float* __restrict__ cb,            // 1056 fp32
    unsigned short* __restrict__ outp)       // R x 1056 bf16
{
    int t = blockIdx.x * 256 + threadIdx.x;
    int c8 = t % 132;
    int rb = t / 132;
    int c = c8 * 8;
    int row0 = rb * 8;
    int l0 = row0 & 4095;

    float w[8][4];
#pragma unroll
    for (int j = 0; j < 8; j++) {
        f32x4_t wv = *(const f32x4_t*)(cw + (c + j) * 4);
        w[j][0] = wv[0]; w[j][1] = wv[1]; w[j][2] = wv[2]; w[j][3] = wv[3];
    }
    float bia[8];
    {
        f32x4_t b0 = *(const f32x4_t*)(cb + c);
        f32x4_t b1 = *(const f32x4_t*)(cb + c + 4);
#pragma unroll
        for (int j = 0; j < 4; j++) { bia[j] = b0[j]; bia[4 + j] = b1[j]; }
    }

    u16x8_t zero;
#pragma unroll
    for (int j = 0; j < 8; j++) zero[j] = 0;

    // window rows row0-3 .. row0+7 (11 rows); pre-batch rows are zero
    u16x8_t win[11];
#pragma unroll
    for (int u = 0; u < 11; u++) {
        int lu = l0 - 3 + u;
        win[u] = (lu >= 0)
            ? *(const u16x8_t*)(xin + (size_t)(row0 - 3 + u) * 1072 + c)
            : zero;
    }

#pragma unroll
    for (int s = 0; s < 8; s++) {
        float acc[8];
#pragma unroll
        for (int j = 0; j < 8; j++) acc[j] = bia[j];
#pragma unroll
        for (int k = 0; k < 4; k++) {
            u16x8_t xv = win[s + k];
#pragma unroll
            for (int j = 0; j < 8; j++)
                acc[j] = fmaf(bf2f(xv[j]), w[j][k], acc[j]);
        }
        u16x8_t o;
#pragma unroll
        for (int j = 0; j < 8; j++) {
            float xx = acc[j];
            o[j] = f2bf(xx * __builtin_amdgcn_rcpf(1.f + __expf(-xx)));
        }
        *(u16x8_t*)(outp + (size_t)(row0 + s) * 1056 + c) = o;
    }
}

// ---------------------------------------------------------------------------
// dt = softplus(dt_raw + dt_bias), dA = exp(dt * -exp(A_log))  (fp32 params)
// ---------------------------------------------------------------------------
__global__ __launch_bounds__(256) void dt_pre_k(
    const unsigned short* __restrict__ xin,  // R x 1072 bf16 (dt raw at 1056..1071)
    const float* __restrict__ dt_bias,
    const float* __restrict__ A_log,
    float* __restrict__ dtb, float* __restrict__ dab)
{
    int t = blockIdx.x * 256 + threadIdx.x;  // R*16
    int h = t & 15;
    int row = t >> 4;
    float x = bf2f(xin[(size_t)row * 1072 + 1056 + h]) + dt_bias[h];
    float dt = (x > 20.f) ? x : log1pf(__expf(x));
    float A = -__expf(A_log[h]);
    dtb[t] = dt;
    dab[t] = __expf(dt * A);
}

// ---------------------------------------------------------------------------
// Chunked scan, chunk=64. xconv row: [0,1024)=x heads, [1024,1040)=B, [1040,1056)=C
// 256-thread blocks = 4 independent chunk-waves; depth-2 register prefetch.
// ---------------------------------------------------------------------------
struct SR { unsigned short x; u16x8_t b0, b1; float dt, dA; };

DEV void load_sr(const unsigned short* xb, const float* dtp, const float* dap,
                 int t, int hp, SR& s)
{
    const unsigned short* xr = xb + (size_t)t * 1056;
    s.x  = xr[hp];
    s.b0 = *(const u16x8_t*)(xr + 1024);
    s.b1 = *(const u16x8_t*)(xr + 1032);
    s.dt = dtp[t * 16];
    s.dA = dap[t * 16];
}

DEV void state_step(float* hs, float& decay, const SR& s)
{
    float coef = s.dt * bf2f(s.x);
#pragma unroll
    for (int n = 0; n < 8; n++) hs[n] = fmaf(hs[n], s.dA, coef * bf2f(s.b0[n]));
#pragma unroll
    for (int n = 0; n < 8; n++) hs[8 + n] = fmaf(hs[8 + n], s.dA, coef * bf2f(s.b1[n]));
    decay *= s.dA;
}

__global__ __launch_bounds__(256) void scan_state_k(
    const unsigned short* __restrict__ xc,
    const float* __restrict__ dtb, const float* __restrict__ dab,
    float* __restrict__ Hend, float* __restrict__ dec)
{
    const int wave  = threadIdx.x >> 6;
    const int p     = threadIdx.x & 63;
    const int bh    = blockIdx.x >> 4;
    const int chunk = ((blockIdx.x & 15) << 2) | wave;
    const int h = bh & 15, b = bh >> 4;
    const int blk = (bh << 6) | chunk;
    const int row0 = b * 4096 + chunk * 64;
    const int hp = h * 64 + p;
    const unsigned short* xb = xc + (size_t)row0 * 1056;
    const float* dtp = dtb + (size_t)row0 * 16 + h;
    const float* dap = dab + (size_t)row0 * 16 + h;

    float hs[16];
#pragma unroll
    for (int n = 0; n < 16; n++) hs[n] = 0.f;
    float decay = 1.f;

    SR A, B, N, M;
    load_sr(xb, dtp, dap, 0, hp, A);
    load_sr(xb, dtp, dap, 1, hp, B);
    for (int t = 0; t < 64; t += 2) {
        int t2 = (t + 2 < 64) ? t + 2 : 62;
        int t3 = (t + 3 < 64) ? t + 3 : 63;
        load_sr(xb, dtp, dap, t2, hp, N);
        state_step(hs, decay, A);
        load_sr(xb, dtp, dap, t3, hp, M);
        state_step(hs, decay, B);
        A = N; B = M;
    }

    float* o = Hend + (size_t)blk * 1024 + p * 16;
#pragma unroll
    for (int n = 0; n < 16; n++) o[n] = hs[n];
    if (p == 0) dec[blk] = decay;
}

// ---------------------------------------------------------------------------
// Combine: exclusive prefix over 64 chunk states per (b,h).
// Split each (b,h) across 4 blocks (thread owns 4 states); next-chunk prefetch.
// ---------------------------------------------------------------------------
__global__ __launch_bounds__(64) void scan_comb_k(float* __restrict__ H, const float* __restrict__ dec)
{
    int bh = blockIdx.x >> 2;
    int q  = blockIdx.x & 3;
    int t  = threadIdx.x;
    float* base = H + (size_t)bh * 64 * 1024 + q * 256 + t * 4;
    const float* dp = dec + bh * 64;
    f32x4_t hs = {0.f, 0.f, 0.f, 0.f};
    f32x4_t cur = *(const f32x4_t*)base;
    for (int c = 0; c < 64; c++) {
        int cn = (c < 63) ? c + 1 : 63;
        f32x4_t nxt = *(const f32x4_t*)(base + (size_t)cn * 1024);
        float d = dp[c];
        *(f32x4_t*)(base + (size_t)c * 1024) = hs;   // exclusive prefix
#pragma unroll
        for (int j = 0; j < 4; j++) hs[j] = fmaf(hs[j], d, cur[j]);
        cur = nxt;
    }
}

// ---------------------------------------------------------------------------
struct ORow { unsigned short x; u16x8_t b0, b1, c0, c1; float dt, dA; };

DEV void load_or(const unsigned short* xb, const float* dtp, const float* dap,
                 int t, int hp, ORow& s)
{
    const unsigned short* xr = xb + (size_t)t * 1056;
    s.x  = xr[hp];
    s.b0 = *(const u16x8_t*)(xr + 1024);
    s.b1 = *(const u16x8_t*)(xr + 1032);
    s.c0 = *(const u16x8_t*)(xr + 1040);
    s.c1 = *(const u16x8_t*)(xr + 1048);
    s.dt = dtp[t * 16];
    s.dA = dap[t * 16];
}

DEV float out_step(float* hs, const ORow& s, float Dh)
{
    float xpf = bf2f(s.x);
    float coef = s.dt * xpf;
    float yp0 = 0.f, yp1 = 0.f, yp2 = 0.f, yp3 = 0.f;
#pragma unroll
    for (int n = 0; n < 4; n++) {
        hs[n] = fmaf(hs[n], s.dA, coef * bf2f(s.b0[n]));
        yp0 = fmaf(hs[n], bf2f(s.c0[n]), yp0);
    }
#pragma unroll
    for (int n = 4; n < 8; n++) {
        hs[n] = fmaf(hs[n], s.dA, coef * bf2f(s.b0[n]));
        yp1 = fmaf(hs[n], bf2f(s.c0[n]), yp1);
    }
#pragma unroll
    for (int n = 0; n < 4; n++) {
        hs[8 + n] = fmaf(hs[8 + n], s.dA, coef * bf2f(s.b1[n]));
        yp2 = fmaf(hs[8 + n], bf2f(s.c1[n]), yp2);
    }
#pragma unroll
    for (int n = 4; n < 8; n++) {
        hs[8 + n] = fmaf(hs[8 + n], s.dA, coef * bf2f(s.b1[n]));
        yp3 = fmaf(hs[8 + n], bf2f(s.c1[n]), yp3);
    }
    return fmaf(Dh, xpf, (yp0 + yp1) + (yp2 + yp3));
}

__global__ __launch_bounds__(256) void scan_out_k(
    const unsigned short* __restrict__ xc,
    const float* __restrict__ dtb, const float* __restrict__ dab,
    const float* __restrict__ Hst,
    const float* __restrict__ Dp,
    unsigned short* __restrict__ ybuf)  // R x 1024 bf16
{
    const int wave  = threadIdx.x >> 6;
    const int p     = threadIdx.x & 63;
    const int bh    = blockIdx.x >> 4;
    const int chunk = ((blockIdx.x & 15) << 2) | wave;
    const int h = bh & 15, b = bh >> 4;
    const int blk = (bh << 6) | chunk;
    const int row0 = b * 4096 + chunk * 64;
    const int hp = h * 64 + p;
    const unsigned short* xb = xc + (size_t)row0 * 1056;
    const float* dtp = dtb + (size_t)row0 * 16 + h;
    const float* dap = dab + (size_t)row0 * 16 + h;
    unsigned short* yb = ybuf + (size_t)row0 * 1024 + hp;

    float hs[16];
    const float* hi = Hst + (size_t)blk * 1024 + p * 16;
#pragma unroll
    for (int n = 0; n < 16; n++) hs[n] = hi[n];
    float Dh = Dp[h];

    ORow A, B, N, M;
    load_or(xb, dtp, dap, 0, hp, A);
    load_or(xb, dtp, dap, 1, hp, B);
    for (int t = 0; t < 64; t += 2) {
        int t2 = (t + 2 < 64) ? t + 2 : 62;
        int t3 = (t + 3 < 64) ? t + 3 : 63;
        load_or(xb, dtp, dap, t2, hp, N);
        float y0 = out_step(hs, A, Dh);
        yb[(size_t)t * 1024] = f2bf(y0);
        load_or(xb, dtp, dap, t3, hp, M);
        float y1 = out_step(hs, B, Dh);
        yb[(size_t)(t + 1) * 1024] = f2bf(y1);
        A = N; B = M;
    }
}

// ---------------------------------------------------------------------------
// Gated RMSNorm (in-place on y, bf16): norm_w fp32
// ---------------------------------------------------------------------------
__global__ __launch_bounds__(256) void rmsgate_k(
    unsigned short* __restrict__ y,
    const unsigned short* __restrict__ z,
    const float* __restrict__ nw)
{
    __shared__ float sred[256];
    int row = blockIdx.x;
    int t = threadIdx.x;
    int c = t * 4;
    u16x4_t yv = *(const u16x4_t*)(y + (size_t)row * 1024 + c);
    u16x4_t zv = *(const u16x4_t*)(z + (size_t)row * 1024 + c);
    float g[4];
    float ss = 0.f;
#pragma unroll
    for (int j = 0; j < 4; j++) {
        float zf = bf2f(zv[j]);
        float sil = zf * __builtin_amdgcn_rcpf(1.f + __expf(-zf));
        g[j] = bf2f(yv[j]) * sil;
        ss += g[j] * g[j];
    }
    sred[t] = ss;
    __syncthreads();
#pragma unroll
    for (int s = 128; s > 0; s >>= 1) {
        if (t < s) sred[t] += sred[t + s];
        __syncthreads();
    }
    float scale = rsqrtf(sred[0] * (1.f / 1024.f) + 1e-5f);
    u16x4_t o4;
#pragma unroll
    for (int j = 0; j < 4; j++) o4[j] = f2bf(g[j] * scale * nw[c + j]);
    *(u16x4_t*)(y + (size_t)row * 1024 + c) = o4;
}

// ---------------------------------------------------------------------------
// Final: out = LayerNorm(x + f)  — all fp32 I/O
// ---------------------------------------------------------------------------
__global__ __launch_bounds__(128) void ln_k(
    const float* __restrict__ x,   // R x 512 fp32
    const float* __restrict__ f,   // R x 512 fp32
    const float* __restrict__ lw,
    const float* __restrict__ lb,
    float* __restrict__ outp)      // R x 512 fp32
{
    __shared__ float sA[128], sB[128];
    int row = blockIdx.x;
    int t = threadIdx.x;
    int c = t * 4;
    float s[4];
    float sum = 0.f, sq = 0.f;
    f32x4_t xv = *(const f32x4_t*)(x + (size_t)row * 512 + c);
    f32x4_t fv = *(const f32x4_t*)(f + (size_t)row * 512 + c);
#pragma unroll
    for (int j = 0; j < 4; j++) {
        s[j] = xv[j] + fv[j];
        sum += s[j];
        sq += s[j] * s[j];
    }
    sA[t] = sum; sB[t] = sq;
    __syncthreads();
#pragma unroll
    for (int st = 64; st > 0; st >>= 1) {
        if (t < st) { sA[t] += sA[t + st]; sB[t] += sB[t + st]; }
        __syncthreads();
    }
    float mu = sA[0] * (1.f / 512.f);
    float var = sB[0] * (1.f / 512.f) - mu * mu;
    if (var < 0.f) var = 0.f;
    float inv = rsqrtf(var + 1e-5f);
    f32x4_t o4;
#pragma unroll
    for (int j = 0; j < 4; j++)
        o4[j] = (s[j] - mu) * inv * lw[c + j] + lb[c + j];
    *(f32x4_t*)(outp + (size_t)row * 512 + c) = o4;
}

// ---------------------------------------------------------------------------
extern "C" void kernel_launch(void* const* d_in, const int* in_sizes, int n_in,
                              void* d_out, int out_size, void* d_ws, size_t ws_size,
                              hipStream_t stream)
{
    (void)in_sizes; (void)n_in; (void)out_size;

    const float* x           = (const float*)d_in[0];
    const float* in_proj[2]  = {(const float*)d_in[1],  (const float*)d_in[9]};
    const float* conv_w[2]   = {(const float*)d_in[2],  (const float*)d_in[10]};
    const float* conv_b[2]   = {(const float*)d_in[3],  (const float*)d_in[11]};
    const float* dt_bias[2]  = {(const float*)d_in[4],  (const float*)d_in[12]};
    const float* A_log[2]    = {(const float*)d_in[5],  (const float*)d_in[13]};
    const float* Dp[2]       = {(const float*)d_in[6],  (const float*)d_in[14]};
    const float* norm_w[2]   = {(const float*)d_in[7],  (const float*)d_in[15]};
    const float* out_proj[2] = {(const float*)d_in[8],  (const float*)d_in[16]};
    const float* proj_w      = (const float*)d_in[17];
    const float* proj_b      = (const float*)d_in[18];
    const float* ln_w        = (const float*)d_in[19];
    const float* ln_b        = (const float*)d_in[20];
    float* outp = (float*)d_out;

    const size_t IP_ELEMS = (size_t)2096 * 512;
    const size_t X_ELEMS  = (size_t)32768 * 512;

    const size_t constBytes = X_ELEMS * 2 + 2 * IP_ELEMS * 2 + 2 * 512 * 1024 * 2 + 4096;
    int g = 1;
    {
        const int cands[3] = {8, 4, 2};
        for (int ci = 0; ci < 3; ci++) {
            size_t R = (size_t)cands[ci] * 4096;
            size_t need = constBytes + R * (2144 + 2112 + 2048 + 64 + 64 + 1024)
                        + (size_t)cands[ci] * 1024 * 4 + 16 * 256;
            if (need <= ws_size) { g = cands[ci]; break; }
        }
    }
    const size_t R = (size_t)g * 4096;
    const int nGroups = 8 / g;
    const int MT = (int)(R >> 7);

    char* ws = (char*)d_ws;
    size_t off = 0;
    auto alloc = [&](size_t bytes) -> char* {
        char* p = ws + off;
        off += (bytes + 255) & ~(size_t)255;
        return p;
    };
    unsigned short* xb16  = (unsigned short*)alloc(X_ELEMS * 2);
    unsigned short* ipb16[2];
    ipb16[0] = (unsigned short*)alloc(IP_ELEMS * 2);
    ipb16[1] = (unsigned short*)alloc(IP_ELEMS * 2);
    unsigned short* Ebuf  = (unsigned short*)alloc(2 * 512 * 1024 * 2);
    unsigned short* Ef    = Ebuf;
    unsigned short* Eb    = Ebuf + 512 * 1024;
    unsigned short* xbcdt = (unsigned short*)alloc(R * 1072 * 2);
    unsigned short* ybuf  = xbcdt;                       // alias (xbcdt dead by scan_out)
    unsigned short* xconv = (unsigned short*)alloc(R * 1056 * 2);
    unsigned short* zbuf  = xconv;                       // alias (xconv dead after scans)
    float* fbuf = (float*)alloc(R * 512 * 4);
    float* dtb  = (float*)alloc(R * 16 * 4);
    float* dab  = (float*)alloc(R * 16 * 4);
    float* Hbuf = (float*)alloc(R * 1024);
    float* dec  = (float*)alloc((size_t)g * 1024 * 4);

    dim3 blk(256);

    cvt_k<<<(unsigned)((X_ELEMS / 8 + 255) / 256), blk, 0, stream>>>(x, xb16, (int)(X_ELEMS / 8));
    cvt_k<<<(unsigned)((IP_ELEMS / 8 + 255) / 256), blk, 0, stream>>>(in_proj[0], ipb16[0], (int)(IP_ELEMS / 8));
    cvt_k<<<(unsigned)((IP_ELEMS / 8 + 255) / 256), blk, 0, stream>>>(in_proj[1], ipb16[1], (int)(IP_ELEMS / 8));
    eprep2_k<<<dim3(128, 2), blk, 0, stream>>>(proj_w, out_proj[0], out_proj[1], Ebuf);

    for (int grp = 0; grp < nGroups; grp++) {
        const unsigned short* xg = xb16 + (size_t)grp * R * 512;
        const float* xgf = x + (size_t)grp * R * 512;
        float* og = outp + (size_t)grp * R * 512;

        for (int dir = 0; dir < 2; dir++) {
            if (dir == 0)
                gemm_bt<false, false, false, false, false><<<dim3(9, MT), blk, 0, stream>>>(
                    xg, ipb16[0] + (size_t)1024 * 512, xbcdt, nullptr, 1072, 512, 1072, 0);
            else
                gemm_bt<true, false, false, false, false><<<dim3(9, MT), blk, 0, stream>>>(
                    xg, ipb16[1] + (size_t)1024 * 512, xbcdt, nullptr, 1072, 512, 1072, 0);

            conv_silu_k<<<(unsigned)(R * 132 / 2048), blk, 0, stream>>>(xbcdt, conv_w[dir], conv_b[dir], xconv);
            dt_pre_k<<<(unsigned)(R * 16 / 256), blk, 0, stream>>>(xbcdt, dt_bias[dir], A_log[dir], dtb, dab);

            scan_state_k<<<(unsigned)(R / 16), blk, 0, stream>>>(xconv, dtb, dab, Hbuf, dec);
            scan_comb_k<<<(unsigned)(g * 64), dim3(64), 0, stream>>>(Hbuf, dec);
            scan_out_k<<<(unsigned)(R / 16), blk, 0, stream>>>(xconv, dtb, dab, Hbuf, Dp[dir], ybuf);

            if (dir == 0)
                gemm_bt<false, false, false, false, false><<<dim3(8, MT), blk, 0, stream>>>(
                    xg, ipb16[0], zbuf, nullptr, 1024, 512, 1024, 0);
            else
                gemm_bt<true, false, false, false, false><<<dim3(8, MT), blk, 0, stream>>>(
                    xg, ipb16[1], zbuf, nullptr, 1024, 512, 1024, 0);

            rmsgate_k<<<(unsigned)R, blk, 0, stream>>>(ybuf, zbuf, norm_w[dir]);

            if (dir == 0)
                gemm_bt<false, false, true, true, false><<<dim3(4, MT), blk, 0, stream>>>(
                    ybuf, Ef, fbuf, proj_b, 512, 1024, 512, 0);
            else
                gemm_bt<false, true, true, false, true><<<dim3(4, MT), blk, 0, stream>>>(
                    ybuf, Eb, fbuf, nullptr, 512, 1024, 512, 0);
        }
        ln_k<<<(unsigned)R, dim3(128), 0, stream>>>(xgf, fbuf, ln_w, ln_b, og);
    }
}

// Round 4
// 964.064 us; speedup vs baseline: 1.3356x; 1.1737x over previous
//
#include <hip/hip_runtime.h>
#include <hip/hip_bf16.h>
#include <math.h>

typedef __bf16 bf16x8_t __attribute__((ext_vector_type(8)));
typedef float f32x4_t __attribute__((ext_vector_type(4)));
typedef unsigned short u16x8_t __attribute__((ext_vector_type(8)));
typedef unsigned short u16x4_t __attribute__((ext_vector_type(4)));

#define DEV __device__ __forceinline__

DEV float bf2f(unsigned short u) {
    unsigned int v = ((unsigned int)u) << 16;
    return __builtin_bit_cast(float, v);
}
DEV unsigned short f2bf(float f) {
    unsigned int u = __builtin_bit_cast(unsigned int, f);
    u += 0x7fffu + ((u >> 16) & 1u);   // RNE
    return (unsigned short)(u >> 16);
}

// ---------------------------------------------------------------------------
// fp32 -> bf16 conversion (8 elems/thread)
// ---------------------------------------------------------------------------
__global__ __launch_bounds__(256) void cvt_k(
    const float* __restrict__ in, unsigned short* __restrict__ out, int n8)
{
    int t = blockIdx.x * 256 + threadIdx.x;
    if (t >= n8) return;
    f32x4_t a = ((const f32x4_t*)in)[t * 2];
    f32x4_t b = ((const f32x4_t*)in)[t * 2 + 1];
    u16x8_t o;
#pragma unroll
    for (int j = 0; j < 4; j++) { o[j] = f2bf(a[j]); o[4 + j] = f2bf(b[j]); }
    ((u16x8_t*)out)[t] = o;
}

// ---------------------------------------------------------------------------
// MFMA GEMM:  C[M x N] = A'[M x K] @ W[N x K]^T   (bf16 in, fp32 accum)
// 128x128 tile, BK=32, global_load_lds width-16 staging, XOR-swizzled chunks.
// ---------------------------------------------------------------------------
template <bool FLIP_A, bool FLIP_C, bool OUT_F32, bool ADD_BIAS, bool ACCUM>
__global__ __launch_bounds__(256, 2) void gemm_bt(
    const unsigned short* __restrict__ A,
    const unsigned short* __restrict__ W,
    void* __restrict__ Cout,
    const float* __restrict__ bias,
    int N, int K, int ldc, int col_ofs)
{
    __shared__ __attribute__((aligned(16))) unsigned char smem[16384]; // A: 8KB, W: 8KB
    const int tid  = threadIdx.x;
    const int wave = tid >> 6;
    const int lane = tid & 63;
    const int mtile = blockIdx.y << 7;
    const int ntile = blockIdx.x << 7;

    const int c0 = tid, c1 = 256 + tid;
    const int r0 = c0 >> 2, p0 = c0 & 3, g0 = p0 ^ ((r0 >> 1) & 3);
    const int r1 = c1 >> 2, p1 = c1 & 3, g1 = p1 ^ ((r1 >> 1) & 3);

    int am0 = mtile + r0; if (FLIP_A) am0 ^= 4095;
    int am1 = mtile + r1; if (FLIP_A) am1 ^= 4095;
    const unsigned short* aP0 = A + (size_t)am0 * K + g0 * 8;
    const unsigned short* aP1 = A + (size_t)am1 * K + g1 * 8;

    int wr0 = ntile + r0; if (wr0 > N - 1) wr0 = N - 1;
    int wr1 = ntile + r1; if (wr1 > N - 1) wr1 = N - 1;
    const unsigned short* wP0 = W + (size_t)wr0 * K + g0 * 8;
    const unsigned short* wP1 = W + (size_t)wr1 * K + g1 * 8;

    unsigned char* ldsA = smem;
    unsigned char* ldsW = smem + 8192;
    unsigned char* ldsA0 = ldsA + wave * 1024;          // wave-uniform bases
    unsigned char* ldsA1 = ldsA + 4096 + wave * 1024;
    unsigned char* ldsW0 = ldsW + wave * 1024;
    unsigned char* ldsW1 = ldsW + 4096 + wave * 1024;

    f32x4_t acc[4][4] = {};

    const int wm = (wave & 1) << 6;
    const int wn = (wave >> 1) << 6;
    const int r    = lane & 15;
    const int quad = lane >> 4;
    const int sw   = (r >> 1) & 3;

    int aoff[4], woff[4];
#pragma unroll
    for (int i = 0; i < 4; i++) {
        int m = wm + i * 16 + r;
        aoff[i] = (m * 4 + (quad ^ sw)) * 16;
        int n = wn + i * 16 + r;
        woff[i] = (n * 4 + (quad ^ sw)) * 16;
    }

    for (int k0 = 0; k0 < K; k0 += 32) {
        __builtin_amdgcn_global_load_lds(
            (const __attribute__((address_space(1))) void*)(aP0 + k0),
            (__attribute__((address_space(3))) void*)ldsA0, 16, 0, 0);
        __builtin_amdgcn_global_load_lds(
            (const __attribute__((address_space(1))) void*)(aP1 + k0),
            (__attribute__((address_space(3))) void*)ldsA1, 16, 0, 0);
        __builtin_amdgcn_global_load_lds(
            (const __attribute__((address_space(1))) void*)(wP0 + k0),
            (__attribute__((address_space(3))) void*)ldsW0, 16, 0, 0);
        __builtin_amdgcn_global_load_lds(
            (const __attribute__((address_space(1))) void*)(wP1 + k0),
            (__attribute__((address_space(3))) void*)ldsW1, 16, 0, 0);
        __syncthreads();

        bf16x8_t af[4], wf[4];
#pragma unroll
        for (int i = 0; i < 4; i++)
            af[i] = __builtin_bit_cast(bf16x8_t, *(const u16x8_t*)(ldsA + aoff[i]));
#pragma unroll
        for (int j = 0; j < 4; j++)
            wf[j] = __builtin_bit_cast(bf16x8_t, *(const u16x8_t*)(ldsW + woff[j]));
#pragma unroll
        for (int i = 0; i < 4; i++)
#pragma unroll
            for (int j = 0; j < 4; j++)
                acc[i][j] = __builtin_amdgcn_mfma_f32_16x16x32_bf16(af[i], wf[j], acc[i][j], 0, 0, 0);
        __syncthreads();
    }

    // epilogue: C/D layout col=lane&15, row=quad*4+reg
#pragma unroll
    for (int i = 0; i < 4; i++) {
#pragma unroll
        for (int j = 0; j < 4; j++) {
            int cc = ntile + wn + j * 16 + r;
            if (cc >= N) continue;
#pragma unroll
            for (int reg = 0; reg < 4; reg++) {
                int rr = mtile + wm + i * 16 + quad * 4 + reg;
                int orow = FLIP_C ? (rr ^ 4095) : rr;
                float v = acc[i][j][reg];
                if (ADD_BIAS) v += bias[cc];
                if (OUT_F32) {
                    float* p = (float*)Cout + (size_t)orow * ldc + col_ofs + cc;
                    if (ACCUM) v += *p;
                    *p = v;
                } else {
                    ((unsigned short*)Cout)[(size_t)orow * ldc + col_ofs + cc] = f2bf(v);
                }
            }
        }
    }
}

// ---------------------------------------------------------------------------
// E[dir][n][k] = sum_j proj_w[n][dir*512+j] * out_proj_dir[j][k]
// ---------------------------------------------------------------------------
__global__ __launch_bounds__(256) void eprep2_k(
    const float* __restrict__ pw,    // 512 x 1024 fp32
    const float* __restrict__ op0,   // 512 x 1024 fp32
    const float* __restrict__ op1,   // 512 x 1024 fp32
    unsigned short* __restrict__ E)  // [2][512][1024] bf16 (Ef then Eb)
{
    const int dir = blockIdx.y;
    const int n0  = blockIdx.x << 2;         // 4 rows per block, uniform
    const int k4  = threadIdx.x;             // float4 column group
    const float* op  = dir ? op1 : op0;
    const float* pwr = pw + (size_t)n0 * 1024 + (dir ? 512 : 0);
    const float* opc = op + (k4 << 2);

    float acc[4][4] = {};
#pragma unroll 8
    for (int j = 0; j < 512; j++) {
        f32x4_t o = *(const f32x4_t*)(opc + ((size_t)j << 10));
        float w0 = pwr[j];
        float w1 = pwr[1024 + j];
        float w2 = pwr[2048 + j];
        float w3 = pwr[3072 + j];
#pragma unroll
        for (int q = 0; q < 4; q++) {
            acc[0][q] = fmaf(w0, o[q], acc[0][q]);
            acc[1][q] = fmaf(w1, o[q], acc[1][q]);
            acc[2][q] = fmaf(w2, o[q], acc[2][q]);
            acc[3][q] = fmaf(w3, o[q], acc[3][q]);
        }
    }

    unsigned short* Ed = E + (size_t)dir * 512 * 1024;
#pragma unroll
    for (int i = 0; i < 4; i++) {
        u16x4_t e;
#pragma unroll
        for (int q = 0; q < 4; q++) e[q] = f2bf(acc[i][q]);
        *(u16x4_t*)(Ed + (size_t)(n0 + i) * 1024 + (k4 << 2)) = e;
    }
}

// ---------------------------------------------------------------------------
// Depthwise causal conv (width 4) + SiLU, 8 rows/thread sliding window.
// ---------------------------------------------------------------------------
__global__ __launch_bounds__(256) void conv_silu_k(
    const unsigned short* __restrict__ xin,  // R x 1072 bf16
    const float* __restrict__ cw,            // 1056 x 4 fp32
    const float* __restrict__ cb,            // 1056 fp32
    unsigned short* __restrict__ outp)       // R x 1056 bf16
{
    int t = blockIdx.x * 256 + threadIdx.x;
    int c8 = t % 132;
    int rb = t / 132;
    int c = c8 * 8;
    int row0 = rb * 8;
    int l0 = row0 & 4095;

    float w[8][4];
#pragma unroll
    for (int j = 0; j < 8; j++) {
        f32x4_t wv = *(const f32x4_t*)(cw + (c + j) * 4);
        w[j][0] = wv[0]; w[j][1] = wv[1]; w[j][2] = wv[2]; w[j][3] = wv[3];
    }
    float bia[8];
    {
        f32x4_t b0 = *(const f32x4_t*)(cb + c);
        f32x4_t b1 = *(const f32x4_t*)(cb + c + 4);
#pragma unroll
        for (int j = 0; j < 4; j++) { bia[j] = b0[j]; bia[4 + j] = b1[j]; }
    }

    u16x8_t zero;
#pragma unroll
    for (int j = 0; j < 8; j++) zero[j] = 0;

    // window rows row0-3 .. row0+7 (11 rows); pre-batch rows are zero
    u16x8_t win[11];
#pragma unroll
    for (int u = 0; u < 11; u++) {
        int lu = l0 - 3 + u;
        win[u] = (lu >= 0)
            ? *(const u16x8_t*)(xin + (size_t)(row0 - 3 + u) * 1072 + c)
            : zero;
    }

#pragma unroll
    for (int s = 0; s < 8; s++) {
        float acc[8];
#pragma unroll
        for (int j = 0; j < 8; j++) acc[j] = bia[j];
#pragma unroll
        for (int k = 0; k < 4; k++) {
            u16x8_t xv = win[s + k];
#pragma unroll
            for (int j = 0; j < 8; j++)
                acc[j] = fmaf(bf2f(xv[j]), w[j][k], acc[j]);
        }
        u16x8_t o;
#pragma unroll
        for (int j = 0; j < 8; j++) {
            float xx = acc[j];
            o[j] = f2bf(xx * __builtin_amdgcn_rcpf(1.f + __expf(-xx)));
        }
        *(u16x8_t*)(outp + (size_t)(row0 + s) * 1056 + c) = o;
    }
}

// ---------------------------------------------------------------------------
// dt = softplus(dt_raw + dt_bias), ldA = dt * -exp(A_log)  (log of dA)
// ---------------------------------------------------------------------------
__global__ __launch_bounds__(256) void dt_pre_k(
    const unsigned short* __restrict__ xin,  // R x 1072 bf16 (dt raw at 1056..1071)
    const float* __restrict__ dt_bias,
    const float* __restrict__ A_log,
    float* __restrict__ dtb, float* __restrict__ ldab)
{
    int t = blockIdx.x * 256 + threadIdx.x;  // R*16
    int h = t & 15;
    int row = t >> 4;
    float x = bf2f(xin[(size_t)row * 1072 + 1056 + h]) + dt_bias[h];
    float dt = (x > 20.f) ? x : log1pf(__expf(x));
    float A = -__expf(A_log[h]);
    dtb[t] = dt;
    ldab[t] = dt * A;       // log(dA); cumsum later (exact: dA = exp(dt*A))
}

// ---------------------------------------------------------------------------
// Chunked scan as MFMA GEMMs (Mamba2 SSD formulation), chunk = 64.
// Per (chunk, head): cs_t = cumsum(ldA); S = C@B^T (shared over heads);
//   W[t,s] = 1[s<=t] exp(cs_t-cs_s) dt_s S[t,s]; Y = exp(cs_t)(C@Hstart^T) + W@X + D x
//   H_end[p,n] = sum_s exp(cs_63-cs_s) dt_s X[s,p] B[s,n]
// X transposed per-head into wave-private LDS tile (16B-block XOR swizzle).
// ---------------------------------------------------------------------------
DEV void stage_xt(const unsigned short* __restrict__ xrow, unsigned short* XtW, int l)
{
    u16x8_t xv[8];
#pragma unroll
    for (int m = 0; m < 8; m++) xv[m] = *(const u16x8_t*)(xrow + m * 8);
#pragma unroll
    for (int p = 0; p < 64; p++) {
        int blkc = (l >> 3) ^ (p & 7);
        XtW[p * 64 + blkc * 8 + (l & 7)] = xv[p >> 3][p & 7];
    }
}

DEV bf16x8_t xt_frag(const unsigned short* XtW, int r, int quad, int jj, int kk)
{
    int p = jj * 16 + r;
    int blkc = (kk * 4 + quad) ^ (p & 7);
    return __builtin_bit_cast(bf16x8_t, *(const u16x8_t*)(XtW + p * 64 + blkc * 8));
}

__global__ __launch_bounds__(256) void scan_chstate_k(
    const unsigned short* __restrict__ xc,   // R x 1056 bf16
    const float* __restrict__ dtb,
    float* __restrict__ lcs,                 // in: ldA ; out: cs (in-place, same elem)
    float* __restrict__ Hend, float* __restrict__ dec)
{
    __shared__ __attribute__((aligned(16))) unsigned char sm[37120];
    unsigned short* Btr = (unsigned short*)sm;          // [16][72] bf16 (B transposed)
    float* csW = (float*)(sm + 2304);                   // [4][64]
    float* dtW = (float*)(sm + 3328);                   // [4][64]
    unsigned short* Xt0 = (unsigned short*)(sm + 4352); // [4][64*64]

    const int tid = threadIdx.x;
    const int w = tid >> 6, l = tid & 63;
    const int r = l & 15, quad = l >> 4;
    const int row0 = blockIdx.x * 64;
    const int b = blockIdx.x >> 6, chunk = blockIdx.x & 63;
    const int h = blockIdx.y * 4 + w;
    const int blk = ((b * 16 + h) << 6) | chunk;

    // stage Bt[n][s] = B[s][n]
    {
        int n = tid & 15, s0 = (tid >> 4) * 4;
#pragma unroll
        for (int js = 0; js < 4; js++) {
            int s = s0 + js;
            Btr[n * 72 + s] = xc[(size_t)(row0 + s) * 1056 + 1024 + n];
        }
    }

    // per-lane ldA/dt + inclusive wave scan -> cs
    float v   = lcs[(size_t)(row0 + l) * 16 + h];
    float dtv = dtb[(size_t)(row0 + l) * 16 + h];
#pragma unroll
    for (int d = 1; d < 64; d <<= 1) {
        float o = __shfl_up(v, d, 64);
        if (l >= d) v += o;
    }
    lcs[(size_t)(row0 + l) * 16 + h] = v;
    csW[w * 64 + l] = v;
    dtW[w * 64 + l] = dtv;
    if (l == 63) dec[blk] = __expf(v);
    __syncthreads();

    unsigned short* XtW = Xt0 + w * 4096;
    stage_xt(xc + (size_t)(row0 + l) * 1056 + h * 64, XtW, l);

    const float* csr = csW + w * 64;
    const float* dtr = dtW + w * 64;
    float cs63 = csr[63];

    f32x4_t z = {0.f, 0.f, 0.f, 0.f};
    f32x4_t hacc[4] = {z, z, z, z};
#pragma unroll
    for (int kk = 0; kk < 2; kk++) {
        int sb = kk * 32 + quad * 8;
        u16x8_t bv = *(const u16x8_t*)(Btr + r * 72 + sb);
        f32x4_t c0 = *(const f32x4_t*)(csr + sb);
        f32x4_t c1 = *(const f32x4_t*)(csr + sb + 4);
        f32x4_t d0 = *(const f32x4_t*)(dtr + sb);
        f32x4_t d1 = *(const f32x4_t*)(dtr + sb + 4);
        u16x8_t wv;
#pragma unroll
        for (int j = 0; j < 4; j++) {
            wv[j]     = f2bf(bf2f(bv[j])     * d0[j] * __expf(cs63 - c0[j]));
            wv[4 + j] = f2bf(bf2f(bv[4 + j]) * d1[j] * __expf(cs63 - c1[j]));
        }
        bf16x8_t wf = __builtin_bit_cast(bf16x8_t, wv);
#pragma unroll
        for (int jj = 0; jj < 4; jj++)
            hacc[jj] = __builtin_amdgcn_mfma_f32_16x16x32_bf16(wf, xt_frag(XtW, r, quad, jj, kk), hacc[jj], 0, 0, 0);
    }
    float* o = Hend + (size_t)blk * 1024;
#pragma unroll
    for (int jj = 0; jj < 4; jj++)
#pragma unroll
        for (int reg = 0; reg < 4; reg++)
            o[(jj * 16 + r) * 16 + quad * 4 + reg] = hacc[jj][reg];
}

// Combine: exclusive prefix over 64 chunk states per (b,h) — unchanged.
__global__ __launch_bounds__(64) void scan_comb_k(float* __restrict__ H, const float* __restrict__ dec)
{
    int bh = blockIdx.x >> 2;
    int q  = blockIdx.x & 3;
    int t  = threadIdx.x;
    float* base = H + (size_t)bh * 64 * 1024 + q * 256 + t * 4;
    const float* dp = dec + bh * 64;
    f32x4_t hs = {0.f, 0.f, 0.f, 0.f};
    f32x4_t cur = *(const f32x4_t*)base;
    for (int c = 0; c < 64; c++) {
        int cn = (c < 63) ? c + 1 : 63;
        f32x4_t nxt = *(const f32x4_t*)(base + (size_t)cn * 1024);
        float d = dp[c];
        *(f32x4_t*)(base + (size_t)c * 1024) = hs;   // exclusive prefix
#pragma unroll
        for (int j = 0; j < 4; j++) hs[j] = fmaf(hs[j], d, cur[j]);
        cur = nxt;
    }
}

__global__ __launch_bounds__(256) void scan_chout_k(
    const unsigned short* __restrict__ xc,
    const float* __restrict__ dtb, const float* __restrict__ csb,
    const float* __restrict__ Hst, const float* __restrict__ Dp,
    unsigned short* __restrict__ ybuf)  // R x 1024 bf16
{
    __shared__ __attribute__((aligned(16))) unsigned char sm[60416];
    unsigned short* Ct = (unsigned short*)sm;            // [64][32] (cols 16..31 = 0)
    unsigned short* Bt = (unsigned short*)(sm + 4096);   // [64][32]
    float* S   = (float*)(sm + 8192);                    // [64][68]
    float* csL = (float*)(sm + 25600);                   // [4][64]
    float* dtL = (float*)(sm + 26624);                   // [4][64]
    unsigned short* Xt0 = (unsigned short*)(sm + 27648); // [4][64*64]

    const int tid = threadIdx.x;
    const int w = tid >> 6, l = tid & 63;
    const int r = l & 15, quad = l >> 4;
    const int row0 = blockIdx.x * 64;
    const int b = blockIdx.x >> 6, chunk = blockIdx.x & 63;
    const int h = blockIdx.y * 4 + w;
    const int blk = ((b * 16 + h) << 6) | chunk;

    // stage padded B/C tiles
    {
        int rowi = tid >> 2, seg = tid & 3;
        u16x8_t vb, vc;
        if (seg < 2) {
            const unsigned short* src = xc + (size_t)(row0 + rowi) * 1056 + 1024 + seg * 8;
            vb = *(const u16x8_t*)src;
            vc = *(const u16x8_t*)(src + 16);
        } else {
#pragma unroll
            for (int j = 0; j < 8; j++) { vb[j] = 0; vc[j] = 0; }
        }
        *(u16x8_t*)(Bt + rowi * 32 + seg * 8) = vb;
        *(u16x8_t*)(Ct + rowi * 32 + seg * 8) = vc;
    }
    // stage cs/dt for this block's 4 heads
    csL[w * 64 + l] = csb[(size_t)(row0 + l) * 16 + h];
    dtL[w * 64 + l] = dtb[(size_t)(row0 + l) * 16 + h];
    __syncthreads();

    // S = C @ B^T : wave w computes t-rows [w*16, w*16+16)
    {
        bf16x8_t cf = __builtin_bit_cast(bf16x8_t, *(const u16x8_t*)(Ct + (w * 16 + r) * 32 + quad * 8));
        f32x4_t z = {0.f, 0.f, 0.f, 0.f};
#pragma unroll
        for (int j = 0; j < 4; j++) {
            bf16x8_t bfv = __builtin_bit_cast(bf16x8_t, *(const u16x8_t*)(Bt + (j * 16 + r) * 32 + quad * 8));
            f32x4_t d = __builtin_amdgcn_mfma_f32_16x16x32_bf16(cf, bfv, z, 0, 0, 0);
#pragma unroll
            for (int reg = 0; reg < 4; reg++)
                S[(w * 16 + quad * 4 + reg) * 68 + j * 16 + r] = d[reg];
        }
    }
    __syncthreads();

    // per-wave head section
    unsigned short* XtW = Xt0 + w * 4096;
    stage_xt(xc + (size_t)(row0 + l) * 1056 + h * 64, XtW, l);

    const float* csr = csL + w * 64;
    const float* dtr = dtL + w * 64;

    // Y_inter = C @ Hstart^T, then row-scale by exp(cs_t)
    f32x4_t acc[4][4];
    {
        bf16x8_t hf[4];
#pragma unroll
        for (int jj = 0; jj < 4; jj++) {
            int p = jj * 16 + r;
            u16x8_t hv;
            if (quad < 2) {
                const float* hp = Hst + (size_t)blk * 1024 + p * 16 + quad * 8;
                f32x4_t h0 = *(const f32x4_t*)hp;
                f32x4_t h1 = *(const f32x4_t*)(hp + 4);
#pragma unroll
                for (int j = 0; j < 4; j++) { hv[j] = f2bf(h0[j]); hv[4 + j] = f2bf(h1[j]); }
            } else {
#pragma unroll
                for (int j = 0; j < 8; j++) hv[j] = 0;
            }
            hf[jj] = __builtin_bit_cast(bf16x8_t, hv);
        }
        f32x4_t z = {0.f, 0.f, 0.f, 0.f};
#pragma unroll
        for (int i = 0; i < 4; i++) {
            bf16x8_t cf = __builtin_bit_cast(bf16x8_t, *(const u16x8_t*)(Ct + (i * 16 + r) * 32 + quad * 8));
#pragma unroll
            for (int jj = 0; jj < 4; jj++)
                acc[i][jj] = __builtin_amdgcn_mfma_f32_16x16x32_bf16(cf, hf[jj], z, 0, 0, 0);
        }
#pragma unroll
        for (int i = 0; i < 4; i++) {
            f32x4_t es;
#pragma unroll
            for (int reg = 0; reg < 4; reg++) es[reg] = __expf(csr[i * 16 + quad * 4 + reg]);
#pragma unroll
            for (int jj = 0; jj < 4; jj++)
#pragma unroll
                for (int reg = 0; reg < 4; reg++) acc[i][jj][reg] *= es[reg];
        }
    }

    // Y_intra += W @ X
#pragma unroll
    for (int kk = 0; kk < 2; kk++) {
        int sb = kk * 32 + quad * 8;
        bf16x8_t xf[4];
#pragma unroll
        for (int jj = 0; jj < 4; jj++) xf[jj] = xt_frag(XtW, r, quad, jj, kk);
        f32x4_t c0 = *(const f32x4_t*)(csr + sb);
        f32x4_t c1 = *(const f32x4_t*)(csr + sb + 4);
        f32x4_t d0 = *(const f32x4_t*)(dtr + sb);
        f32x4_t d1 = *(const f32x4_t*)(dtr + sb + 4);
#pragma unroll
        for (int i = 0; i < 4; i++) {
            int t = i * 16 + r;
            float cst = csr[t];
            const float* Srow = S + t * 68;
            f32x4_t s0 = *(const f32x4_t*)(Srow + sb);
            f32x4_t s1 = *(const f32x4_t*)(Srow + sb + 4);
            u16x8_t wv;
#pragma unroll
            for (int j = 0; j < 4; j++) {
                int s = sb + j;
                float v0 = (s <= t) ? __expf(cst - c0[j]) * d0[j] * s0[j] : 0.f;
                wv[j] = f2bf(v0);
                int s2 = sb + 4 + j;
                float v1 = (s2 <= t) ? __expf(cst - c1[j]) * d1[j] * s1[j] : 0.f;
                wv[4 + j] = f2bf(v1);
            }
            bf16x8_t wf = __builtin_bit_cast(bf16x8_t, wv);
#pragma unroll
            for (int jj = 0; jj < 4; jj++)
                acc[i][jj] = __builtin_amdgcn_mfma_f32_16x16x32_bf16(wf, xf[jj], acc[i][jj], 0, 0, 0);
        }
    }

    // D-term + store y
    float Dh = Dp[h];
#pragma unroll
    for (int i = 0; i < 4; i++) {
#pragma unroll
        for (int jj = 0; jj < 4; jj++) {
            int p = jj * 16 + r;
            int t0 = i * 16 + quad * 4;
            int blk2 = (t0 >> 3) ^ (p & 7);
            u16x4_t x4 = *(const u16x4_t*)(XtW + p * 64 + blk2 * 8 + (t0 & 7));
#pragma unroll
            for (int reg = 0; reg < 4; reg++) {
                float yv = fmaf(Dh, bf2f(x4[reg]), acc[i][jj][reg]);
                ybuf[(size_t)(row0 + t0 + reg) * 1024 + h * 64 + p] = f2bf(yv);
            }
        }
    }
}

// ---------------------------------------------------------------------------
// Gated RMSNorm (in-place on y, bf16): norm_w fp32
// ---------------------------------------------------------------------------
__global__ __launch_bounds__(256) void rmsgate_k(
    unsigned short* __restrict__ y,
    const unsigned short* __restrict__ z,
    const float* __restrict__ nw)
{
    __shared__ float sred[256];
    int row = blockIdx.x;
    int t = threadIdx.x;
    int c = t * 4;
    u16x4_t yv = *(const u16x4_t*)(y + (size_t)row * 1024 + c);
    u16x4_t zv = *(const u16x4_t*)(z + (size_t)row * 1024 + c);
    float g[4];
    float ss = 0.f;
#pragma unroll
    for (int j = 0; j < 4; j++) {
        float zf = bf2f(zv[j]);
        float sil = zf * __builtin_amdgcn_rcpf(1.f + __expf(-zf));
        g[j] = bf2f(yv[j]) * sil;
        ss += g[j] * g[j];
    }
    sred[t] = ss;
    __syncthreads();
#pragma unroll
    for (int s = 128; s > 0; s >>= 1) {
        if (t < s) sred[t] += sred[t + s];
        __syncthreads();
    }
    float scale = rsqrtf(sred[0] * (1.f / 1024.f) + 1e-5f);
    u16x4_t o4;
#pragma unroll
    for (int j = 0; j < 4; j++) o4[j] = f2bf(g[j] * scale * nw[c + j]);
    *(u16x4_t*)(y + (size_t)row * 1024 + c) = o4;
}

// ---------------------------------------------------------------------------
// Final: out = LayerNorm(x + f)  — all fp32 I/O
// ---------------------------------------------------------------------------
__global__ __launch_bounds__(128) void ln_k(
    const float* __restrict__ x,   // R x 512 fp32
    const float* __restrict__ f,   // R x 512 fp32
    const float* __restrict__ lw,
    const float* __restrict__ lb,
    float* __restrict__ outp)      // R x 512 fp32
{
    __shared__ float sA[128], sB[128];
    int row = blockIdx.x;
    int t = threadIdx.x;
    int c = t * 4;
    float s[4];
    float sum = 0.f, sq = 0.f;
    f32x4_t xv = *(const f32x4_t*)(x + (size_t)row * 512 + c);
    f32x4_t fv = *(const f32x4_t*)(f + (size_t)row * 512 + c);
#pragma unroll
    for (int j = 0; j < 4; j++) {
        s[j] = xv[j] + fv[j];
        sum += s[j];
        sq += s[j] * s[j];
    }
    sA[t] = sum; sB[t] = sq;
    __syncthreads();
#pragma unroll
    for (int st = 64; st > 0; st >>= 1) {
        if (t < st) { sA[t] += sA[t + st]; sB[t] += sB[t + st]; }
        __syncthreads();
    }
    float mu = sA[0] * (1.f / 512.f);
    float var = sB[0] * (1.f / 512.f) - mu * mu;
    if (var < 0.f) var = 0.f;
    float inv = rsqrtf(var + 1e-5f);
    f32x4_t o4;
#pragma unroll
    for (int j = 0; j < 4; j++)
        o4[j] = (s[j] - mu) * inv * lw[c + j] + lb[c + j];
    *(f32x4_t*)(outp + (size_t)row * 512 + c) = o4;
}

// ---------------------------------------------------------------------------
extern "C" void kernel_launch(void* const* d_in, const int* in_sizes, int n_in,
                              void* d_out, int out_size, void* d_ws, size_t ws_size,
                              hipStream_t stream)
{
    (void)in_sizes; (void)n_in; (void)out_size;

    const float* x           = (const float*)d_in[0];
    const float* in_proj[2]  = {(const float*)d_in[1],  (const float*)d_in[9]};
    const float* conv_w[2]   = {(const float*)d_in[2],  (const float*)d_in[10]};
    const float* conv_b[2]   = {(const float*)d_in[3],  (const float*)d_in[11]};
    const float* dt_bias[2]  = {(const float*)d_in[4],  (const float*)d_in[12]};
    const float* A_log[2]    = {(const float*)d_in[5],  (const float*)d_in[13]};
    const float* Dp[2]       = {(const float*)d_in[6],  (const float*)d_in[14]};
    const float* norm_w[2]   = {(const float*)d_in[7],  (const float*)d_in[15]};
    const float* out_proj[2] = {(const float*)d_in[8],  (const float*)d_in[16]};
    const float* proj_w      = (const float*)d_in[17];
    const float* proj_b      = (const float*)d_in[18];
    const float* ln_w        = (const float*)d_in[19];
    const float* ln_b        = (const float*)d_in[20];
    float* outp = (float*)d_out;

    const size_t IP_ELEMS = (size_t)2096 * 512;
    const size_t X_ELEMS  = (size_t)32768 * 512;

    const size_t constBytes = X_ELEMS * 2 + 2 * IP_ELEMS * 2 + 2 * 512 * 1024 * 2 + 4096;
    int g = 1;
    {
        const int cands[3] = {8, 4, 2};
        for (int ci = 0; ci < 3; ci++) {
            size_t R = (size_t)cands[ci] * 4096;
            size_t need = constBytes + R * (2144 + 2112 + 2048 + 64 + 64 + 1024)
                        + (size_t)cands[ci] * 1024 * 4 + 16 * 256;
            if (need <= ws_size) { g = cands[ci]; break; }
        }
    }
    const size_t R = (size_t)g * 4096;
    const int nGroups = 8 / g;
    const int MT = (int)(R >> 7);

    char* ws = (char*)d_ws;
    size_t off = 0;
    auto alloc = [&](size_t bytes) -> char* {
        char* p = ws + off;
        off += (bytes + 255) & ~(size_t)255;
        return p;
    };
    unsigned short* xb16  = (unsigned short*)alloc(X_ELEMS * 2);
    unsigned short* ipb16[2];
    ipb16[0] = (unsigned short*)alloc(IP_ELEMS * 2);
    ipb16[1] = (unsigned short*)alloc(IP_ELEMS * 2);
    unsigned short* Ebuf  = (unsigned short*)alloc(2 * 512 * 1024 * 2);
    unsigned short* Ef    = Ebuf;
    unsigned short* Eb    = Ebuf + 512 * 1024;
    unsigned short* xbcdt = (unsigned short*)alloc(R * 1072 * 2);
    unsigned short* ybuf  = xbcdt;                       // alias (xbcdt dead by scan out)
    unsigned short* xconv = (unsigned short*)alloc(R * 1056 * 2);
    unsigned short* zbuf  = xconv;                       // alias (xconv dead after scans)
    float* fbuf = (float*)alloc(R * 512 * 4);
    float* dtb  = (float*)alloc(R * 16 * 4);
    float* dab  = (float*)alloc(R * 16 * 4);             // ldA -> cs (in-place in scan_chstate_k)
    float* Hbuf = (float*)alloc(R * 1024);
    float* dec  = (float*)alloc((size_t)g * 1024 * 4);

    dim3 blk(256);

    cvt_k<<<(unsigned)((X_ELEMS / 8 + 255) / 256), blk, 0, stream>>>(x, xb16, (int)(X_ELEMS / 8));
    cvt_k<<<(unsigned)((IP_ELEMS / 8 + 255) / 256), blk, 0, stream>>>(in_proj[0], ipb16[0], (int)(IP_ELEMS / 8));
    cvt_k<<<(unsigned)((IP_ELEMS / 8 + 255) / 256), blk, 0, stream>>>(in_proj[1], ipb16[1], (int)(IP_ELEMS / 8));
    eprep2_k<<<dim3(128, 2), blk, 0, stream>>>(proj_w, out_proj[0], out_proj[1], Ebuf);

    for (int grp = 0; grp < nGroups; grp++) {
        const unsigned short* xg = xb16 + (size_t)grp * R * 512;
        const float* xgf = x + (size_t)grp * R * 512;
        float* og = outp + (size_t)grp * R * 512;

        for (int dir = 0; dir < 2; dir++) {
            if (dir == 0)
                gemm_bt<false, false, false, false, false><<<dim3(9, MT), blk, 0, stream>>>(
                    xg, ipb16[0] + (size_t)1024 * 512, xbcdt, nullptr, 1072, 512, 1072, 0);
            else
                gemm_bt<true, false, false, false, false><<<dim3(9, MT), blk, 0, stream>>>(
                    xg, ipb16[1] + (size_t)1024 * 512, xbcdt, nullptr, 1072, 512, 1072, 0);

            conv_silu_k<<<(unsigned)(R * 132 / 2048), blk, 0, stream>>>(xbcdt, conv_w[dir], conv_b[dir], xconv);
            dt_pre_k<<<(unsigned)(R * 16 / 256), blk, 0, stream>>>(xbcdt, dt_bias[dir], A_log[dir], dtb, dab);

            scan_chstate_k<<<dim3((unsigned)(R / 64), 4), blk, 0, stream>>>(xconv, dtb, dab, Hbuf, dec);
            scan_comb_k<<<(unsigned)(g * 64), dim3(64), 0, stream>>>(Hbuf, dec);
            scan_chout_k<<<dim3((unsigned)(R / 64), 4), blk, 0, stream>>>(xconv, dtb, dab, Hbuf, Dp[dir], ybuf);

            if (dir == 0)
                gemm_bt<false, false, false, false, false><<<dim3(8, MT), blk, 0, stream>>>(
                    xg, ipb16[0], zbuf, nullptr, 1024, 512, 1024, 0);
            else
                gemm_bt<true, false, false, false, false><<<dim3(8, MT), blk, 0, stream>>>(
                    xg, ipb16[1], zbuf, nullptr, 1024, 512, 1024, 0);

            rmsgate_k<<<(unsigned)R, blk, 0, stream>>>(ybuf, zbuf, norm_w[dir]);

            if (dir == 0)
                gemm_bt<false, false, true, true, false><<<dim3(4, MT), blk, 0, stream>>>(
                    ybuf, Ef, fbuf, proj_b, 512, 1024, 512, 0);
            else
                gemm_bt<false, true, true, false, true><<<dim3(4, MT), blk, 0, stream>>>(
                    ybuf, Eb, fbuf, nullptr, 512, 1024, 512, 0);
        }
        ln_k<<<(unsigned)R, dim3(128), 0, stream>>>(xgf, fbuf, ln_w, ln_b, og);
    }
}

// Round 5
// 952.315 us; speedup vs baseline: 1.3521x; 1.0123x over previous
//
#include <hip/hip_runtime.h>
#include <hip/hip_bf16.h>
#include <math.h>

typedef __bf16 bf16x8_t __attribute__((ext_vector_type(8)));
typedef float f32x4_t __attribute__((ext_vector_type(4)));
typedef unsigned short u16x8_t __attribute__((ext_vector_type(8)));
typedef unsigned short u16x4_t __attribute__((ext_vector_type(4)));

#define DEV __device__ __forceinline__

DEV float bf2f(unsigned short u) {
    unsigned int v = ((unsigned int)u) << 16;
    return __builtin_bit_cast(float, v);
}
DEV unsigned short f2bf(float f) {
    unsigned int u = __builtin_bit_cast(unsigned int, f);
    u += 0x7fffu + ((u >> 16) & 1u);   // RNE
    return (unsigned short)(u >> 16);
}

// ---------------------------------------------------------------------------
// fp32 -> bf16 conversion (8 elems/thread)
// ---------------------------------------------------------------------------
__global__ __launch_bounds__(256) void cvt_k(
    const float* __restrict__ in, unsigned short* __restrict__ out, int n8)
{
    int t = blockIdx.x * 256 + threadIdx.x;
    if (t >= n8) return;
    f32x4_t a = ((const f32x4_t*)in)[t * 2];
    f32x4_t b = ((const f32x4_t*)in)[t * 2 + 1];
    u16x8_t o;
#pragma unroll
    for (int j = 0; j < 4; j++) { o[j] = f2bf(a[j]); o[4 + j] = f2bf(b[j]); }
    ((u16x8_t*)out)[t] = o;
}

// ---------------------------------------------------------------------------
// MFMA GEMM:  C[M x N] = A'[M x K] @ W[N x K]^T   (bf16 in, fp32 accum)
// 128x128 tile, BK=32, global_load_lds width-16 staging, XOR-swizzled chunks.
// ---------------------------------------------------------------------------
template <bool FLIP_A, bool FLIP_C, bool OUT_F32, bool ADD_BIAS, bool ACCUM>
__global__ __launch_bounds__(256, 2) void gemm_bt(
    const unsigned short* __restrict__ A,
    const unsigned short* __restrict__ W,
    void* __restrict__ Cout,
    const float* __restrict__ bias,
    int N, int K, int ldc, int col_ofs)
{
    __shared__ __attribute__((aligned(16))) unsigned char smem[16384]; // A: 8KB, W: 8KB
    const int tid  = threadIdx.x;
    const int wave = tid >> 6;
    const int lane = tid & 63;
    const int mtile = blockIdx.y << 7;
    const int ntile = blockIdx.x << 7;

    const int c0 = tid, c1 = 256 + tid;
    const int r0 = c0 >> 2, p0 = c0 & 3, g0 = p0 ^ ((r0 >> 1) & 3);
    const int r1 = c1 >> 2, p1 = c1 & 3, g1 = p1 ^ ((r1 >> 1) & 3);

    int am0 = mtile + r0; if (FLIP_A) am0 ^= 4095;
    int am1 = mtile + r1; if (FLIP_A) am1 ^= 4095;
    const unsigned short* aP0 = A + (size_t)am0 * K + g0 * 8;
    const unsigned short* aP1 = A + (size_t)am1 * K + g1 * 8;

    int wr0 = ntile + r0; if (wr0 > N - 1) wr0 = N - 1;
    int wr1 = ntile + r1; if (wr1 > N - 1) wr1 = N - 1;
    const unsigned short* wP0 = W + (size_t)wr0 * K + g0 * 8;
    const unsigned short* wP1 = W + (size_t)wr1 * K + g1 * 8;

    unsigned char* ldsA = smem;
    unsigned char* ldsW = smem + 8192;
    unsigned char* ldsA0 = ldsA + wave * 1024;          // wave-uniform bases
    unsigned char* ldsA1 = ldsA + 4096 + wave * 1024;
    unsigned char* ldsW0 = ldsW + wave * 1024;
    unsigned char* ldsW1 = ldsW + 4096 + wave * 1024;

    f32x4_t acc[4][4] = {};

    const int wm = (wave & 1) << 6;
    const int wn = (wave >> 1) << 6;
    const int r    = lane & 15;
    const int quad = lane >> 4;
    const int sw   = (r >> 1) & 3;

    int aoff[4], woff[4];
#pragma unroll
    for (int i = 0; i < 4; i++) {
        int m = wm + i * 16 + r;
        aoff[i] = (m * 4 + (quad ^ sw)) * 16;
        int n = wn + i * 16 + r;
        woff[i] = (n * 4 + (quad ^ sw)) * 16;
    }

    for (int k0 = 0; k0 < K; k0 += 32) {
        __builtin_amdgcn_global_load_lds(
            (const __attribute__((address_space(1))) void*)(aP0 + k0),
            (__attribute__((address_space(3))) void*)ldsA0, 16, 0, 0);
        __builtin_amdgcn_global_load_lds(
            (const __attribute__((address_space(1))) void*)(aP1 + k0),
            (__attribute__((address_space(3))) void*)ldsA1, 16, 0, 0);
        __builtin_amdgcn_global_load_lds(
            (const __attribute__((address_space(1))) void*)(wP0 + k0),
            (__attribute__((address_space(3))) void*)ldsW0, 16, 0, 0);
        __builtin_amdgcn_global_load_lds(
            (const __attribute__((address_space(1))) void*)(wP1 + k0),
            (__attribute__((address_space(3))) void*)ldsW1, 16, 0, 0);
        __syncthreads();

        bf16x8_t af[4], wf[4];
#pragma unroll
        for (int i = 0; i < 4; i++)
            af[i] = __builtin_bit_cast(bf16x8_t, *(const u16x8_t*)(ldsA + aoff[i]));
#pragma unroll
        for (int j = 0; j < 4; j++)
            wf[j] = __builtin_bit_cast(bf16x8_t, *(const u16x8_t*)(ldsW + woff[j]));
#pragma unroll
        for (int i = 0; i < 4; i++)
#pragma unroll
            for (int j = 0; j < 4; j++)
                acc[i][j] = __builtin_amdgcn_mfma_f32_16x16x32_bf16(af[i], wf[j], acc[i][j], 0, 0, 0);
        __syncthreads();
    }

    // epilogue: C/D layout col=lane&15, row=quad*4+reg
#pragma unroll
    for (int i = 0; i < 4; i++) {
#pragma unroll
        for (int j = 0; j < 4; j++) {
            int cc = ntile + wn + j * 16 + r;
            if (cc >= N) continue;
#pragma unroll
            for (int reg = 0; reg < 4; reg++) {
                int rr = mtile + wm + i * 16 + quad * 4 + reg;
                int orow = FLIP_C ? (rr ^ 4095) : rr;
                float v = acc[i][j][reg];
                if (ADD_BIAS) v += bias[cc];
                if (OUT_F32) {
                    float* p = (float*)Cout + (size_t)orow * ldc + col_ofs + cc;
                    if (ACCUM) v += *p;
                    *p = v;
                } else {
                    ((unsigned short*)Cout)[(size_t)orow * ldc + col_ofs + cc] = f2bf(v);
                }
            }
        }
    }
}

// ---------------------------------------------------------------------------
// pack proj_w slices to bf16: pwb[dir][n][j] = bf16(pw[n][dir*512+j])
// ---------------------------------------------------------------------------
__global__ __launch_bounds__(256) void pack_pw_k(
    const float* __restrict__ pw, unsigned short* __restrict__ pwb)
{
    int t = blockIdx.x * 256 + threadIdx.x;   // 65536 threads, 8 elems each
    int j8 = t & 63;
    int n  = (t >> 6) & 511;
    int dir = t >> 15;
    const float* src = pw + (size_t)n * 1024 + dir * 512 + j8 * 8;
    f32x4_t a = *(const f32x4_t*)src;
    f32x4_t b = *(const f32x4_t*)(src + 4);
    u16x8_t o;
#pragma unroll
    for (int j = 0; j < 4; j++) { o[j] = f2bf(a[j]); o[4 + j] = f2bf(b[j]); }
    *(u16x8_t*)(pwb + (size_t)dir * 512 * 512 + (size_t)n * 512 + j8 * 8) = o;
}

// ---------------------------------------------------------------------------
// transpose out_proj to bf16: opT[dir][k][j] = bf16(op_dir[j][k])
// ---------------------------------------------------------------------------
__global__ __launch_bounds__(256) void tr_op_k(
    const float* __restrict__ op0, const float* __restrict__ op1,
    unsigned short* __restrict__ opT)
{
    __shared__ float tile[32][33];
    const int dir = blockIdx.z;
    const float* op = dir ? op1 : op0;
    const int k0 = blockIdx.x * 32;
    const int j0 = blockIdx.y * 32;
    const int tx = threadIdx.x & 31, ty = threadIdx.x >> 5;
#pragma unroll
    for (int i = 0; i < 4; i++) {
        int j = j0 + ty + i * 8;
        tile[ty + i * 8][tx] = op[(size_t)j * 1024 + k0 + tx];
    }
    __syncthreads();
    unsigned short* dst = opT + (size_t)dir * 1024 * 512;
#pragma unroll
    for (int i = 0; i < 4; i++) {
        int k = k0 + ty + i * 8;
        dst[(size_t)k * 512 + j0 + tx] = f2bf(tile[tx][ty + i * 8]);
    }
}

// ---------------------------------------------------------------------------
// Depthwise causal conv (width 4) + SiLU, 8 rows/thread sliding window.
// ---------------------------------------------------------------------------
__global__ __launch_bounds__(256) void conv_silu_k(
    const unsigned short* __restrict__ xin,  // R x 1072 bf16
    const float* __restrict__ cw,            // 1056 x 4 fp32
    const float* __restrict__ cb,            // 1056 fp32
    unsigned short* __restrict__ outp)       // R x 1056 bf16
{
    int t = blockIdx.x * 256 + threadIdx.x;
    int c8 = t % 132;
    int rb = t / 132;
    int c = c8 * 8;
    int row0 = rb * 8;
    int l0 = row0 & 4095;

    float w[8][4];
#pragma unroll
    for (int j = 0; j < 8; j++) {
        f32x4_t wv = *(const f32x4_t*)(cw + (c + j) * 4);
        w[j][0] = wv[0]; w[j][1] = wv[1]; w[j][2] = wv[2]; w[j][3] = wv[3];
    }
    float bia[8];
    {
        f32x4_t b0 = *(const f32x4_t*)(cb + c);
        f32x4_t b1 = *(const f32x4_t*)(cb + c + 4);
#pragma unroll
        for (int j = 0; j < 4; j++) { bia[j] = b0[j]; bia[4 + j] = b1[j]; }
    }

    u16x8_t zero;
#pragma unroll
    for (int j = 0; j < 8; j++) zero[j] = 0;

    // window rows row0-3 .. row0+7 (11 rows); pre-batch rows are zero
    u16x8_t win[11];
#pragma unroll
    for (int u = 0; u < 11; u++) {
        int lu = l0 - 3 + u;
        win[u] = (lu >= 0)
            ? *(const u16x8_t*)(xin + (size_t)(row0 - 3 + u) * 1072 + c)
            : zero;
    }

#pragma unroll
    for (int s = 0; s < 8; s++) {
        float acc[8];
#pragma unroll
        for (int j = 0; j < 8; j++) acc[j] = bia[j];
#pragma unroll
        for (int k = 0; k < 4; k++) {
            u16x8_t xv = win[s + k];
#pragma unroll
            for (int j = 0; j < 8; j++)
                acc[j] = fmaf(bf2f(xv[j]), w[j][k], acc[j]);
        }
        u16x8_t o;
#pragma unroll
        for (int j = 0; j < 8; j++) {
            float xx = acc[j];
            o[j] = f2bf(xx * __builtin_amdgcn_rcpf(1.f + __expf(-xx)));
        }
        *(u16x8_t*)(outp + (size_t)(row0 + s) * 1056 + c) = o;
    }
}

// ---------------------------------------------------------------------------
// dt = softplus(dt_raw + dt_bias), ldA = dt * -exp(A_log)  (log of dA)
// ---------------------------------------------------------------------------
__global__ __launch_bounds__(256) void dt_pre_k(
    const unsigned short* __restrict__ xin,  // R x 1072 bf16 (dt raw at 1056..1071)
    const float* __restrict__ dt_bias,
    const float* __restrict__ A_log,
    float* __restrict__ dtb, float* __restrict__ ldab)
{
    int t = blockIdx.x * 256 + threadIdx.x;  // R*16
    int h = t & 15;
    int row = t >> 4;
    float x = bf2f(xin[(size_t)row * 1072 + 1056 + h]) + dt_bias[h];
    float dt = (x > 20.f) ? x : log1pf(__expf(x));
    float A = -__expf(A_log[h]);
    dtb[t] = dt;
    ldab[t] = dt * A;       // log(dA); cumsum later (exact: dA = exp(dt*A))
}

// ---------------------------------------------------------------------------
// Chunked scan as MFMA GEMMs (Mamba2 SSD formulation), chunk = 64.
// ---------------------------------------------------------------------------
DEV void stage_xt(const unsigned short* __restrict__ xrow, unsigned short* XtW, int l)
{
    u16x8_t xv[8];
#pragma unroll
    for (int m = 0; m < 8; m++) xv[m] = *(const u16x8_t*)(xrow + m * 8);
#pragma unroll
    for (int p = 0; p < 64; p++) {
        int blkc = (l >> 3) ^ (p & 7);
        XtW[p * 64 + blkc * 8 + (l & 7)] = xv[p >> 3][p & 7];
    }
}

DEV bf16x8_t xt_frag(const unsigned short* XtW, int r, int quad, int jj, int kk)
{
    int p = jj * 16 + r;
    int blkc = (kk * 4 + quad) ^ (p & 7);
    return __builtin_bit_cast(bf16x8_t, *(const u16x8_t*)(XtW + p * 64 + blkc * 8));
}

__global__ __launch_bounds__(256) void scan_chstate_k(
    const unsigned short* __restrict__ xc,   // R x 1056 bf16
    const float* __restrict__ dtb,
    float* __restrict__ lcs,                 // in: ldA ; out: cs (in-place, same elem)
    float* __restrict__ Hend, float* __restrict__ dec)
{
    __shared__ __attribute__((aligned(16))) unsigned char sm[37120];
    unsigned short* Btr = (unsigned short*)sm;          // [16][72] bf16 (B transposed)
    float* csW = (float*)(sm + 2304);                   // [4][64]
    float* dtW = (float*)(sm + 3328);                   // [4][64]
    unsigned short* Xt0 = (unsigned short*)(sm + 4352); // [4][64*64]

    const int tid = threadIdx.x;
    const int w = tid >> 6, l = tid & 63;
    const int r = l & 15, quad = l >> 4;
    const int row0 = blockIdx.x * 64;
    const int b = blockIdx.x >> 6, chunk = blockIdx.x & 63;
    const int h = blockIdx.y * 4 + w;
    const int blk = ((b * 16 + h) << 6) | chunk;

    // stage Bt[n][s] = B[s][n]
    {
        int n = tid & 15, s0 = (tid >> 4) * 4;
#pragma unroll
        for (int js = 0; js < 4; js++) {
            int s = s0 + js;
            Btr[n * 72 + s] = xc[(size_t)(row0 + s) * 1056 + 1024 + n];
        }
    }

    // per-lane ldA/dt + inclusive wave scan -> cs
    float v   = lcs[(size_t)(row0 + l) * 16 + h];
    float dtv = dtb[(size_t)(row0 + l) * 16 + h];
#pragma unroll
    for (int d = 1; d < 64; d <<= 1) {
        float o = __shfl_up(v, d, 64);
        if (l >= d) v += o;
    }
    lcs[(size_t)(row0 + l) * 16 + h] = v;
    csW[w * 64 + l] = v;
    dtW[w * 64 + l] = dtv;
    if (l == 63) dec[blk] = __expf(v);
    __syncthreads();

    unsigned short* XtW = Xt0 + w * 4096;
    stage_xt(xc + (size_t)(row0 + l) * 1056 + h * 64, XtW, l);

    const float* csr = csW + w * 64;
    const float* dtr = dtW + w * 64;
    float cs63 = csr[63];

    f32x4_t z = {0.f, 0.f, 0.f, 0.f};
    f32x4_t hacc[4] = {z, z, z, z};
#pragma unroll
    for (int kk = 0; kk < 2; kk++) {
        int sb = kk * 32 + quad * 8;
        u16x8_t bv = *(const u16x8_t*)(Btr + r * 72 + sb);
        f32x4_t c0 = *(const f32x4_t*)(csr + sb);
        f32x4_t c1 = *(const f32x4_t*)(csr + sb + 4);
        f32x4_t d0 = *(const f32x4_t*)(dtr + sb);
        f32x4_t d1 = *(const f32x4_t*)(dtr + sb + 4);
        u16x8_t wv;
#pragma unroll
        for (int j = 0; j < 4; j++) {
            wv[j]     = f2bf(bf2f(bv[j])     * d0[j] * __expf(cs63 - c0[j]));
            wv[4 + j] = f2bf(bf2f(bv[4 + j]) * d1[j] * __expf(cs63 - c1[j]));
        }
        bf16x8_t wf = __builtin_bit_cast(bf16x8_t, wv);
#pragma unroll
        for (int jj = 0; jj < 4; jj++)
            hacc[jj] = __builtin_amdgcn_mfma_f32_16x16x32_bf16(wf, xt_frag(XtW, r, quad, jj, kk), hacc[jj], 0, 0, 0);
    }
    float* o = Hend + (size_t)blk * 1024;
#pragma unroll
    for (int jj = 0; jj < 4; jj++)
#pragma unroll
        for (int reg = 0; reg < 4; reg++)
            o[(jj * 16 + r) * 16 + quad * 4 + reg] = hacc[jj][reg];
}

// Combine: exclusive prefix over 64 chunk states per (b,h) — unchanged.
__global__ __launch_bounds__(64) void scan_comb_k(float* __restrict__ H, const float* __restrict__ dec)
{
    int bh = blockIdx.x >> 2;
    int q  = blockIdx.x & 3;
    int t  = threadIdx.x;
    float* base = H + (size_t)bh * 64 * 1024 + q * 256 + t * 4;
    const float* dp = dec + bh * 64;
    f32x4_t hs = {0.f, 0.f, 0.f, 0.f};
    f32x4_t cur = *(const f32x4_t*)base;
    for (int c = 0; c < 64; c++) {
        int cn = (c < 63) ? c + 1 : 63;
        f32x4_t nxt = *(const f32x4_t*)(base + (size_t)cn * 1024);
        float d = dp[c];
        *(f32x4_t*)(base + (size_t)c * 1024) = hs;   // exclusive prefix
#pragma unroll
        for (int j = 0; j < 4; j++) hs[j] = fmaf(hs[j], d, cur[j]);
        cur = nxt;
    }
}

__global__ __launch_bounds__(256) void scan_chout_k(
    const unsigned short* __restrict__ xc,
    const float* __restrict__ dtb, const float* __restrict__ csb,
    const float* __restrict__ Hst, const float* __restrict__ Dp,
    unsigned short* __restrict__ ybuf)  // R x 1024 bf16
{
    __shared__ __attribute__((aligned(16))) unsigned char sm[60416];
    unsigned short* Ct = (unsigned short*)sm;            // [64][32] (cols 16..31 = 0)
    unsigned short* Bt = (unsigned short*)(sm + 4096);   // [64][32]
    float* S   = (float*)(sm + 8192);                    // [64][68]
    float* csL = (float*)(sm + 25600);                   // [4][64]
    float* dtL = (float*)(sm + 26624);                   // [4][64]
    unsigned short* Xt0 = (unsigned short*)(sm + 27648); // [4][64*64]

    const int tid = threadIdx.x;
    const int w = tid >> 6, l = tid & 63;
    const int r = l & 15, quad = l >> 4;
    const int row0 = blockIdx.x * 64;
    const int b = blockIdx.x >> 6, chunk = blockIdx.x & 63;
    const int h = blockIdx.y * 4 + w;
    const int blk = ((b * 16 + h) << 6) | chunk;

    // stage padded B/C tiles
    {
        int rowi = tid >> 2, seg = tid & 3;
        u16x8_t vb, vc;
        if (seg < 2) {
            const unsigned short* src = xc + (size_t)(row0 + rowi) * 1056 + 1024 + seg * 8;
            vb = *(const u16x8_t*)src;
            vc = *(const u16x8_t*)(src + 16);
        } else {
#pragma unroll
            for (int j = 0; j < 8; j++) { vb[j] = 0; vc[j] = 0; }
        }
        *(u16x8_t*)(Bt + rowi * 32 + seg * 8) = vb;
        *(u16x8_t*)(Ct + rowi * 32 + seg * 8) = vc;
    }
    // stage cs/dt for this block's 4 heads
    csL[w * 64 + l] = csb[(size_t)(row0 + l) * 16 + h];
    dtL[w * 64 + l] = dtb[(size_t)(row0 + l) * 16 + h];
    __syncthreads();

    // S = C @ B^T : wave w computes t-rows [w*16, w*16+16)
    {
        bf16x8_t cf = __builtin_bit_cast(bf16x8_t, *(const u16x8_t*)(Ct + (w * 16 + r) * 32 + quad * 8));
        f32x4_t z = {0.f, 0.f, 0.f, 0.f};
#pragma unroll
        for (int j = 0; j < 4; j++) {
            bf16x8_t bfv = __builtin_bit_cast(bf16x8_t, *(const u16x8_t*)(Bt + (j * 16 + r) * 32 + quad * 8));
            f32x4_t d = __builtin_amdgcn_mfma_f32_16x16x32_bf16(cf, bfv, z, 0, 0, 0);
#pragma unroll
            for (int reg = 0; reg < 4; reg++)
                S[(w * 16 + quad * 4 + reg) * 68 + j * 16 + r] = d[reg];
        }
    }
    __syncthreads();

    // per-wave head section
    unsigned short* XtW = Xt0 + w * 4096;
    stage_xt(xc + (size_t)(row0 + l) * 1056 + h * 64, XtW, l);

    const float* csr = csL + w * 64;
    const float* dtr = dtL + w * 64;

    // Y_inter = C @ Hstart^T, then row-scale by exp(cs_t)
    f32x4_t acc[4][4];
    {
        bf16x8_t hf[4];
#pragma unroll
        for (int jj = 0; jj < 4; jj++) {
            int p = jj * 16 + r;
            u16x8_t hv;
            if (quad < 2) {
                const float* hp = Hst + (size_t)blk * 1024 + p * 16 + quad * 8;
                f32x4_t h0 = *(const f32x4_t*)hp;
                f32x4_t h1 = *(const f32x4_t*)(hp + 4);
#pragma unroll
                for (int j = 0; j < 4; j++) { hv[j] = f2bf(h0[j]); hv[4 + j] = f2bf(h1[j]); }
            } else {
#pragma unroll
                for (int j = 0; j < 8; j++) hv[j] = 0;
            }
            hf[jj] = __builtin_bit_cast(bf16x8_t, hv);
        }
        f32x4_t z = {0.f, 0.f, 0.f, 0.f};
#pragma unroll
        for (int i = 0; i < 4; i++) {
            bf16x8_t cf = __builtin_bit_cast(bf16x8_t, *(const u16x8_t*)(Ct + (i * 16 + r) * 32 + quad * 8));
#pragma unroll
            for (int jj = 0; jj < 4; jj++)
                acc[i][jj] = __builtin_amdgcn_mfma_f32_16x16x32_bf16(cf, hf[jj], z, 0, 0, 0);
        }
#pragma unroll
        for (int i = 0; i < 4; i++) {
            f32x4_t es;
#pragma unroll
            for (int reg = 0; reg < 4; reg++) es[reg] = __expf(csr[i * 16 + quad * 4 + reg]);
#pragma unroll
            for (int jj = 0; jj < 4; jj++)
#pragma unroll
                for (int reg = 0; reg < 4; reg++) acc[i][jj][reg] *= es[reg];
        }
    }

    // Y_intra += W @ X
#pragma unroll
    for (int kk = 0; kk < 2; kk++) {
        int sb = kk * 32 + quad * 8;
        bf16x8_t xf[4];
#pragma unroll
        for (int jj = 0; jj < 4; jj++) xf[jj] = xt_frag(XtW, r, quad, jj, kk);
        f32x4_t c0 = *(const f32x4_t*)(csr + sb);
        f32x4_t c1 = *(const f32x4_t*)(csr + sb + 4);
        f32x4_t d0 = *(const f32x4_t*)(dtr + sb);
        f32x4_t d1 = *(const f32x4_t*)(dtr + sb + 4);
#pragma unroll
        for (int i = 0; i < 4; i++) {
            int t = i * 16 + r;
            float cst = csr[t];
            const float* Srow = S + t * 68;
            f32x4_t s0 = *(const f32x4_t*)(Srow + sb);
            f32x4_t s1 = *(const f32x4_t*)(Srow + sb + 4);
            u16x8_t wv;
#pragma unroll
            for (int j = 0; j < 4; j++) {
                int s = sb + j;
                float v0 = (s <= t) ? __expf(cst - c0[j]) * d0[j] * s0[j] : 0.f;
                wv[j] = f2bf(v0);
                int s2 = sb + 4 + j;
                float v1 = (s2 <= t) ? __expf(cst - c1[j]) * d1[j] * s1[j] : 0.f;
                wv[4 + j] = f2bf(v1);
            }
            bf16x8_t wf = __builtin_bit_cast(bf16x8_t, wv);
#pragma unroll
            for (int jj = 0; jj < 4; jj++)
                acc[i][jj] = __builtin_amdgcn_mfma_f32_16x16x32_bf16(wf, xf[jj], acc[i][jj], 0, 0, 0);
        }
    }

    // D-term + store y
    float Dh = Dp[h];
#pragma unroll
    for (int i = 0; i < 4; i++) {
#pragma unroll
        for (int jj = 0; jj < 4; jj++) {
            int p = jj * 16 + r;
            int t0 = i * 16 + quad * 4;
            int blk2 = (t0 >> 3) ^ (p & 7);
            u16x4_t x4 = *(const u16x4_t*)(XtW + p * 64 + blk2 * 8 + (t0 & 7));
#pragma unroll
            for (int reg = 0; reg < 4; reg++) {
                float yv = fmaf(Dh, bf2f(x4[reg]), acc[i][jj][reg]);
                ybuf[(size_t)(row0 + t0 + reg) * 1024 + h * 64 + p] = f2bf(yv);
            }
        }
    }
}

// ---------------------------------------------------------------------------
// Gated RMSNorm (in-place on y, bf16): wave-per-row, no barriers
// ---------------------------------------------------------------------------
__global__ __launch_bounds__(256) void rmsgate_k(
    unsigned short* __restrict__ y,
    const unsigned short* __restrict__ z,
    const float* __restrict__ nw)
{
    const int wave = threadIdx.x >> 6, lane = threadIdx.x & 63;
    const size_t row = (size_t)blockIdx.x * 4 + wave;
    const int c = lane * 16;
    unsigned short* yp = y + row * 1024 + c;
    const unsigned short* zp = z + row * 1024 + c;
    u16x8_t yv0 = *(const u16x8_t*)yp;
    u16x8_t yv1 = *(const u16x8_t*)(yp + 8);
    u16x8_t zv0 = *(const u16x8_t*)zp;
    u16x8_t zv1 = *(const u16x8_t*)(zp + 8);
    float g[16];
    float ss = 0.f;
#pragma unroll
    for (int j = 0; j < 8; j++) {
        float zf = bf2f(zv0[j]);
        float sil = zf * __builtin_amdgcn_rcpf(1.f + __expf(-zf));
        g[j] = bf2f(yv0[j]) * sil;
        ss += g[j] * g[j];
    }
#pragma unroll
    for (int j = 0; j < 8; j++) {
        float zf = bf2f(zv1[j]);
        float sil = zf * __builtin_amdgcn_rcpf(1.f + __expf(-zf));
        g[8 + j] = bf2f(yv1[j]) * sil;
        ss += g[8 + j] * g[8 + j];
    }
#pragma unroll
    for (int m = 32; m > 0; m >>= 1) ss += __shfl_xor(ss, m, 64);
    float scale = rsqrtf(ss * (1.f / 1024.f) + 1e-5f);
    f32x4_t w0 = *(const f32x4_t*)(nw + c);
    f32x4_t w1 = *(const f32x4_t*)(nw + c + 4);
    f32x4_t w2 = *(const f32x4_t*)(nw + c + 8);
    f32x4_t w3 = *(const f32x4_t*)(nw + c + 12);
    u16x8_t o0, o1;
#pragma unroll
    for (int j = 0; j < 4; j++) {
        o0[j]     = f2bf(g[j]      * scale * w0[j]);
        o0[4 + j] = f2bf(g[4 + j]  * scale * w1[j]);
        o1[j]     = f2bf(g[8 + j]  * scale * w2[j]);
        o1[4 + j] = f2bf(g[12 + j] * scale * w3[j]);
    }
    *(u16x8_t*)yp = o0;
    *(u16x8_t*)(yp + 8) = o1;
}

// ---------------------------------------------------------------------------
// Final: out = LayerNorm(x + f) — wave-per-row, no barriers
// ---------------------------------------------------------------------------
__global__ __launch_bounds__(256) void ln_k(
    const float* __restrict__ x,   // R x 512 fp32
    const float* __restrict__ f,   // R x 512 fp32
    const float* __restrict__ lw,
    const float* __restrict__ lb,
    float* __restrict__ outp)      // R x 512 fp32
{
    const int wave = threadIdx.x >> 6, lane = threadIdx.x & 63;
    const size_t row = (size_t)blockIdx.x * 4 + wave;
    const int c = lane * 8;
    f32x4_t xv0 = *(const f32x4_t*)(x + row * 512 + c);
    f32x4_t xv1 = *(const f32x4_t*)(x + row * 512 + c + 4);
    f32x4_t fv0 = *(const f32x4_t*)(f + row * 512 + c);
    f32x4_t fv1 = *(const f32x4_t*)(f + row * 512 + c + 4);
    float s[8];
    float sum = 0.f, sq = 0.f;
#pragma unroll
    for (int j = 0; j < 4; j++) {
        s[j] = xv0[j] + fv0[j];
        s[4 + j] = xv1[j] + fv1[j];
    }
#pragma unroll
    for (int j = 0; j < 8; j++) { sum += s[j]; sq += s[j] * s[j]; }
#pragma unroll
    for (int m = 32; m > 0; m >>= 1) {
        sum += __shfl_xor(sum, m, 64);
        sq  += __shfl_xor(sq, m, 64);
    }
    float mu = sum * (1.f / 512.f);
    float var = sq * (1.f / 512.f) - mu * mu;
    if (var < 0.f) var = 0.f;
    float inv = rsqrtf(var + 1e-5f);
    f32x4_t w0 = *(const f32x4_t*)(lw + c);
    f32x4_t w1 = *(const f32x4_t*)(lw + c + 4);
    f32x4_t b0 = *(const f32x4_t*)(lb + c);
    f32x4_t b1 = *(const f32x4_t*)(lb + c + 4);
    f32x4_t o0, o1;
#pragma unroll
    for (int j = 0; j < 4; j++) {
        o0[j] = (s[j] - mu) * inv * w0[j] + b0[j];
        o1[j] = (s[4 + j] - mu) * inv * w1[j] + b1[j];
    }
    *(f32x4_t*)(outp + row * 512 + c) = o0;
    *(f32x4_t*)(outp + row * 512 + c + 4) = o1;
}

// ---------------------------------------------------------------------------
extern "C" void kernel_launch(void* const* d_in, const int* in_sizes, int n_in,
                              void* d_out, int out_size, void* d_ws, size_t ws_size,
                              hipStream_t stream)
{
    (void)in_sizes; (void)n_in; (void)out_size;

    const float* x           = (const float*)d_in[0];
    const float* in_proj[2]  = {(const float*)d_in[1],  (const float*)d_in[9]};
    const float* conv_w[2]   = {(const float*)d_in[2],  (const float*)d_in[10]};
    const float* conv_b[2]   = {(const float*)d_in[3],  (const float*)d_in[11]};
    const float* dt_bias[2]  = {(const float*)d_in[4],  (const float*)d_in[12]};
    const float* A_log[2]    = {(const float*)d_in[5],  (const float*)d_in[13]};
    const float* Dp[2]       = {(const float*)d_in[6],  (const float*)d_in[14]};
    const float* norm_w[2]   = {(const float*)d_in[7],  (const float*)d_in[15]};
    const float* out_proj[2] = {(const float*)d_in[8],  (const float*)d_in[16]};
    const float* proj_w      = (const float*)d_in[17];
    const float* proj_b      = (const float*)d_in[18];
    const float* ln_w        = (const float*)d_in[19];
    const float* ln_b        = (const float*)d_in[20];
    float* outp = (float*)d_out;

    const size_t IP_ELEMS = (size_t)2096 * 512;
    const size_t X_ELEMS  = (size_t)32768 * 512;

    const size_t constBytes = X_ELEMS * 2 + 2 * IP_ELEMS * 2 + 2 * 512 * 1024 * 2
                            + 2 * 512 * 512 * 2 + 2 * 1024 * 512 * 2 + 8192;
    int g = 1;
    {
        const int cands[3] = {8, 4, 2};
        for (int ci = 0; ci < 3; ci++) {
            size_t R = (size_t)cands[ci] * 4096;
            size_t need = constBytes + R * (2144 + 2112 + 2048 + 64 + 64 + 1024)
                        + (size_t)cands[ci] * 1024 * 4 + 16 * 256;
            if (need <= ws_size) { g = cands[ci]; break; }
        }
    }
    const size_t R = (size_t)g * 4096;
    const int nGroups = 8 / g;
    const int MT = (int)(R >> 7);

    char* ws = (char*)d_ws;
    size_t off = 0;
    auto alloc = [&](size_t bytes) -> char* {
        char* p = ws + off;
        off += (bytes + 255) & ~(size_t)255;
        return p;
    };
    unsigned short* xb16  = (unsigned short*)alloc(X_ELEMS * 2);
    unsigned short* ipb16[2];
    ipb16[0] = (unsigned short*)alloc(IP_ELEMS * 2);
    ipb16[1] = (unsigned short*)alloc(IP_ELEMS * 2);
    unsigned short* Ebuf  = (unsigned short*)alloc(2 * 512 * 1024 * 2);
    unsigned short* Ef    = Ebuf;
    unsigned short* Eb    = Ebuf + 512 * 1024;
    unsigned short* pwb   = (unsigned short*)alloc(2 * 512 * 512 * 2);
    unsigned short* opT   = (unsigned short*)alloc(2 * 1024 * 512 * 2);
    unsigned short* xbcdt = (unsigned short*)alloc(R * 1072 * 2);
    unsigned short* ybuf  = xbcdt;                       // alias (xbcdt dead by scan out)
    unsigned short* xconv = (unsigned short*)alloc(R * 1056 * 2);
    unsigned short* zbuf  = xconv;                       // alias (xconv dead after scans)
    float* fbuf = (float*)alloc(R * 512 * 4);
    float* dtb  = (float*)alloc(R * 16 * 4);
    float* dab  = (float*)alloc(R * 16 * 4);             // ldA -> cs (in-place in scan_chstate_k)
    float* Hbuf = (float*)alloc(R * 1024);
    float* dec  = (float*)alloc((size_t)g * 1024 * 4);

    dim3 blk(256);

    cvt_k<<<(unsigned)((X_ELEMS / 8 + 255) / 256), blk, 0, stream>>>(x, xb16, (int)(X_ELEMS / 8));
    cvt_k<<<(unsigned)((IP_ELEMS / 8 + 255) / 256), blk, 0, stream>>>(in_proj[0], ipb16[0], (int)(IP_ELEMS / 8));
    cvt_k<<<(unsigned)((IP_ELEMS / 8 + 255) / 256), blk, 0, stream>>>(in_proj[1], ipb16[1], (int)(IP_ELEMS / 8));
    pack_pw_k<<<256, blk, 0, stream>>>(proj_w, pwb);
    tr_op_k<<<dim3(32, 16, 2), blk, 0, stream>>>(out_proj[0], out_proj[1], opT);
    gemm_bt<false, false, false, false, false><<<dim3(8, 4), blk, 0, stream>>>(
        pwb, opT, Ef, nullptr, 1024, 512, 1024, 0);
    gemm_bt<false, false, false, false, false><<<dim3(8, 4), blk, 0, stream>>>(
        pwb + 512 * 512, opT + 1024 * 512, Eb, nullptr, 1024, 512, 1024, 0);

    for (int grp = 0; grp < nGroups; grp++) {
        const unsigned short* xg = xb16 + (size_t)grp * R * 512;
        const float* xgf = x + (size_t)grp * R * 512;
        float* og = outp + (size_t)grp * R * 512;

        for (int dir = 0; dir < 2; dir++) {
            if (dir == 0)
                gemm_bt<false, false, false, false, false><<<dim3(9, MT), blk, 0, stream>>>(
                    xg, ipb16[0] + (size_t)1024 * 512, xbcdt, nullptr, 1072, 512, 1072, 0);
            else
                gemm_bt<true, false, false, false, false><<<dim3(9, MT), blk, 0, stream>>>(
                    xg, ipb16[1] + (size_t)1024 * 512, xbcdt, nullptr, 1072, 512, 1072, 0);

            conv_silu_k<<<(unsigned)(R * 132 / 2048), blk, 0, stream>>>(xbcdt, conv_w[dir], conv_b[dir], xconv);
            dt_pre_k<<<(unsigned)(R * 16 / 256), blk, 0, stream>>>(xbcdt, dt_bias[dir], A_log[dir], dtb, dab);

            scan_chstate_k<<<dim3((unsigned)(R / 64), 4), blk, 0, stream>>>(xconv, dtb, dab, Hbuf, dec);
            scan_comb_k<<<(unsigned)(g * 64), dim3(64), 0, stream>>>(Hbuf, dec);
            scan_chout_k<<<dim3((unsigned)(R / 64), 4), blk, 0, stream>>>(xconv, dtb, dab, Hbuf, Dp[dir], ybuf);

            if (dir == 0)
                gemm_bt<false, false, false, false, false><<<dim3(8, MT), blk, 0, stream>>>(
                    xg, ipb16[0], zbuf, nullptr, 1024, 512, 1024, 0);
            else
                gemm_bt<true, false, false, false, false><<<dim3(8, MT), blk, 0, stream>>>(
                    xg, ipb16[1], zbuf, nullptr, 1024, 512, 1024, 0);

            rmsgate_k<<<(unsigned)(R / 4), blk, 0, stream>>>(ybuf, zbuf, norm_w[dir]);

            if (dir == 0)
                gemm_bt<false, false, true, true, false><<<dim3(4, MT), blk, 0, stream>>>(
                    ybuf, Ef, fbuf, proj_b, 512, 1024, 512, 0);
            else
                gemm_bt<false, true, true, false, true><<<dim3(4, MT), blk, 0, stream>>>(
                    ybuf, Eb, fbuf, nullptr, 512, 1024, 512, 0);
        }
        ln_k<<<(unsigned)(R / 4), blk, 0, stream>>>(xgf, fbuf, ln_w, ln_b, og);
    }
}

// Round 6
// 911.604 us; speedup vs baseline: 1.4125x; 1.0447x over previous
//
#include <hip/hip_runtime.h>
#include <hip/hip_bf16.h>
#include <math.h>

typedef __bf16 bf16x8_t __attribute__((ext_vector_type(8)));
typedef float f32x4_t __attribute__((ext_vector_type(4)));
typedef unsigned short u16x8_t __attribute__((ext_vector_type(8)));
typedef unsigned short u16x4_t __attribute__((ext_vector_type(4)));

#define DEV __device__ __forceinline__

DEV float bf2f(unsigned short u) {
    unsigned int v = ((unsigned int)u) << 16;
    return __builtin_bit_cast(float, v);
}
DEV unsigned short f2bf(float f) {
    unsigned int u = __builtin_bit_cast(unsigned int, f);
    u += 0x7fffu + ((u >> 16) & 1u);   // RNE
    return (unsigned short)(u >> 16);
}

// ---------------------------------------------------------------------------
// fp32 -> bf16 conversion (8 elems/thread)
// ---------------------------------------------------------------------------
__global__ __launch_bounds__(256) void cvt_k(
    const float* __restrict__ in, unsigned short* __restrict__ out, int n8)
{
    int t = blockIdx.x * 256 + threadIdx.x;
    if (t >= n8) return;
    f32x4_t a = ((const f32x4_t*)in)[t * 2];
    f32x4_t b = ((const f32x4_t*)in)[t * 2 + 1];
    u16x8_t o;
#pragma unroll
    for (int j = 0; j < 4; j++) { o[j] = f2bf(a[j]); o[4 + j] = f2bf(b[j]); }
    ((u16x8_t*)out)[t] = o;
}

// ---------------------------------------------------------------------------
// MFMA GEMM:  C[M x N] = A'[M x K] @ W[N x K]^T   (bf16 in, fp32 accum)
// 128x128 tile, BK=32, global_load_lds width-16 staging, XOR-swizzled chunks.
// NT>0: 1-D grid with XCD-chunked bijective swizzle — all NT N-tiles of an
// M-panel land on one XCD so the A-panel is fetched from HBM once (L2 reuse).
// NT==0: plain 2-D grid (small prep GEMMs).
// ---------------------------------------------------------------------------
template <int NT, bool FLIP_A, bool FLIP_C, bool OUT_F32, bool ADD_BIAS, bool ACCUM>
__global__ __launch_bounds__(256, 2) void gemm_bt(
    const unsigned short* __restrict__ A,
    const unsigned short* __restrict__ W,
    void* __restrict__ Cout,
    const float* __restrict__ bias,
    int N, int K, int ldc, int col_ofs)
{
    __shared__ __attribute__((aligned(16))) unsigned char smem[16384]; // A: 8KB, W: 8KB
    const int tid  = threadIdx.x;
    const int wave = tid >> 6;
    const int lane = tid & 63;

    int mtile_i, ntile_i;
    if (NT == 0) {
        mtile_i = blockIdx.y;
        ntile_i = blockIdx.x;
    } else {
        const int L = blockIdx.x;
        const int MTl = (int)gridDim.x / NT;   // M-tiles; always % 8 == 0 here
        const int ppx = MTl >> 3;              // M-panels per XCD
        const int xcd = L & 7, q = L >> 3;
        mtile_i = xcd * ppx + q / NT;
        ntile_i = q % NT;
    }
    const int mtile = mtile_i << 7;
    const int ntile = ntile_i << 7;

    const int c0 = tid, c1 = 256 + tid;
    const int r0 = c0 >> 2, p0 = c0 & 3, g0 = p0 ^ ((r0 >> 1) & 3);
    const int r1 = c1 >> 2, p1 = c1 & 3, g1 = p1 ^ ((r1 >> 1) & 3);

    int am0 = mtile + r0; if (FLIP_A) am0 ^= 4095;
    int am1 = mtile + r1; if (FLIP_A) am1 ^= 4095;
    const unsigned short* aP0 = A + (size_t)am0 * K + g0 * 8;
    const unsigned short* aP1 = A + (size_t)am1 * K + g1 * 8;

    int wr0 = ntile + r0; if (wr0 > N - 1) wr0 = N - 1;
    int wr1 = ntile + r1; if (wr1 > N - 1) wr1 = N - 1;
    const unsigned short* wP0 = W + (size_t)wr0 * K + g0 * 8;
    const unsigned short* wP1 = W + (size_t)wr1 * K + g1 * 8;

    unsigned char* ldsA = smem;
    unsigned char* ldsW = smem + 8192;
    unsigned char* ldsA0 = ldsA + wave * 1024;          // wave-uniform bases
    unsigned char* ldsA1 = ldsA + 4096 + wave * 1024;
    unsigned char* ldsW0 = ldsW + wave * 1024;
    unsigned char* ldsW1 = ldsW + 4096 + wave * 1024;

    f32x4_t acc[4][4] = {};

    const int wm = (wave & 1) << 6;
    const int wn = (wave >> 1) << 6;
    const int r    = lane & 15;
    const int quad = lane >> 4;
    const int sw   = (r >> 1) & 3;

    int aoff[4], woff[4];
#pragma unroll
    for (int i = 0; i < 4; i++) {
        int m = wm + i * 16 + r;
        aoff[i] = (m * 4 + (quad ^ sw)) * 16;
        int n = wn + i * 16 + r;
        woff[i] = (n * 4 + (quad ^ sw)) * 16;
    }

    for (int k0 = 0; k0 < K; k0 += 32) {
        __builtin_amdgcn_global_load_lds(
            (const __attribute__((address_space(1))) void*)(aP0 + k0),
            (__attribute__((address_space(3))) void*)ldsA0, 16, 0, 0);
        __builtin_amdgcn_global_load_lds(
            (const __attribute__((address_space(1))) void*)(aP1 + k0),
            (__attribute__((address_space(3))) void*)ldsA1, 16, 0, 0);
        __builtin_amdgcn_global_load_lds(
            (const __attribute__((address_space(1))) void*)(wP0 + k0),
            (__attribute__((address_space(3))) void*)ldsW0, 16, 0, 0);
        __builtin_amdgcn_global_load_lds(
            (const __attribute__((address_space(1))) void*)(wP1 + k0),
            (__attribute__((address_space(3))) void*)ldsW1, 16, 0, 0);
        __syncthreads();

        bf16x8_t af[4], wf[4];
#pragma unroll
        for (int i = 0; i < 4; i++)
            af[i] = __builtin_bit_cast(bf16x8_t, *(const u16x8_t*)(ldsA + aoff[i]));
#pragma unroll
        for (int j = 0; j < 4; j++)
            wf[j] = __builtin_bit_cast(bf16x8_t, *(const u16x8_t*)(ldsW + woff[j]));
#pragma unroll
        for (int i = 0; i < 4; i++)
#pragma unroll
            for (int j = 0; j < 4; j++)
                acc[i][j] = __builtin_amdgcn_mfma_f32_16x16x32_bf16(af[i], wf[j], acc[i][j], 0, 0, 0);
        __syncthreads();
    }

    // epilogue: C/D layout col=lane&15, row=quad*4+reg
#pragma unroll
    for (int i = 0; i < 4; i++) {
#pragma unroll
        for (int j = 0; j < 4; j++) {
            int cc = ntile + wn + j * 16 + r;
            if (cc >= N) continue;
#pragma unroll
            for (int reg = 0; reg < 4; reg++) {
                int rr = mtile + wm + i * 16 + quad * 4 + reg;
                int orow = FLIP_C ? (rr ^ 4095) : rr;
                float v = acc[i][j][reg];
                if (ADD_BIAS) v += bias[cc];
                if (OUT_F32) {
                    float* p = (float*)Cout + (size_t)orow * ldc + col_ofs + cc;
                    if (ACCUM) v += *p;
                    *p = v;
                } else {
                    ((unsigned short*)Cout)[(size_t)orow * ldc + col_ofs + cc] = f2bf(v);
                }
            }
        }
    }
}

// ---------------------------------------------------------------------------
// pack proj_w slices to bf16: pwb[dir][n][j] = bf16(pw[n][dir*512+j])
// ---------------------------------------------------------------------------
__global__ __launch_bounds__(256) void pack_pw_k(
    const float* __restrict__ pw, unsigned short* __restrict__ pwb)
{
    int t = blockIdx.x * 256 + threadIdx.x;   // 65536 threads, 8 elems each
    int j8 = t & 63;
    int n  = (t >> 6) & 511;
    int dir = t >> 15;
    const float* src = pw + (size_t)n * 1024 + dir * 512 + j8 * 8;
    f32x4_t a = *(const f32x4_t*)src;
    f32x4_t b = *(const f32x4_t*)(src + 4);
    u16x8_t o;
#pragma unroll
    for (int j = 0; j < 4; j++) { o[j] = f2bf(a[j]); o[4 + j] = f2bf(b[j]); }
    *(u16x8_t*)(pwb + (size_t)dir * 512 * 512 + (size_t)n * 512 + j8 * 8) = o;
}

// ---------------------------------------------------------------------------
// transpose out_proj to bf16: opT[dir][k][j] = bf16(op_dir[j][k])
// ---------------------------------------------------------------------------
__global__ __launch_bounds__(256) void tr_op_k(
    const float* __restrict__ op0, const float* __restrict__ op1,
    unsigned short* __restrict__ opT)
{
    __shared__ float tile[32][33];
    const int dir = blockIdx.z;
    const float* op = dir ? op1 : op0;
    const int k0 = blockIdx.x * 32;
    const int j0 = blockIdx.y * 32;
    const int tx = threadIdx.x & 31, ty = threadIdx.x >> 5;
#pragma unroll
    for (int i = 0; i < 4; i++) {
        int j = j0 + ty + i * 8;
        tile[ty + i * 8][tx] = op[(size_t)j * 1024 + k0 + tx];
    }
    __syncthreads();
    unsigned short* dst = opT + (size_t)dir * 1024 * 512;
#pragma unroll
    for (int i = 0; i < 4; i++) {
        int k = k0 + ty + i * 8;
        dst[(size_t)k * 512 + j0 + tx] = f2bf(tile[tx][ty + i * 8]);
    }
}

// ---------------------------------------------------------------------------
// Depthwise causal conv (width 4) + SiLU, 8 rows/thread sliding window.
// ---------------------------------------------------------------------------
__global__ __launch_bounds__(256) void conv_silu_k(
    const unsigned short* __restrict__ xin,  // R x 1072 bf16
    const float* __restrict__ cw,            // 1056 x 4 fp32
    const float* __restrict__ cb,            // 1056 fp32
    unsigned short* __restrict__ outp)       // R x 1056 bf16
{
    int t = blockIdx.x * 256 + threadIdx.x;
    int c8 = t % 132;
    int rb = t / 132;
    int c = c8 * 8;
    int row0 = rb * 8;
    int l0 = row0 & 4095;

    float w[8][4];
#pragma unroll
    for (int j = 0; j < 8; j++) {
        f32x4_t wv = *(const f32x4_t*)(cw + (c + j) * 4);
        w[j][0] = wv[0]; w[j][1] = wv[1]; w[j][2] = wv[2]; w[j][3] = wv[3];
    }
    float bia[8];
    {
        f32x4_t b0 = *(const f32x4_t*)(cb + c);
        f32x4_t b1 = *(const f32x4_t*)(cb + c + 4);
#pragma unroll
        for (int j = 0; j < 4; j++) { bia[j] = b0[j]; bia[4 + j] = b1[j]; }
    }

    u16x8_t zero;
#pragma unroll
    for (int j = 0; j < 8; j++) zero[j] = 0;

    // window rows row0-3 .. row0+7 (11 rows); pre-batch rows are zero
    u16x8_t win[11];
#pragma unroll
    for (int u = 0; u < 11; u++) {
        int lu = l0 - 3 + u;
        win[u] = (lu >= 0)
            ? *(const u16x8_t*)(xin + (size_t)(row0 - 3 + u) * 1072 + c)
            : zero;
    }

#pragma unroll
    for (int s = 0; s < 8; s++) {
        float acc[8];
#pragma unroll
        for (int j = 0; j < 8; j++) acc[j] = bia[j];
#pragma unroll
        for (int k = 0; k < 4; k++) {
            u16x8_t xv = win[s + k];
#pragma unroll
            for (int j = 0; j < 8; j++)
                acc[j] = fmaf(bf2f(xv[j]), w[j][k], acc[j]);
        }
        u16x8_t o;
#pragma unroll
        for (int j = 0; j < 8; j++) {
            float xx = acc[j];
            o[j] = f2bf(xx * __builtin_amdgcn_rcpf(1.f + __expf(-xx)));
        }
        *(u16x8_t*)(outp + (size_t)(row0 + s) * 1056 + c) = o;
    }
}

// ---------------------------------------------------------------------------
// dt = softplus(dt_raw + dt_bias), ldA = dt * -exp(A_log)  (log of dA)
// ---------------------------------------------------------------------------
__global__ __launch_bounds__(256) void dt_pre_k(
    const unsigned short* __restrict__ xin,  // R x 1072 bf16 (dt raw at 1056..1071)
    const float* __restrict__ dt_bias,
    const float* __restrict__ A_log,
    float* __restrict__ dtb, float* __restrict__ ldab)
{
    int t = blockIdx.x * 256 + threadIdx.x;  // R*16
    int h = t & 15;
    int row = t >> 4;
    float x = bf2f(xin[(size_t)row * 1072 + 1056 + h]) + dt_bias[h];
    float dt = (x > 20.f) ? x : log1pf(__expf(x));
    float A = -__expf(A_log[h]);
    dtb[t] = dt;
    ldab[t] = dt * A;       // log(dA); cumsum later (exact: dA = exp(dt*A))
}

// ---------------------------------------------------------------------------
// Chunked scan as MFMA GEMMs (Mamba2 SSD formulation), chunk = 64.
// ---------------------------------------------------------------------------
DEV void stage_xt(const unsigned short* __restrict__ xrow, unsigned short* XtW, int l)
{
    u16x8_t xv[8];
#pragma unroll
    for (int m = 0; m < 8; m++) xv[m] = *(const u16x8_t*)(xrow + m * 8);
#pragma unroll
    for (int p = 0; p < 64; p++) {
        int blkc = (l >> 3) ^ (p & 7);
        XtW[p * 64 + blkc * 8 + (l & 7)] = xv[p >> 3][p & 7];
    }
}

DEV bf16x8_t xt_frag(const unsigned short* XtW, int r, int quad, int jj, int kk)
{
    int p = jj * 16 + r;
    int blkc = (kk * 4 + quad) ^ (p & 7);
    return __builtin_bit_cast(bf16x8_t, *(const u16x8_t*)(XtW + p * 64 + blkc * 8));
}

__global__ __launch_bounds__(256) void scan_chstate_k(
    const unsigned short* __restrict__ xc,   // R x 1056 bf16
    const float* __restrict__ dtb,
    float* __restrict__ lcs,                 // in: ldA ; out: cs (in-place, same elem)
    float* __restrict__ Hend, float* __restrict__ dec)
{
    __shared__ __attribute__((aligned(16))) unsigned char sm[37120];
    unsigned short* Btr = (unsigned short*)sm;          // [16][72] bf16 (B transposed)
    float* csW = (float*)(sm + 2304);                   // [4][64]
    float* dtW = (float*)(sm + 3328);                   // [4][64]
    unsigned short* Xt0 = (unsigned short*)(sm + 4352); // [4][64*64]

    const int tid = threadIdx.x;
    const int w = tid >> 6, l = tid & 63;
    const int r = l & 15, quad = l >> 4;
    const int row0 = blockIdx.x * 64;
    const int b = blockIdx.x >> 6, chunk = blockIdx.x & 63;
    const int h = blockIdx.y * 4 + w;
    const int blk = ((b * 16 + h) << 6) | chunk;

    // stage Bt[n][s] = B[s][n]
    {
        int n = tid & 15, s0 = (tid >> 4) * 4;
#pragma unroll
        for (int js = 0; js < 4; js++) {
            int s = s0 + js;
            Btr[n * 72 + s] = xc[(size_t)(row0 + s) * 1056 + 1024 + n];
        }
    }

    // per-lane ldA/dt + inclusive wave scan -> cs
    float v   = lcs[(size_t)(row0 + l) * 16 + h];
    float dtv = dtb[(size_t)(row0 + l) * 16 + h];
#pragma unroll
    for (int d = 1; d < 64; d <<= 1) {
        float o = __shfl_up(v, d, 64);
        if (l >= d) v += o;
    }
    lcs[(size_t)(row0 + l) * 16 + h] = v;
    csW[w * 64 + l] = v;
    dtW[w * 64 + l] = dtv;
    if (l == 63) dec[blk] = __expf(v);
    __syncthreads();

    unsigned short* XtW = Xt0 + w * 4096;
    stage_xt(xc + (size_t)(row0 + l) * 1056 + h * 64, XtW, l);

    const float* csr = csW + w * 64;
    const float* dtr = dtW + w * 64;
    float cs63 = csr[63];

    f32x4_t z = {0.f, 0.f, 0.f, 0.f};
    f32x4_t hacc[4] = {z, z, z, z};
#pragma unroll
    for (int kk = 0; kk < 2; kk++) {
        int sb = kk * 32 + quad * 8;
        u16x8_t bv = *(const u16x8_t*)(Btr + r * 72 + sb);
        f32x4_t c0 = *(const f32x4_t*)(csr + sb);
        f32x4_t c1 = *(const f32x4_t*)(csr + sb + 4);
        f32x4_t d0 = *(const f32x4_t*)(dtr + sb);
        f32x4_t d1 = *(const f32x4_t*)(dtr + sb + 4);
        u16x8_t wv;
#pragma unroll
        for (int j = 0; j < 4; j++) {
            wv[j]     = f2bf(bf2f(bv[j])     * d0[j] * __expf(cs63 - c0[j]));
            wv[4 + j] = f2bf(bf2f(bv[4 + j]) * d1[j] * __expf(cs63 - c1[j]));
        }
        bf16x8_t wf = __builtin_bit_cast(bf16x8_t, wv);
#pragma unroll
        for (int jj = 0; jj < 4; jj++)
            hacc[jj] = __builtin_amdgcn_mfma_f32_16x16x32_bf16(wf, xt_frag(XtW, r, quad, jj, kk), hacc[jj], 0, 0, 0);
    }
    float* o = Hend + (size_t)blk * 1024;
#pragma unroll
    for (int jj = 0; jj < 4; jj++)
#pragma unroll
        for (int reg = 0; reg < 4; reg++)
            o[(jj * 16 + r) * 16 + quad * 4 + reg] = hacc[jj][reg];
}

// Combine: exclusive prefix over 64 chunk states per (b,h) — unchanged.
__global__ __launch_bounds__(64) void scan_comb_k(float* __restrict__ H, const float* __restrict__ dec)
{
    int bh = blockIdx.x >> 2;
    int q  = blockIdx.x & 3;
    int t  = threadIdx.x;
    float* base = H + (size_t)bh * 64 * 1024 + q * 256 + t * 4;
    const float* dp = dec + bh * 64;
    f32x4_t hs = {0.f, 0.f, 0.f, 0.f};
    f32x4_t cur = *(const f32x4_t*)base;
    for (int c = 0; c < 64; c++) {
        int cn = (c < 63) ? c + 1 : 63;
        f32x4_t nxt = *(const f32x4_t*)(base + (size_t)cn * 1024);
        float d = dp[c];
        *(f32x4_t*)(base + (size_t)c * 1024) = hs;   // exclusive prefix
#pragma unroll
        for (int j = 0; j < 4; j++) hs[j] = fmaf(hs[j], d, cur[j]);
        cur = nxt;
    }
}

__global__ __launch_bounds__(256) void scan_chout_k(
    const unsigned short* __restrict__ xc,
    const float* __restrict__ dtb, const float* __restrict__ csb,
    const float* __restrict__ Hst, const float* __restrict__ Dp,
    unsigned short* __restrict__ ybuf)  // R x 1024 bf16
{
    __shared__ __attribute__((aligned(16))) unsigned char sm[60416];
    unsigned short* Ct = (unsigned short*)sm;            // [64][32] (cols 16..31 = 0)
    unsigned short* Bt = (unsigned short*)(sm + 4096);   // [64][32]
    float* S   = (float*)(sm + 8192);                    // [64][68]
    float* csL = (float*)(sm + 25600);                   // [4][64]
    float* dtL = (float*)(sm + 26624);                   // [4][64]
    unsigned short* Xt0 = (unsigned short*)(sm + 27648); // [4][64*64]

    const int tid = threadIdx.x;
    const int w = tid >> 6, l = tid & 63;
    const int r = l & 15, quad = l >> 4;
    const int row0 = blockIdx.x * 64;
    const int b = blockIdx.x >> 6, chunk = blockIdx.x & 63;
    const int h = blockIdx.y * 4 + w;
    const int blk = ((b * 16 + h) << 6) | chunk;

    // stage padded B/C tiles
    {
        int rowi = tid >> 2, seg = tid & 3;
        u16x8_t vb, vc;
        if (seg < 2) {
            const unsigned short* src = xc + (size_t)(row0 + rowi) * 1056 + 1024 + seg * 8;
            vb = *(const u16x8_t*)src;
            vc = *(const u16x8_t*)(src + 16);
        } else {
#pragma unroll
            for (int j = 0; j < 8; j++) { vb[j] = 0; vc[j] = 0; }
        }
        *(u16x8_t*)(Bt + rowi * 32 + seg * 8) = vb;
        *(u16x8_t*)(Ct + rowi * 32 + seg * 8) = vc;
    }
    // stage cs/dt for this block's 4 heads
    csL[w * 64 + l] = csb[(size_t)(row0 + l) * 16 + h];
    dtL[w * 64 + l] = dtb[(size_t)(row0 + l) * 16 + h];
    __syncthreads();

    // S = C @ B^T : wave w computes t-rows [w*16, w*16+16)
    {
        bf16x8_t cf = __builtin_bit_cast(bf16x8_t, *(const u16x8_t*)(Ct + (w * 16 + r) * 32 + quad * 8));
        f32x4_t z = {0.f, 0.f, 0.f, 0.f};
#pragma unroll
        for (int j = 0; j < 4; j++) {
            bf16x8_t bfv = __builtin_bit_cast(bf16x8_t, *(const u16x8_t*)(Bt + (j * 16 + r) * 32 + quad * 8));
            f32x4_t d = __builtin_amdgcn_mfma_f32_16x16x32_bf16(cf, bfv, z, 0, 0, 0);
#pragma unroll
            for (int reg = 0; reg < 4; reg++)
                S[(w * 16 + quad * 4 + reg) * 68 + j * 16 + r] = d[reg];
        }
    }
    __syncthreads();

    // per-wave head section
    unsigned short* XtW = Xt0 + w * 4096;
    stage_xt(xc + (size_t)(row0 + l) * 1056 + h * 64, XtW, l);

    const float* csr = csL + w * 64;
    const float* dtr = dtL + w * 64;

    // Y_inter = C @ Hstart^T, then row-scale by exp(cs_t)
    f32x4_t acc[4][4];
    {
        bf16x8_t hf[4];
#pragma unroll
        for (int jj = 0; jj < 4; jj++) {
            int p = jj * 16 + r;
            u16x8_t hv;
            if (quad < 2) {
                const float* hp = Hst + (size_t)blk * 1024 + p * 16 + quad * 8;
                f32x4_t h0 = *(const f32x4_t*)hp;
                f32x4_t h1 = *(const f32x4_t*)(hp + 4);
#pragma unroll
                for (int j = 0; j < 4; j++) { hv[j] = f2bf(h0[j]); hv[4 + j] = f2bf(h1[j]); }
            } else {
#pragma unroll
                for (int j = 0; j < 8; j++) hv[j] = 0;
            }
            hf[jj] = __builtin_bit_cast(bf16x8_t, hv);
        }
        f32x4_t z = {0.f, 0.f, 0.f, 0.f};
#pragma unroll
        for (int i = 0; i < 4; i++) {
            bf16x8_t cf = __builtin_bit_cast(bf16x8_t, *(const u16x8_t*)(Ct + (i * 16 + r) * 32 + quad * 8));
#pragma unroll
            for (int jj = 0; jj < 4; jj++)
                acc[i][jj] = __builtin_amdgcn_mfma_f32_16x16x32_bf16(cf, hf[jj], z, 0, 0, 0);
        }
#pragma unroll
        for (int i = 0; i < 4; i++) {
            f32x4_t es;
#pragma unroll
            for (int reg = 0; reg < 4; reg++) es[reg] = __expf(csr[i * 16 + quad * 4 + reg]);
#pragma unroll
            for (int jj = 0; jj < 4; jj++)
#pragma unroll
                for (int reg = 0; reg < 4; reg++) acc[i][jj][reg] *= es[reg];
        }
    }

    // Y_intra += W @ X
#pragma unroll
    for (int kk = 0; kk < 2; kk++) {
        int sb = kk * 32 + quad * 8;
        bf16x8_t xf[4];
#pragma unroll
        for (int jj = 0; jj < 4; jj++) xf[jj] = xt_frag(XtW, r, quad, jj, kk);
        f32x4_t c0 = *(const f32x4_t*)(csr + sb);
        f32x4_t c1 = *(const f32x4_t*)(csr + sb + 4);
        f32x4_t d0 = *(const f32x4_t*)(dtr + sb);
        f32x4_t d1 = *(const f32x4_t*)(dtr + sb + 4);
#pragma unroll
        for (int i = 0; i < 4; i++) {
            int t = i * 16 + r;
            float cst = csr[t];
            const float* Srow = S + t * 68;
            f32x4_t s0 = *(const f32x4_t*)(Srow + sb);
            f32x4_t s1 = *(const f32x4_t*)(Srow + sb + 4);
            u16x8_t wv;
#pragma unroll
            for (int j = 0; j < 4; j++) {
                int s = sb + j;
                float v0 = (s <= t) ? __expf(cst - c0[j]) * d0[j] * s0[j] : 0.f;
                wv[j] = f2bf(v0);
                int s2 = sb + 4 + j;
                float v1 = (s2 <= t) ? __expf(cst - c1[j]) * d1[j] * s1[j] : 0.f;
                wv[4 + j] = f2bf(v1);
            }
            bf16x8_t wf = __builtin_bit_cast(bf16x8_t, wv);
#pragma unroll
            for (int jj = 0; jj < 4; jj++)
                acc[i][jj] = __builtin_amdgcn_mfma_f32_16x16x32_bf16(wf, xf[jj], acc[i][jj], 0, 0, 0);
        }
    }

    // D-term + store y
    float Dh = Dp[h];
#pragma unroll
    for (int i = 0; i < 4; i++) {
#pragma unroll
        for (int jj = 0; jj < 4; jj++) {
            int p = jj * 16 + r;
            int t0 = i * 16 + quad * 4;
            int blk2 = (t0 >> 3) ^ (p & 7);
            u16x4_t x4 = *(const u16x4_t*)(XtW + p * 64 + blk2 * 8 + (t0 & 7));
#pragma unroll
            for (int reg = 0; reg < 4; reg++) {
                float yv = fmaf(Dh, bf2f(x4[reg]), acc[i][jj][reg]);
                ybuf[(size_t)(row0 + t0 + reg) * 1024 + h * 64 + p] = f2bf(yv);
            }
        }
    }
}

// ---------------------------------------------------------------------------
// Gated RMSNorm (in-place on y, bf16): wave-per-row, no barriers
// ---------------------------------------------------------------------------
__global__ __launch_bounds__(256) void rmsgate_k(
    unsigned short* __restrict__ y,
    const unsigned short* __restrict__ z,
    const float* __restrict__ nw)
{
    const int wave = threadIdx.x >> 6, lane = threadIdx.x & 63;
    const size_t row = (size_t)blockIdx.x * 4 + wave;
    const int c = lane * 16;
    unsigned short* yp = y + row * 1024 + c;
    const unsigned short* zp = z + row * 1024 + c;
    u16x8_t yv0 = *(const u16x8_t*)yp;
    u16x8_t yv1 = *(const u16x8_t*)(yp + 8);
    u16x8_t zv0 = *(const u16x8_t*)zp;
    u16x8_t zv1 = *(const u16x8_t*)(zp + 8);
    float g[16];
    float ss = 0.f;
#pragma unroll
    for (int j = 0; j < 8; j++) {
        float zf = bf2f(zv0[j]);
        float sil = zf * __builtin_amdgcn_rcpf(1.f + __expf(-zf));
        g[j] = bf2f(yv0[j]) * sil;
        ss += g[j] * g[j];
    }
#pragma unroll
    for (int j = 0; j < 8; j++) {
        float zf = bf2f(zv1[j]);
        float sil = zf * __builtin_amdgcn_rcpf(1.f + __expf(-zf));
        g[8 + j] = bf2f(yv1[j]) * sil;
        ss += g[8 + j] * g[8 + j];
    }
#pragma unroll
    for (int m = 32; m > 0; m >>= 1) ss += __shfl_xor(ss, m, 64);
    float scale = rsqrtf(ss * (1.f / 1024.f) + 1e-5f);
    f32x4_t w0 = *(const f32x4_t*)(nw + c);
    f32x4_t w1 = *(const f32x4_t*)(nw + c + 4);
    f32x4_t w2 = *(const f32x4_t*)(nw + c + 8);
    f32x4_t w3 = *(const f32x4_t*)(nw + c + 12);
    u16x8_t o0, o1;
#pragma unroll
    for (int j = 0; j < 4; j++) {
        o0[j]     = f2bf(g[j]      * scale * w0[j]);
        o0[4 + j] = f2bf(g[4 + j]  * scale * w1[j]);
        o1[j]     = f2bf(g[8 + j]  * scale * w2[j]);
        o1[4 + j] = f2bf(g[12 + j] * scale * w3[j]);
    }
    *(u16x8_t*)yp = o0;
    *(u16x8_t*)(yp + 8) = o1;
}

// ---------------------------------------------------------------------------
// Final: out = LayerNorm(x + f) — wave-per-row, no barriers
// ---------------------------------------------------------------------------
__global__ __launch_bounds__(256) void ln_k(
    const float* __restrict__ x,   // R x 512 fp32
    const float* __restrict__ f,   // R x 512 fp32
    const float* __restrict__ lw,
    const float* __restrict__ lb,
    float* __restrict__ outp)      // R x 512 fp32
{
    const int wave = threadIdx.x >> 6, lane = threadIdx.x & 63;
    const size_t row = (size_t)blockIdx.x * 4 + wave;
    const int c = lane * 8;
    f32x4_t xv0 = *(const f32x4_t*)(x + row * 512 + c);
    f32x4_t xv1 = *(const f32x4_t*)(x + row * 512 + c + 4);
    f32x4_t fv0 = *(const f32x4_t*)(f + row * 512 + c);
    f32x4_t fv1 = *(const f32x4_t*)(f + row * 512 + c + 4);
    float s[8];
    float sum = 0.f, sq = 0.f;
#pragma unroll
    for (int j = 0; j < 4; j++) {
        s[j] = xv0[j] + fv0[j];
        s[4 + j] = xv1[j] + fv1[j];
    }
#pragma unroll
    for (int j = 0; j < 8; j++) { sum += s[j]; sq += s[j] * s[j]; }
#pragma unroll
    for (int m = 32; m > 0; m >>= 1) {
        sum += __shfl_xor(sum, m, 64);
        sq  += __shfl_xor(sq, m, 64);
    }
    float mu = sum * (1.f / 512.f);
    float var = sq * (1.f / 512.f) - mu * mu;
    if (var < 0.f) var = 0.f;
    float inv = rsqrtf(var + 1e-5f);
    f32x4_t w0 = *(const f32x4_t*)(lw + c);
    f32x4_t w1 = *(const f32x4_t*)(lw + c + 4);
    f32x4_t b0 = *(const f32x4_t*)(lb + c);
    f32x4_t b1 = *(const f32x4_t*)(lb + c + 4);
    f32x4_t o0, o1;
#pragma unroll
    for (int j = 0; j < 4; j++) {
        o0[j] = (s[j] - mu) * inv * w0[j] + b0[j];
        o1[j] = (s[4 + j] - mu) * inv * w1[j] + b1[j];
    }
    *(f32x4_t*)(outp + row * 512 + c) = o0;
    *(f32x4_t*)(outp + row * 512 + c + 4) = o1;
}

// ---------------------------------------------------------------------------
extern "C" void kernel_launch(void* const* d_in, const int* in_sizes, int n_in,
                              void* d_out, int out_size, void* d_ws, size_t ws_size,
                              hipStream_t stream)
{
    (void)in_sizes; (void)n_in; (void)out_size;

    const float* x           = (const float*)d_in[0];
    const float* in_proj[2]  = {(const float*)d_in[1],  (const float*)d_in[9]};
    const float* conv_w[2]   = {(const float*)d_in[2],  (const float*)d_in[10]};
    const float* conv_b[2]   = {(const float*)d_in[3],  (const float*)d_in[11]};
    const float* dt_bias[2]  = {(const float*)d_in[4],  (const float*)d_in[12]};
    const float* A_log[2]    = {(const float*)d_in[5],  (const float*)d_in[13]};
    const float* Dp[2]       = {(const float*)d_in[6],  (const float*)d_in[14]};
    const float* norm_w[2]   = {(const float*)d_in[7],  (const float*)d_in[15]};
    const float* out_proj[2] = {(const float*)d_in[8],  (const float*)d_in[16]};
    const float* proj_w      = (const float*)d_in[17];
    const float* proj_b      = (const float*)d_in[18];
    const float* ln_w        = (const float*)d_in[19];
    const float* ln_b        = (const float*)d_in[20];
    float* outp = (float*)d_out;

    const size_t IP_ELEMS = (size_t)2096 * 512;
    const size_t X_ELEMS  = (size_t)32768 * 512;

    const size_t constBytes = X_ELEMS * 2 + 2 * IP_ELEMS * 2 + 2 * 512 * 1024 * 2
                            + 2 * 512 * 512 * 2 + 2 * 1024 * 512 * 2 + 8192;
    int g = 1;
    {
        const int cands[3] = {8, 4, 2};
        for (int ci = 0; ci < 3; ci++) {
            size_t R = (size_t)cands[ci] * 4096;
            size_t need = constBytes + R * (2144 + 2112 + 2048 + 64 + 64 + 1024)
                        + (size_t)cands[ci] * 1024 * 4 + 16 * 256;
            if (need <= ws_size) { g = cands[ci]; break; }
        }
    }
    const size_t R = (size_t)g * 4096;
    const int nGroups = 8 / g;
    const int MT = (int)(R >> 7);

    char* ws = (char*)d_ws;
    size_t off = 0;
    auto alloc = [&](size_t bytes) -> char* {
        char* p = ws + off;
        off += (bytes + 255) & ~(size_t)255;
        return p;
    };
    unsigned short* xb16  = (unsigned short*)alloc(X_ELEMS * 2);
    unsigned short* ipb16[2];
    ipb16[0] = (unsigned short*)alloc(IP_ELEMS * 2);
    ipb16[1] = (unsigned short*)alloc(IP_ELEMS * 2);
    unsigned short* Ebuf  = (unsigned short*)alloc(2 * 512 * 1024 * 2);
    unsigned short* Ef    = Ebuf;
    unsigned short* Eb    = Ebuf + 512 * 1024;
    unsigned short* pwb   = (unsigned short*)alloc(2 * 512 * 512 * 2);
    unsigned short* opT   = (unsigned short*)alloc(2 * 1024 * 512 * 2);
    unsigned short* xbcdt = (unsigned short*)alloc(R * 1072 * 2);
    unsigned short* ybuf  = xbcdt;                       // alias (xbcdt dead by scan out)
    unsigned short* xconv = (unsigned short*)alloc(R * 1056 * 2);
    unsigned short* zbuf  = xconv;                       // alias (xconv dead after scans)
    float* fbuf = (float*)alloc(R * 512 * 4);
    float* dtb  = (float*)alloc(R * 16 * 4);
    float* dab  = (float*)alloc(R * 16 * 4);             // ldA -> cs (in-place in scan_chstate_k)
    float* Hbuf = (float*)alloc(R * 1024);
    float* dec  = (float*)alloc((size_t)g * 1024 * 4);

    dim3 blk(256);

    cvt_k<<<(unsigned)((X_ELEMS / 8 + 255) / 256), blk, 0, stream>>>(x, xb16, (int)(X_ELEMS / 8));
    cvt_k<<<(unsigned)((IP_ELEMS / 8 + 255) / 256), blk, 0, stream>>>(in_proj[0], ipb16[0], (int)(IP_ELEMS / 8));
    cvt_k<<<(unsigned)((IP_ELEMS / 8 + 255) / 256), blk, 0, stream>>>(in_proj[1], ipb16[1], (int)(IP_ELEMS / 8));
    pack_pw_k<<<256, blk, 0, stream>>>(proj_w, pwb);
    tr_op_k<<<dim3(32, 16, 2), blk, 0, stream>>>(out_proj[0], out_proj[1], opT);
    gemm_bt<0, false, false, false, false, false><<<dim3(8, 4), blk, 0, stream>>>(
        pwb, opT, Ef, nullptr, 1024, 512, 1024, 0);
    gemm_bt<0, false, false, false, false, false><<<dim3(8, 4), blk, 0, stream>>>(
        pwb + 512 * 512, opT + 1024 * 512, Eb, nullptr, 1024, 512, 1024, 0);

    for (int grp = 0; grp < nGroups; grp++) {
        const unsigned short* xg = xb16 + (size_t)grp * R * 512;
        const float* xgf = x + (size_t)grp * R * 512;
        float* og = outp + (size_t)grp * R * 512;

        for (int dir = 0; dir < 2; dir++) {
            if (dir == 0)
                gemm_bt<9, false, false, false, false, false><<<(unsigned)(9 * MT), blk, 0, stream>>>(
                    xg, ipb16[0] + (size_t)1024 * 512, xbcdt, nullptr, 1072, 512, 1072, 0);
            else
                gemm_bt<9, true, false, false, false, false><<<(unsigned)(9 * MT), blk, 0, stream>>>(
                    xg, ipb16[1] + (size_t)1024 * 512, xbcdt, nullptr, 1072, 512, 1072, 0);

            conv_silu_k<<<(unsigned)(R * 132 / 2048), blk, 0, stream>>>(xbcdt, conv_w[dir], conv_b[dir], xconv);
            dt_pre_k<<<(unsigned)(R * 16 / 256), blk, 0, stream>>>(xbcdt, dt_bias[dir], A_log[dir], dtb, dab);

            scan_chstate_k<<<dim3((unsigned)(R / 64), 4), blk, 0, stream>>>(xconv, dtb, dab, Hbuf, dec);
            scan_comb_k<<<(unsigned)(g * 64), dim3(64), 0, stream>>>(Hbuf, dec);
            scan_chout_k<<<dim3((unsigned)(R / 64), 4), blk, 0, stream>>>(xconv, dtb, dab, Hbuf, Dp[dir], ybuf);

            if (dir == 0)
                gemm_bt<8, false, false, false, false, false><<<(unsigned)(8 * MT), blk, 0, stream>>>(
                    xg, ipb16[0], zbuf, nullptr, 1024, 512, 1024, 0);
            else
                gemm_bt<8, true, false, false, false, false><<<(unsigned)(8 * MT), blk, 0, stream>>>(
                    xg, ipb16[1], zbuf, nullptr, 1024, 512, 1024, 0);

            rmsgate_k<<<(unsigned)(R / 4), blk, 0, stream>>>(ybuf, zbuf, norm_w[dir]);

            if (dir == 0)
                gemm_bt<4, false, false, true, true, false><<<(unsigned)(4 * MT), blk, 0, stream>>>(
                    ybuf, Ef, fbuf, proj_b, 512, 1024, 512, 0);
            else
                gemm_bt<4, false, true, true, false, true><<<(unsigned)(4 * MT), blk, 0, stream>>>(
                    ybuf, Eb, fbuf, nullptr, 512, 1024, 512, 0);
        }
        ln_k<<<(unsigned)(R / 4), blk, 0, stream>>>(xgf, fbuf, ln_w, ln_b, og);
    }
}

// Round 7
// 876.920 us; speedup vs baseline: 1.4684x; 1.0396x over previous
//
#include <hip/hip_runtime.h>
#include <hip/hip_bf16.h>
#include <math.h>

typedef __bf16 bf16x8_t __attribute__((ext_vector_type(8)));
typedef float f32x4_t __attribute__((ext_vector_type(4)));
typedef unsigned short u16x8_t __attribute__((ext_vector_type(8)));
typedef unsigned short u16x4_t __attribute__((ext_vector_type(4)));

#define DEV __device__ __forceinline__

DEV float bf2f(unsigned short u) {
    unsigned int v = ((unsigned int)u) << 16;
    return __builtin_bit_cast(float, v);
}
DEV unsigned short f2bf(float f) {
    unsigned int u = __builtin_bit_cast(unsigned int, f);
    u += 0x7fffu + ((u >> 16) & 1u);   // RNE
    return (unsigned short)(u >> 16);
}

// ---------------------------------------------------------------------------
// fp32 -> bf16 conversion (8 elems/thread)
// ---------------------------------------------------------------------------
__global__ __launch_bounds__(256) void cvt_k(
    const float* __restrict__ in, unsigned short* __restrict__ out, int n8)
{
    int t = blockIdx.x * 256 + threadIdx.x;
    if (t >= n8) return;
    f32x4_t a = ((const f32x4_t*)in)[t * 2];
    f32x4_t b = ((const f32x4_t*)in)[t * 2 + 1];
    u16x8_t o;
#pragma unroll
    for (int j = 0; j < 4; j++) { o[j] = f2bf(a[j]); o[4 + j] = f2bf(b[j]); }
    ((u16x8_t*)out)[t] = o;
}

// ---------------------------------------------------------------------------
// MFMA GEMM:  C[M x N] = A'[M x K] @ W[N x K]^T   (bf16 in, fp32 accum)
// 128x128 tile, BK=32, global_load_lds width-16 staging, XOR-swizzled chunks.
// Double-buffered LDS (2-phase): stage tile k+1 BEFORE computing tile k, one
// __syncthreads per iteration — load latency hides under ds_read+MFMA.
// NT>0: 1-D grid with XCD-chunked bijective swizzle (A-panel L2 locality).
// NT==0: plain 2-D grid (small prep GEMMs).
// ---------------------------------------------------------------------------
template <int NT, bool FLIP_A, bool FLIP_C, bool OUT_F32, bool ADD_BIAS, bool ACCUM>
__global__ __launch_bounds__(256, 2) void gemm_bt(
    const unsigned short* __restrict__ A,
    const unsigned short* __restrict__ W,
    void* __restrict__ Cout,
    const float* __restrict__ bias,
    int N, int K, int ldc, int col_ofs)
{
    __shared__ __attribute__((aligned(16))) unsigned char smem[32768]; // 2 x (A 8KB + W 8KB)
    const int tid  = threadIdx.x;
    const int wave = tid >> 6;
    const int lane = tid & 63;

    int mtile_i, ntile_i;
    if (NT == 0) {
        mtile_i = blockIdx.y;
        ntile_i = blockIdx.x;
    } else {
        const int L = blockIdx.x;
        const int MTl = (int)gridDim.x / NT;   // M-tiles; always % 8 == 0 here
        const int ppx = MTl >> 3;              // M-panels per XCD
        const int xcd = L & 7, q = L >> 3;
        mtile_i = xcd * ppx + q / NT;
        ntile_i = q % NT;
    }
    const int mtile = mtile_i << 7;
    const int ntile = ntile_i << 7;

    const int c0 = tid, c1 = 256 + tid;
    const int r0 = c0 >> 2, p0 = c0 & 3, g0 = p0 ^ ((r0 >> 1) & 3);
    const int r1 = c1 >> 2, p1 = c1 & 3, g1 = p1 ^ ((r1 >> 1) & 3);

    int am0 = mtile + r0; if (FLIP_A) am0 ^= 4095;
    int am1 = mtile + r1; if (FLIP_A) am1 ^= 4095;
    const unsigned short* aP0 = A + (size_t)am0 * K + g0 * 8;
    const unsigned short* aP1 = A + (size_t)am1 * K + g1 * 8;

    int wr0 = ntile + r0; if (wr0 > N - 1) wr0 = N - 1;
    int wr1 = ntile + r1; if (wr1 > N - 1) wr1 = N - 1;
    const unsigned short* wP0 = W + (size_t)wr0 * K + g0 * 8;
    const unsigned short* wP1 = W + (size_t)wr1 * K + g1 * 8;

    const int stago = wave * 1024;   // wave-uniform staging offset within each 4KB quarter

    f32x4_t acc[4][4] = {};

    const int wm = (wave & 1) << 6;
    const int wn = (wave >> 1) << 6;
    const int r    = lane & 15;
    const int quad = lane >> 4;
    const int sw   = (r >> 1) & 3;

    int aoff[4], woff[4];
#pragma unroll
    for (int i = 0; i < 4; i++) {
        int m = wm + i * 16 + r;
        aoff[i] = (m * 4 + (quad ^ sw)) * 16;
        int n = wn + i * 16 + r;
        woff[i] = (n * 4 + (quad ^ sw)) * 16 + 8192;
    }

    auto STAGE = [&](int kt, int bufsel) {
        const int k0 = kt << 5;
        unsigned char* base = smem + bufsel * 16384;
        __builtin_amdgcn_global_load_lds(
            (const __attribute__((address_space(1))) void*)(aP0 + k0),
            (__attribute__((address_space(3))) void*)(base + stago), 16, 0, 0);
        __builtin_amdgcn_global_load_lds(
            (const __attribute__((address_space(1))) void*)(aP1 + k0),
            (__attribute__((address_space(3))) void*)(base + 4096 + stago), 16, 0, 0);
        __builtin_amdgcn_global_load_lds(
            (const __attribute__((address_space(1))) void*)(wP0 + k0),
            (__attribute__((address_space(3))) void*)(base + 8192 + stago), 16, 0, 0);
        __builtin_amdgcn_global_load_lds(
            (const __attribute__((address_space(1))) void*)(wP1 + k0),
            (__attribute__((address_space(3))) void*)(base + 12288 + stago), 16, 0, 0);
    };

    const int nt = K >> 5;
    STAGE(0, 0);
    __syncthreads();

    for (int kt = 0; kt < nt; kt++) {
        const int cur = kt & 1;
        if (kt + 1 < nt) STAGE(kt + 1, cur ^ 1);   // prefetch next tile (latency hides under compute)

        const unsigned char* bufc = smem + cur * 16384;
        bf16x8_t af[4], wf[4];
#pragma unroll
        for (int i = 0; i < 4; i++)
            af[i] = __builtin_bit_cast(bf16x8_t, *(const u16x8_t*)(bufc + aoff[i]));
#pragma unroll
        for (int j = 0; j < 4; j++)
            wf[j] = __builtin_bit_cast(bf16x8_t, *(const u16x8_t*)(bufc + woff[j]));
#pragma unroll
        for (int i = 0; i < 4; i++)
#pragma unroll
            for (int j = 0; j < 4; j++)
                acc[i][j] = __builtin_amdgcn_mfma_f32_16x16x32_bf16(af[i], wf[j], acc[i][j], 0, 0, 0);
        __syncthreads();   // drains prefetch (already landed) + protects buf reuse
    }

    // epilogue: C/D layout col=lane&15, row=quad*4+reg
#pragma unroll
    for (int i = 0; i < 4; i++) {
#pragma unroll
        for (int j = 0; j < 4; j++) {
            int cc = ntile + wn + j * 16 + r;
            if (cc >= N) continue;
#pragma unroll
            for (int reg = 0; reg < 4; reg++) {
                int rr = mtile + wm + i * 16 + quad * 4 + reg;
                int orow = FLIP_C ? (rr ^ 4095) : rr;
                float v = acc[i][j][reg];
                if (ADD_BIAS) v += bias[cc];
                if (OUT_F32) {
                    float* p = (float*)Cout + (size_t)orow * ldc + col_ofs + cc;
                    if (ACCUM) v += *p;
                    *p = v;
                } else {
                    ((unsigned short*)Cout)[(size_t)orow * ldc + col_ofs + cc] = f2bf(v);
                }
            }
        }
    }
}

// ---------------------------------------------------------------------------
// pack proj_w slices to bf16: pwb[dir][n][j] = bf16(pw[n][dir*512+j])
// ---------------------------------------------------------------------------
__global__ __launch_bounds__(256) void pack_pw_k(
    const float* __restrict__ pw, unsigned short* __restrict__ pwb)
{
    int t = blockIdx.x * 256 + threadIdx.x;   // 65536 threads, 8 elems each
    int j8 = t & 63;
    int n  = (t >> 6) & 511;
    int dir = t >> 15;
    const float* src = pw + (size_t)n * 1024 + dir * 512 + j8 * 8;
    f32x4_t a = *(const f32x4_t*)src;
    f32x4_t b = *(const f32x4_t*)(src + 4);
    u16x8_t o;
#pragma unroll
    for (int j = 0; j < 4; j++) { o[j] = f2bf(a[j]); o[4 + j] = f2bf(b[j]); }
    *(u16x8_t*)(pwb + (size_t)dir * 512 * 512 + (size_t)n * 512 + j8 * 8) = o;
}

// ---------------------------------------------------------------------------
// transpose out_proj to bf16: opT[dir][k][j] = bf16(op_dir[j][k])
// ---------------------------------------------------------------------------
__global__ __launch_bounds__(256) void tr_op_k(
    const float* __restrict__ op0, const float* __restrict__ op1,
    unsigned short* __restrict__ opT)
{
    __shared__ float tile[32][33];
    const int dir = blockIdx.z;
    const float* op = dir ? op1 : op0;
    const int k0 = blockIdx.x * 32;
    const int j0 = blockIdx.y * 32;
    const int tx = threadIdx.x & 31, ty = threadIdx.x >> 5;
#pragma unroll
    for (int i = 0; i < 4; i++) {
        int j = j0 + ty + i * 8;
        tile[ty + i * 8][tx] = op[(size_t)j * 1024 + k0 + tx];
    }
    __syncthreads();
    unsigned short* dst = opT + (size_t)dir * 1024 * 512;
#pragma unroll
    for (int i = 0; i < 4; i++) {
        int k = k0 + ty + i * 8;
        dst[(size_t)k * 512 + j0 + tx] = f2bf(tile[tx][ty + i * 8]);
    }
}

// ---------------------------------------------------------------------------
// Depthwise causal conv (width 4) + SiLU, 8 rows/thread sliding window.
// ---------------------------------------------------------------------------
__global__ __launch_bounds__(256) void conv_silu_k(
    const unsigned short* __restrict__ xin,  // R x 1072 bf16
    const float* __restrict__ cw,            // 1056 x 4 fp32
    const float* __restrict__ cb,            // 1056 fp32
    unsigned short* __restrict__ outp)       // R x 1056 bf16
{
    int t = blockIdx.x * 256 + threadIdx.x;
    int c8 = t % 132;
    int rb = t / 132;
    int c = c8 * 8;
    int row0 = rb * 8;
    int l0 = row0 & 4095;

    float w[8][4];
#pragma unroll
    for (int j = 0; j < 8; j++) {
        f32x4_t wv = *(const f32x4_t*)(cw + (c + j) * 4);
        w[j][0] = wv[0]; w[j][1] = wv[1]; w[j][2] = wv[2]; w[j][3] = wv[3];
    }
    float bia[8];
    {
        f32x4_t b0 = *(const f32x4_t*)(cb + c);
        f32x4_t b1 = *(const f32x4_t*)(cb + c + 4);
#pragma unroll
        for (int j = 0; j < 4; j++) { bia[j] = b0[j]; bia[4 + j] = b1[j]; }
    }

    u16x8_t zero;
#pragma unroll
    for (int j = 0; j < 8; j++) zero[j] = 0;

    // window rows row0-3 .. row0+7 (11 rows); pre-batch rows are zero
    u16x8_t win[11];
#pragma unroll
    for (int u = 0; u < 11; u++) {
        int lu = l0 - 3 + u;
        win[u] = (lu >= 0)
            ? *(const u16x8_t*)(xin + (size_t)(row0 - 3 + u) * 1072 + c)
            : zero;
    }

#pragma unroll
    for (int s = 0; s < 8; s++) {
        float acc[8];
#pragma unroll
        for (int j = 0; j < 8; j++) acc[j] = bia[j];
#pragma unroll
        for (int k = 0; k < 4; k++) {
            u16x8_t xv = win[s + k];
#pragma unroll
            for (int j = 0; j < 8; j++)
                acc[j] = fmaf(bf2f(xv[j]), w[j][k], acc[j]);
        }
        u16x8_t o;
#pragma unroll
        for (int j = 0; j < 8; j++) {
            float xx = acc[j];
            o[j] = f2bf(xx * __builtin_amdgcn_rcpf(1.f + __expf(-xx)));
        }
        *(u16x8_t*)(outp + (size_t)(row0 + s) * 1056 + c) = o;
    }
}

// ---------------------------------------------------------------------------
// dt = softplus(dt_raw + dt_bias), ldA = dt * -exp(A_log)  (log of dA)
// ---------------------------------------------------------------------------
__global__ __launch_bounds__(256) void dt_pre_k(
    const unsigned short* __restrict__ xin,  // R x 1072 bf16 (dt raw at 1056..1071)
    const float* __restrict__ dt_bias,
    const float* __restrict__ A_log,
    float* __restrict__ dtb, float* __restrict__ ldab)
{
    int t = blockIdx.x * 256 + threadIdx.x;  // R*16
    int h = t & 15;
    int row = t >> 4;
    float x = bf2f(xin[(size_t)row * 1072 + 1056 + h]) + dt_bias[h];
    float dt = (x > 20.f) ? x : log1pf(__expf(x));
    float A = -__expf(A_log[h]);
    dtb[t] = dt;
    ldab[t] = dt * A;       // log(dA); cumsum later (exact: dA = exp(dt*A))
}

// ---------------------------------------------------------------------------
// Chunked scan as MFMA GEMMs (Mamba2 SSD formulation), chunk = 64.
// ---------------------------------------------------------------------------
DEV void stage_xt(const unsigned short* __restrict__ xrow, unsigned short* XtW, int l)
{
    u16x8_t xv[8];
#pragma unroll
    for (int m = 0; m < 8; m++) xv[m] = *(const u16x8_t*)(xrow + m * 8);
#pragma unroll
    for (int p = 0; p < 64; p++) {
        int blkc = (l >> 3) ^ (p & 7);
        XtW[p * 64 + blkc * 8 + (l & 7)] = xv[p >> 3][p & 7];
    }
}

DEV bf16x8_t xt_frag(const unsigned short* XtW, int r, int quad, int jj, int kk)
{
    int p = jj * 16 + r;
    int blkc = (kk * 4 + quad) ^ (p & 7);
    return __builtin_bit_cast(bf16x8_t, *(const u16x8_t*)(XtW + p * 64 + blkc * 8));
}

__global__ __launch_bounds__(256) void scan_chstate_k(
    const unsigned short* __restrict__ xc,   // R x 1056 bf16
    const float* __restrict__ dtb,
    float* __restrict__ lcs,                 // in: ldA ; out: cs (in-place, same elem)
    float* __restrict__ Hend, float* __restrict__ dec)
{
    __shared__ __attribute__((aligned(16))) unsigned char sm[37120];
    unsigned short* Btr = (unsigned short*)sm;          // [16][72] bf16 (B transposed)
    float* csW = (float*)(sm + 2304);                   // [4][64]
    float* dtW = (float*)(sm + 3328);                   // [4][64]
    unsigned short* Xt0 = (unsigned short*)(sm + 4352); // [4][64*64]

    const int tid = threadIdx.x;
    const int w = tid >> 6, l = tid & 63;
    const int r = l & 15, quad = l >> 4;
    const int row0 = blockIdx.x * 64;
    const int b = blockIdx.x >> 6, chunk = blockIdx.x & 63;
    const int h = blockIdx.y * 4 + w;
    const int blk = ((b * 16 + h) << 6) | chunk;

    // stage Bt[n][s] = B[s][n]
    {
        int n = tid & 15, s0 = (tid >> 4) * 4;
#pragma unroll
        for (int js = 0; js < 4; js++) {
            int s = s0 + js;
            Btr[n * 72 + s] = xc[(size_t)(row0 + s) * 1056 + 1024 + n];
        }
    }

    // per-lane ldA/dt + inclusive wave scan -> cs
    float v   = lcs[(size_t)(row0 + l) * 16 + h];
    float dtv = dtb[(size_t)(row0 + l) * 16 + h];
#pragma unroll
    for (int d = 1; d < 64; d <<= 1) {
        float o = __shfl_up(v, d, 64);
        if (l >= d) v += o;
    }
    lcs[(size_t)(row0 + l) * 16 + h] = v;
    csW[w * 64 + l] = v;
    dtW[w * 64 + l] = dtv;
    if (l == 63) dec[blk] = __expf(v);
    __syncthreads();

    unsigned short* XtW = Xt0 + w * 4096;
    stage_xt(xc + (size_t)(row0 + l) * 1056 + h * 64, XtW, l);

    const float* csr = csW + w * 64;
    const float* dtr = dtW + w * 64;
    float cs63 = csr[63];

    f32x4_t z = {0.f, 0.f, 0.f, 0.f};
    f32x4_t hacc[4] = {z, z, z, z};
#pragma unroll
    for (int kk = 0; kk < 2; kk++) {
        int sb = kk * 32 + quad * 8;
        u16x8_t bv = *(const u16x8_t*)(Btr + r * 72 + sb);
        f32x4_t c0 = *(const f32x4_t*)(csr + sb);
        f32x4_t c1 = *(const f32x4_t*)(csr + sb + 4);
        f32x4_t d0 = *(const f32x4_t*)(dtr + sb);
        f32x4_t d1 = *(const f32x4_t*)(dtr + sb + 4);
        u16x8_t wv;
#pragma unroll
        for (int j = 0; j < 4; j++) {
            wv[j]     = f2bf(bf2f(bv[j])     * d0[j] * __expf(cs63 - c0[j]));
            wv[4 + j] = f2bf(bf2f(bv[4 + j]) * d1[j] * __expf(cs63 - c1[j]));
        }
        bf16x8_t wf = __builtin_bit_cast(bf16x8_t, wv);
#pragma unroll
        for (int jj = 0; jj < 4; jj++)
            hacc[jj] = __builtin_amdgcn_mfma_f32_16x16x32_bf16(wf, xt_frag(XtW, r, quad, jj, kk), hacc[jj], 0, 0, 0);
    }
    float* o = Hend + (size_t)blk * 1024;
#pragma unroll
    for (int jj = 0; jj < 4; jj++)
#pragma unroll
        for (int reg = 0; reg < 4; reg++)
            o[(jj * 16 + r) * 16 + quad * 4 + reg] = hacc[jj][reg];
}

// Combine: exclusive prefix over 64 chunk states per (b,h) — unchanged.
__global__ __launch_bounds__(64) void scan_comb_k(float* __restrict__ H, const float* __restrict__ dec)
{
    int bh = blockIdx.x >> 2;
    int q  = blockIdx.x & 3;
    int t  = threadIdx.x;
    float* base = H + (size_t)bh * 64 * 1024 + q * 256 + t * 4;
    const float* dp = dec + bh * 64;
    f32x4_t hs = {0.f, 0.f, 0.f, 0.f};
    f32x4_t cur = *(const f32x4_t*)base;
    for (int c = 0; c < 64; c++) {
        int cn = (c < 63) ? c + 1 : 63;
        f32x4_t nxt = *(const f32x4_t*)(base + (size_t)cn * 1024);
        float d = dp[c];
        *(f32x4_t*)(base + (size_t)c * 1024) = hs;   // exclusive prefix
#pragma unroll
        for (int j = 0; j < 4; j++) hs[j] = fmaf(hs[j], d, cur[j]);
        cur = nxt;
    }
}

__global__ __launch_bounds__(256) void scan_chout_k(
    const unsigned short* __restrict__ xc,
    const float* __restrict__ dtb, const float* __restrict__ csb,
    const float* __restrict__ Hst, const float* __restrict__ Dp,
    unsigned short* __restrict__ ybuf)  // R x 1024 bf16
{
    __shared__ __attribute__((aligned(16))) unsigned char sm[60416];
    unsigned short* Ct = (unsigned short*)sm;            // [64][32] (cols 16..31 = 0)
    unsigned short* Bt = (unsigned short*)(sm + 4096);   // [64][32]
    float* S   = (float*)(sm + 8192);                    // [64][68]
    float* csL = (float*)(sm + 25600);                   // [4][64]
    float* dtL = (float*)(sm + 26624);                   // [4][64]
    unsigned short* Xt0 = (unsigned short*)(sm + 27648); // [4][64*64]

    const int tid = threadIdx.x;
    const int w = tid >> 6, l = tid & 63;
    const int r = l & 15, quad = l >> 4;
    const int row0 = blockIdx.x * 64;
    const int b = blockIdx.x >> 6, chunk = blockIdx.x & 63;
    const int h = blockIdx.y * 4 + w;
    const int blk = ((b * 16 + h) << 6) | chunk;

    // stage padded B/C tiles
    {
        int rowi = tid >> 2, seg = tid & 3;
        u16x8_t vb, vc;
        if (seg < 2) {
            const unsigned short* src = xc + (size_t)(row0 + rowi) * 1056 + 1024 + seg * 8;
            vb = *(const u16x8_t*)src;
            vc = *(const u16x8_t*)(src + 16);
        } else {
#pragma unroll
            for (int j = 0; j < 8; j++) { vb[j] = 0; vc[j] = 0; }
        }
        *(u16x8_t*)(Bt + rowi * 32 + seg * 8) = vb;
        *(u16x8_t*)(Ct + rowi * 32 + seg * 8) = vc;
    }
    // stage cs/dt for this block's 4 heads
    csL[w * 64 + l] = csb[(size_t)(row0 + l) * 16 + h];
    dtL[w * 64 + l] = dtb[(size_t)(row0 + l) * 16 + h];
    __syncthreads();

    // S = C @ B^T : wave w computes t-rows [w*16, w*16+16)
    {
        bf16x8_t cf = __builtin_bit_cast(bf16x8_t, *(const u16x8_t*)(Ct + (w * 16 + r) * 32 + quad * 8));
        f32x4_t z = {0.f, 0.f, 0.f, 0.f};
#pragma unroll
        for (int j = 0; j < 4; j++) {
            bf16x8_t bfv = __builtin_bit_cast(bf16x8_t, *(const u16x8_t*)(Bt + (j * 16 + r) * 32 + quad * 8));
            f32x4_t d = __builtin_amdgcn_mfma_f32_16x16x32_bf16(cf, bfv, z, 0, 0, 0);
#pragma unroll
            for (int reg = 0; reg < 4; reg++)
                S[(w * 16 + quad * 4 + reg) * 68 + j * 16 + r] = d[reg];
        }
    }
    __syncthreads();

    // per-wave head section
    unsigned short* XtW = Xt0 + w * 4096;
    stage_xt(xc + (size_t)(row0 + l) * 1056 + h * 64, XtW, l);

    const float* csr = csL + w * 64;
    const float* dtr = dtL + w * 64;

    // Y_inter = C @ Hstart^T, then row-scale by exp(cs_t)
    f32x4_t acc[4][4];
    {
        bf16x8_t hf[4];
#pragma unroll
        for (int jj = 0; jj < 4; jj++) {
            int p = jj * 16 + r;
            u16x8_t hv;
            if (quad < 2) {
                const float* hp = Hst + (size_t)blk * 1024 + p * 16 + quad * 8;
                f32x4_t h0 = *(const f32x4_t*)hp;
                f32x4_t h1 = *(const f32x4_t*)(hp + 4);
#pragma unroll
                for (int j = 0; j < 4; j++) { hv[j] = f2bf(h0[j]); hv[4 + j] = f2bf(h1[j]); }
            } else {
#pragma unroll
                for (int j = 0; j < 8; j++) hv[j] = 0;
            }
            hf[jj] = __builtin_bit_cast(bf16x8_t, hv);
        }
        f32x4_t z = {0.f, 0.f, 0.f, 0.f};
#pragma unroll
        for (int i = 0; i < 4; i++) {
            bf16x8_t cf = __builtin_bit_cast(bf16x8_t, *(const u16x8_t*)(Ct + (i * 16 + r) * 32 + quad * 8));
#pragma unroll
            for (int jj = 0; jj < 4; jj++)
                acc[i][jj] = __builtin_amdgcn_mfma_f32_16x16x32_bf16(cf, hf[jj], z, 0, 0, 0);
        }
#pragma unroll
        for (int i = 0; i < 4; i++) {
            f32x4_t es;
#pragma unroll
            for (int reg = 0; reg < 4; reg++) es[reg] = __expf(csr[i * 16 + quad * 4 + reg]);
#pragma unroll
            for (int jj = 0; jj < 4; jj++)
#pragma unroll
                for (int reg = 0; reg < 4; reg++) acc[i][jj][reg] *= es[reg];
        }
    }

    // Y_intra += W @ X
#pragma unroll
    for (int kk = 0; kk < 2; kk++) {
        int sb = kk * 32 + quad * 8;
        bf16x8_t xf[4];
#pragma unroll
        for (int jj = 0; jj < 4; jj++) xf[jj] = xt_frag(XtW, r, quad, jj, kk);
        f32x4_t c0 = *(const f32x4_t*)(csr + sb);
        f32x4_t c1 = *(const f32x4_t*)(csr + sb + 4);
        f32x4_t d0 = *(const f32x4_t*)(dtr + sb);
        f32x4_t d1 = *(const f32x4_t*)(dtr + sb + 4);
#pragma unroll
        for (int i = 0; i < 4; i++) {
            int t = i * 16 + r;
            float cst = csr[t];
            const float* Srow = S + t * 68;
            f32x4_t s0 = *(const f32x4_t*)(Srow + sb);
            f32x4_t s1 = *(const f32x4_t*)(Srow + sb + 4);
            u16x8_t wv;
#pragma unroll
            for (int j = 0; j < 4; j++) {
                int s = sb + j;
                float v0 = (s <= t) ? __expf(cst - c0[j]) * d0[j] * s0[j] : 0.f;
                wv[j] = f2bf(v0);
                int s2 = sb + 4 + j;
                float v1 = (s2 <= t) ? __expf(cst - c1[j]) * d1[j] * s1[j] : 0.f;
                wv[4 + j] = f2bf(v1);
            }
            bf16x8_t wf = __builtin_bit_cast(bf16x8_t, wv);
#pragma unroll
            for (int jj = 0; jj < 4; jj++)
                acc[i][jj] = __builtin_amdgcn_mfma_f32_16x16x32_bf16(wf, xf[jj], acc[i][jj], 0, 0, 0);
        }
    }

    // D-term + store y
    float Dh = Dp[h];
#pragma unroll
    for (int i = 0; i < 4; i++) {
#pragma unroll
        for (int jj = 0; jj < 4; jj++) {
            int p = jj * 16 + r;
            int t0 = i * 16 + quad * 4;
            int blk2 = (t0 >> 3) ^ (p & 7);
            u16x4_t x4 = *(const u16x4_t*)(XtW + p * 64 + blk2 * 8 + (t0 & 7));
#pragma unroll
            for (int reg = 0; reg < 4; reg++) {
                float yv = fmaf(Dh, bf2f(x4[reg]), acc[i][jj][reg]);
                ybuf[(size_t)(row0 + t0 + reg) * 1024 + h * 64 + p] = f2bf(yv);
            }
        }
    }
}

// ---------------------------------------------------------------------------
// Gated RMSNorm (in-place on y, bf16): wave-per-row, no barriers
// ---------------------------------------------------------------------------
__global__ __launch_bounds__(256) void rmsgate_k(
    unsigned short* __restrict__ y,
    const unsigned short* __restrict__ z,
    const float* __restrict__ nw)
{
    const int wave = threadIdx.x >> 6, lane = threadIdx.x & 63;
    const size_t row = (size_t)blockIdx.x * 4 + wave;
    const int c = lane * 16;
    unsigned short* yp = y + row * 1024 + c;
    const unsigned short* zp = z + row * 1024 + c;
    u16x8_t yv0 = *(const u16x8_t*)yp;
    u16x8_t yv1 = *(const u16x8_t*)(yp + 8);
    u16x8_t zv0 = *(const u16x8_t*)zp;
    u16x8_t zv1 = *(const u16x8_t*)(zp + 8);
    float g[16];
    float ss = 0.f;
#pragma unroll
    for (int j = 0; j < 8; j++) {
        float zf = bf2f(zv0[j]);
        float sil = zf * __builtin_amdgcn_rcpf(1.f + __expf(-zf));
        g[j] = bf2f(yv0[j]) * sil;
        ss += g[j] * g[j];
    }
#pragma unroll
    for (int j = 0; j < 8; j++) {
        float zf = bf2f(zv1[j]);
        float sil = zf * __builtin_amdgcn_rcpf(1.f + __expf(-zf));
        g[8 + j] = bf2f(yv1[j]) * sil;
        ss += g[8 + j] * g[8 + j];
    }
#pragma unroll
    for (int m = 32; m > 0; m >>= 1) ss += __shfl_xor(ss, m, 64);
    float scale = rsqrtf(ss * (1.f / 1024.f) + 1e-5f);
    f32x4_t w0 = *(const f32x4_t*)(nw + c);
    f32x4_t w1 = *(const f32x4_t*)(nw + c + 4);
    f32x4_t w2 = *(const f32x4_t*)(nw + c + 8);
    f32x4_t w3 = *(const f32x4_t*)(nw + c + 12);
    u16x8_t o0, o1;
#pragma unroll
    for (int j = 0; j < 4; j++) {
        o0[j]     = f2bf(g[j]      * scale * w0[j]);
        o0[4 + j] = f2bf(g[4 + j]  * scale * w1[j]);
        o1[j]     = f2bf(g[8 + j]  * scale * w2[j]);
        o1[4 + j] = f2bf(g[12 + j] * scale * w3[j]);
    }
    *(u16x8_t*)yp = o0;
    *(u16x8_t*)(yp + 8) = o1;
}

// ---------------------------------------------------------------------------
// Final: out = LayerNorm(x + f) — wave-per-row, no barriers
// ---------------------------------------------------------------------------
__global__ __launch_bounds__(256) void ln_k(
    const float* __restrict__ x,   // R x 512 fp32
    const float* __restrict__ f,   // R x 512 fp32
    const float* __restrict__ lw,
    const float* __restrict__ lb,
    float* __restrict__ outp)      // R x 512 fp32
{
    const int wave = threadIdx.x >> 6, lane = threadIdx.x & 63;
    const size_t row = (size_t)blockIdx.x * 4 + wave;
    const int c = lane * 8;
    f32x4_t xv0 = *(const f32x4_t*)(x + row * 512 + c);
    f32x4_t xv1 = *(const f32x4_t*)(x + row * 512 + c + 4);
    f32x4_t fv0 = *(const f32x4_t*)(f + row * 512 + c);
    f32x4_t fv1 = *(const f32x4_t*)(f + row * 512 + c + 4);
    float s[8];
    float sum = 0.f, sq = 0.f;
#pragma unroll
    for (int j = 0; j < 4; j++) {
        s[j] = xv0[j] + fv0[j];
        s[4 + j] = xv1[j] + fv1[j];
    }
#pragma unroll
    for (int j = 0; j < 8; j++) { sum += s[j]; sq += s[j] * s[j]; }
#pragma unroll
    for (int m = 32; m > 0; m >>= 1) {
        sum += __shfl_xor(sum, m, 64);
        sq  += __shfl_xor(sq, m, 64);
    }
    float mu = sum * (1.f / 512.f);
    float var = sq * (1.f / 512.f) - mu * mu;
    if (var < 0.f) var = 0.f;
    float inv = rsqrtf(var + 1e-5f);
    f32x4_t w0 = *(const f32x4_t*)(lw + c);
    f32x4_t w1 = *(const f32x4_t*)(lw + c + 4);
    f32x4_t b0 = *(const f32x4_t*)(lb + c);
    f32x4_t b1 = *(const f32x4_t*)(lb + c + 4);
    f32x4_t o0, o1;
#pragma unroll
    for (int j = 0; j < 4; j++) {
        o0[j] = (s[j] - mu) * inv * w0[j] + b0[j];
        o1[j] = (s[4 + j] - mu) * inv * w1[j] + b1[j];
    }
    *(f32x4_t*)(outp + row * 512 + c) = o0;
    *(f32x4_t*)(outp + row * 512 + c + 4) = o1;
}

// ---------------------------------------------------------------------------
extern "C" void kernel_launch(void* const* d_in, const int* in_sizes, int n_in,
                              void* d_out, int out_size, void* d_ws, size_t ws_size,
                              hipStream_t stream)
{
    (void)in_sizes; (void)n_in; (void)out_size;

    const float* x           = (const float*)d_in[0];
    const float* in_proj[2]  = {(const float*)d_in[1],  (const float*)d_in[9]};
    const float* conv_w[2]   = {(const float*)d_in[2],  (const float*)d_in[10]};
    const float* conv_b[2]   = {(const float*)d_in[3],  (const float*)d_in[11]};
    const float* dt_bias[2]  = {(const float*)d_in[4],  (const float*)d_in[12]};
    const float* A_log[2]    = {(const float*)d_in[5],  (const float*)d_in[13]};
    const float* Dp[2]       = {(const float*)d_in[6],  (const float*)d_in[14]};
    const float* norm_w[2]   = {(const float*)d_in[7],  (const float*)d_in[15]};
    const float* out_proj[2] = {(const float*)d_in[8],  (const float*)d_in[16]};
    const float* proj_w      = (const float*)d_in[17];
    const float* proj_b      = (const float*)d_in[18];
    const float* ln_w        = (const float*)d_in[19];
    const float* ln_b        = (const float*)d_in[20];
    float* outp = (float*)d_out;

    const size_t IP_ELEMS = (size_t)2096 * 512;
    const size_t X_ELEMS  = (size_t)32768 * 512;

    const size_t constBytes = X_ELEMS * 2 + 2 * IP_ELEMS * 2 + 2 * 512 * 1024 * 2
                            + 2 * 512 * 512 * 2 + 2 * 1024 * 512 * 2 + 8192;
    int g = 1;
    {
        const int cands[3] = {8, 4, 2};
        for (int ci = 0; ci < 3; ci++) {
            size_t R = (size_t)cands[ci] * 4096;
            size_t need = constBytes + R * (2144 + 2112 + 2048 + 64 + 64 + 1024)
                        + (size_t)cands[ci] * 1024 * 4 + 16 * 256;
            if (need <= ws_size) { g = cands[ci]; break; }
        }
    }
    const size_t R = (size_t)g * 4096;
    const int nGroups = 8 / g;
    const int MT = (int)(R >> 7);

    char* ws = (char*)d_ws;
    size_t off = 0;
    auto alloc = [&](size_t bytes) -> char* {
        char* p = ws + off;
        off += (bytes + 255) & ~(size_t)255;
        return p;
    };
    unsigned short* xb16  = (unsigned short*)alloc(X_ELEMS * 2);
    unsigned short* ipb16[2];
    ipb16[0] = (unsigned short*)alloc(IP_ELEMS * 2);
    ipb16[1] = (unsigned short*)alloc(IP_ELEMS * 2);
    unsigned short* Ebuf  = (unsigned short*)alloc(2 * 512 * 1024 * 2);
    unsigned short* Ef    = Ebuf;
    unsigned short* Eb    = Ebuf + 512 * 1024;
    unsigned short* pwb   = (unsigned short*)alloc(2 * 512 * 512 * 2);
    unsigned short* opT   = (unsigned short*)alloc(2 * 1024 * 512 * 2);
    unsigned short* xbcdt = (unsigned short*)alloc(R * 1072 * 2);
    unsigned short* ybuf  = xbcdt;                       // alias (xbcdt dead by scan out)
    unsigned short* xconv = (unsigned short*)alloc(R * 1056 * 2);
    unsigned short* zbuf  = xconv;                       // alias (xconv dead after scans)
    float* fbuf = (float*)alloc(R * 512 * 4);
    float* dtb  = (float*)alloc(R * 16 * 4);
    float* dab  = (float*)alloc(R * 16 * 4);             // ldA -> cs (in-place in scan_chstate_k)
    float* Hbuf = (float*)alloc(R * 1024);
    float* dec  = (float*)alloc((size_t)g * 1024 * 4);

    dim3 blk(256);

    cvt_k<<<(unsigned)((X_ELEMS / 8 + 255) / 256), blk, 0, stream>>>(x, xb16, (int)(X_ELEMS / 8));
    cvt_k<<<(unsigned)((IP_ELEMS / 8 + 255) / 256), blk, 0, stream>>>(in_proj[0], ipb16[0], (int)(IP_ELEMS / 8));
    cvt_k<<<(unsigned)((IP_ELEMS / 8 + 255) / 256), blk, 0, stream>>>(in_proj[1], ipb16[1], (int)(IP_ELEMS / 8));
    pack_pw_k<<<256, blk, 0, stream>>>(proj_w, pwb);
    tr_op_k<<<dim3(32, 16, 2), blk, 0, stream>>>(out_proj[0], out_proj[1], opT);
    gemm_bt<0, false, false, false, false, false><<<dim3(8, 4), blk, 0, stream>>>(
        pwb, opT, Ef, nullptr, 1024, 512, 1024, 0);
    gemm_bt<0, false, false, false, false, false><<<dim3(8, 4), blk, 0, stream>>>(
        pwb + 512 * 512, opT + 1024 * 512, Eb, nullptr, 1024, 512, 1024, 0);

    for (int grp = 0; grp < nGroups; grp++) {
        const unsigned short* xg = xb16 + (size_t)grp * R * 512;
        const float* xgf = x + (size_t)grp * R * 512;
        float* og = outp + (size_t)grp * R * 512;

        for (int dir = 0; dir < 2; dir++) {
            if (dir == 0)
                gemm_bt<9, false, false, false, false, false><<<(unsigned)(9 * MT), blk, 0, stream>>>(
                    xg, ipb16[0] + (size_t)1024 * 512, xbcdt, nullptr, 1072, 512, 1072, 0);
            else
                gemm_bt<9, true, false, false, false, false><<<(unsigned)(9 * MT), blk, 0, stream>>>(
                    xg, ipb16[1] + (size_t)1024 * 512, xbcdt, nullptr, 1072, 512, 1072, 0);

            conv_silu_k<<<(unsigned)(R * 132 / 2048), blk, 0, stream>>>(xbcdt, conv_w[dir], conv_b[dir], xconv);
            dt_pre_k<<<(unsigned)(R * 16 / 256), blk, 0, stream>>>(xbcdt, dt_bias[dir], A_log[dir], dtb, dab);

            scan_chstate_k<<<dim3((unsigned)(R / 64), 4), blk, 0, stream>>>(xconv, dtb, dab, Hbuf, dec);
            scan_comb_k<<<(unsigned)(g * 64), dim3(64), 0, stream>>>(Hbuf, dec);
            scan_chout_k<<<dim3((unsigned)(R / 64), 4), blk, 0, stream>>>(xconv, dtb, dab, Hbuf, Dp[dir], ybuf);

            if (dir == 0)
                gemm_bt<8, false, false, false, false, false><<<(unsigned)(8 * MT), blk, 0, stream>>>(
                    xg, ipb16[0], zbuf, nullptr, 1024, 512, 1024, 0);
            else
                gemm_bt<8, true, false, false, false, false><<<(unsigned)(8 * MT), blk, 0, stream>>>(
                    xg, ipb16[1], zbuf, nullptr, 1024, 512, 1024, 0);

            rmsgate_k<<<(unsigned)(R / 4), blk, 0, stream>>>(ybuf, zbuf, norm_w[dir]);

            if (dir == 0)
                gemm_bt<4, false, false, true, true, false><<<(unsigned)(4 * MT), blk, 0, stream>>>(
                    ybuf, Ef, fbuf, proj_b, 512, 1024, 512, 0);
            else
                gemm_bt<4, false, true, true, false, true><<<(unsigned)(4 * MT), blk, 0, stream>>>(
                    ybuf, Eb, fbuf, nullptr, 512, 1024, 512, 0);
        }
        ln_k<<<(unsigned)(R / 4), blk, 0, stream>>>(xgf, fbuf, ln_w, ln_b, og);
    }
}